// Round 1
// baseline (6594.786 us; speedup 1.0000x reference)
//
#include <hip/hip_runtime.h>
#include <float.h>
#include <math.h>

#define MG 128
#define NNODE 62
#define DD 512
#define NH 8
#define DH 64
#define DFF 2048
#define NLAYER 4
#define EPG 600
#define KP1 50
#define KP2 40
#define NTOK (MG*NNODE)      // 7936
#define NEDGE (MG*EPG)       // 76800
#define EPSV 1e-5f

__device__ __forceinline__ float wave_sum(float v) {
  for (int off = 32; off; off >>= 1) v += __shfl_xor(v, off);
  return v;
}
__device__ __forceinline__ float wave_max(float v) {
  for (int off = 32; off; off >>= 1) v = fmaxf(v, __shfl_xor(v, off));
  return v;
}

// ---------------- BatchNorm stats (train mode, per-channel over (N,L)) ----------------
__global__ __launch_bounds__(256) void bn_stats_kernel(const float* __restrict__ x,
    float* __restrict__ mu, float* __restrict__ rs) {
  int s = blockIdx.x;
  float sum = 0.f, sq = 0.f;
  for (int i = threadIdx.x; i < MG*NNODE; i += 256) {
    int b = i / NNODE, j = i - b*NNODE;
    float v = x[(size_t)(b*NNODE + s)*NNODE + j];
    sum += v; sq += v*v;
  }
  __shared__ float r1[4], r2[4];
  sum = wave_sum(sum); sq = wave_sum(sq);
  int wv = threadIdx.x >> 6, lane = threadIdx.x & 63;
  if (lane == 0) { r1[wv] = sum; r2[wv] = sq; }
  __syncthreads();
  if (threadIdx.x == 0) {
    float S = r1[0]+r1[1]+r1[2]+r1[3];
    float Q = r2[0]+r2[1]+r2[2]+r2[3];
    float m = S / (float)(MG*NNODE);
    float var = Q / (float)(MG*NNODE) - m*m;
    mu[s] = m;
    rs[s] = rsqrtf(var + EPSV);
  }
}

// ---------------- t[s,b,:] = BN(x)[b,s,:] @ W_emb  (tok = s*128+b) ----------------
__global__ __launch_bounds__(256) void embed_kernel(const float* __restrict__ x,
    const float* __restrict__ mu, const float* __restrict__ rs,
    const float* __restrict__ gg, const float* __restrict__ bb,
    const float* __restrict__ W, float* __restrict__ T) {
  int tok = blockIdx.x;
  int s = tok >> 7, b = tok & 127;
  __shared__ float xb[NNODE];
  if (threadIdx.x < NNODE) {
    float v = x[(size_t)(b*NNODE + s)*NNODE + threadIdx.x];
    xb[threadIdx.x] = (v - mu[s]) * rs[s] * gg[s] + bb[s];
  }
  __syncthreads();
  int d = threadIdx.x;
  float a0 = 0.f, a1 = 0.f;
  for (int j = 0; j < NNODE; ++j) {
    float xv = xb[j];
    a0 += xv * W[(size_t)j*DD + d];
    a1 += xv * W[(size_t)j*DD + d + 256];
  }
  T[(size_t)tok*DD + d] = a0;
  T[(size_t)tok*DD + d + 256] = a1;
}

// ---------------- generic fp32 GEMM: C = A[M,K] @ B[K,N] (+bias)(+relu) ----------------
template<bool RELU>
__global__ __launch_bounds__(256) void gemm_kernel(const float* __restrict__ A,
    const float* __restrict__ B, const float* __restrict__ bias, float* __restrict__ C,
    int M, int N, int K) {
  __shared__ float As[16][68];
  __shared__ float Bs[16][68];
  int bm = blockIdx.y * 64, bn = blockIdx.x * 64;
  int tid = threadIdx.x;
  int tx = tid & 15, ty = tid >> 4;
  float acc[4][4] = {};
  for (int k0 = 0; k0 < K; k0 += 16) {
    {
      int row = tid >> 2; int kk = (tid & 3) * 4;
      int gm = bm + row;
      #pragma unroll
      for (int i = 0; i < 4; ++i) {
        int gk = k0 + kk + i;
        As[kk+i][row] = (gm < M && gk < K) ? A[(size_t)gm*K + gk] : 0.f;
      }
    }
    {
      int krow = tid >> 4; int nn = (tid & 15) * 4;
      int gk = k0 + krow;
      #pragma unroll
      for (int i = 0; i < 4; ++i) {
        int gn = bn + nn + i;
        Bs[krow][nn+i] = (gk < K && gn < N) ? B[(size_t)gk*N + gn] : 0.f;
      }
    }
    __syncthreads();
    #pragma unroll
    for (int k = 0; k < 16; ++k) {
      float a[4], bb2[4];
      #pragma unroll
      for (int i = 0; i < 4; ++i) a[i] = As[k][ty*4+i];
      #pragma unroll
      for (int j = 0; j < 4; ++j) bb2[j] = Bs[k][tx*4+j];
      #pragma unroll
      for (int i = 0; i < 4; ++i)
        #pragma unroll
        for (int j = 0; j < 4; ++j) acc[i][j] += a[i]*bb2[j];
    }
    __syncthreads();
  }
  #pragma unroll
  for (int i = 0; i < 4; ++i) {
    int gm = bm + ty*4 + i;
    if (gm >= M) continue;
    #pragma unroll
    for (int j = 0; j < 4; ++j) {
      int gn = bn + tx*4 + j;
      if (gn >= N) continue;
      float v = acc[i][j] + (bias ? bias[gn] : 0.f);
      if (RELU) v = fmaxf(v, 0.f);
      C[(size_t)gm*N + gn] = v;
    }
  }
}

// ---------------- fused attention per (b,h): QK^T, softmax, PV ----------------
__global__ __launch_bounds__(256) void attn_kernel(const float* __restrict__ QKV,
    float* __restrict__ O) {
  int b = blockIdx.x >> 3, h = blockIdx.x & 7;
  __shared__ float qs[NNODE][DH+1];
  __shared__ float ks[NNODE][DH+1];
  __shared__ float ps[NNODE][DH+1];
  for (int i = threadIdx.x; i < NNODE*DH; i += 256) {
    int s = i >> 6, d = i & 63;
    size_t base = ((size_t)(s*MG + b))*(3*DD) + h*DH + d;
    qs[s][d] = QKV[base];
    ks[s][d] = QKV[base + DD];
  }
  __syncthreads();
  int lane = threadIdx.x & 63, wv = threadIdx.x >> 6;
  for (int s = wv; s < NNODE; s += 4) {
    float acc = -FLT_MAX;
    if (lane < NNODE) {
      float a = 0.f;
      #pragma unroll
      for (int d = 0; d < DH; ++d) a += qs[s][d]*ks[lane][d];
      acc = a * 0.125f;
    }
    float mx = wave_max(acc);
    float e = (lane < NNODE) ? expf(acc - mx) : 0.f;
    float sm = wave_sum(e);
    ps[s][lane] = e / sm;
  }
  __syncthreads();
  // reuse qs for V
  for (int i = threadIdx.x; i < NNODE*DH; i += 256) {
    int s = i >> 6, d = i & 63;
    qs[s][d] = QKV[((size_t)(s*MG + b))*(3*DD) + 2*DD + h*DH + d];
  }
  __syncthreads();
  for (int s = wv; s < NNODE; s += 4) {
    float acc = 0.f;
    for (int t = 0; t < NNODE; ++t) acc += ps[s][t]*qs[t][lane];
    O[((size_t)(s*MG + b))*DD + h*DH + lane] = acc;
  }
}

// ---------------- X = LayerNorm(X + R) row-wise (512) ----------------
__global__ __launch_bounds__(256) void add_ln_kernel(float* __restrict__ X,
    const float* __restrict__ R, const float* __restrict__ gg, const float* __restrict__ bb) {
  size_t row = blockIdx.x;
  int t = threadIdx.x;
  float v0 = X[row*DD + t] + R[row*DD + t];
  float v1 = X[row*DD + t + 256] + R[row*DD + t + 256];
  __shared__ float red[4];
  float s = wave_sum(v0 + v1);
  int wv = t >> 6, lane = t & 63;
  if (lane == 0) red[wv] = s;
  __syncthreads();
  float mu = (red[0]+red[1]+red[2]+red[3]) * (1.f/DD);
  float d0 = v0 - mu, d1 = v1 - mu;
  float q = wave_sum(d0*d0 + d1*d1);
  __syncthreads();
  if (lane == 0) red[wv] = q;
  __syncthreads();
  float var = (red[0]+red[1]+red[2]+red[3]) * (1.f/DD);
  float rs = rsqrtf(var + EPSV);
  X[row*DD + t] = d0*rs*gg[t] + bb[t];
  X[row*DD + t+256] = d1*rs*gg[t+256] + bb[t+256];
}

// ---------------- graph-structure helpers ----------------
__global__ void fill_int_kernel(int* p, int v, int n) {
  int i = blockIdx.x*256 + threadIdx.x;
  if (i < n) p[i] = v;
}
__global__ void count_deg_kernel(const int* __restrict__ dst, int* deg, int n) {
  int e = blockIdx.x*256 + threadIdx.x;
  if (e < n) atomicAdd(&deg[dst[e]], 1);   // integer: exact, order-free
}
__global__ void dis_kernel(const int* __restrict__ deg, float* dis, int n) {
  int i = blockIdx.x*256+threadIdx.x;
  if (i < n) dis[i] = rsqrtf((float)deg[i]);
}
__global__ void coef0_kernel(const int* __restrict__ src, const int* __restrict__ dst,
                             const float* __restrict__ dis, float* coef) {
  int e = blockIdx.x*256+threadIdx.x;
  if (e < NEDGE) coef[e] = dis[src[e]]*dis[dst[e]];
}
__global__ void coef1_kernel(const int* __restrict__ src, const int* __restrict__ dst,
                             const int* __restrict__ keep,
                             const float* __restrict__ dis, float* coef) {
  int e = blockIdx.x*256+threadIdx.x;
  if (e < NEDGE) coef[e] = keep[e] ? dis[src[e]]*dis[dst[e]] : 0.f;
}

// ---------------- GCN aggregation, in-place on HW = h@W ----------------
// block = 1 wave (64 ch), graph-serial edge loop (deterministic), edges staged in LDS
__global__ __launch_bounds__(64) void gcn_agg_kernel(const int* __restrict__ src,
    const int* __restrict__ dst, const float* __restrict__ coef,
    const float* __restrict__ dis, const float* __restrict__ bias,
    float* __restrict__ HW, int NP, int relu) {
  int g = blockIdx.x >> 3;
  int c0 = (blockIdx.x & 7) * 64;
  int lane = threadIdx.x;
  __shared__ float hs[NNODE][64];
  __shared__ float as[NNODE][64];
  __shared__ int se[EPG], sd[EPG];
  __shared__ float scf[EPG];
  int base = g * NP;
  for (int i = 0; i < NP; ++i) {
    hs[i][lane] = HW[(size_t)(base+i)*DD + c0 + lane];
    as[i][lane] = 0.f;
  }
  int e0 = g * EPG;
  for (int e = lane; e < EPG; e += 64) {
    se[e] = src[e0+e] - base;
    sd[e] = dst[e0+e] - base;
    scf[e] = coef[e0+e];
  }
  __syncthreads();
  for (int e = 0; e < EPG; ++e) {
    float cf = scf[e];
    if (cf != 0.f) as[sd[e]][lane] += cf * hs[se[e]][lane];
  }
  __syncthreads();
  for (int i = 0; i < NP; ++i) {
    float d = dis[base+i]; float d2 = d*d;
    float v = as[i][lane] + hs[i][lane]*d2 + bias[c0+lane];
    if (relu) v = fmaxf(v, 0.f);
    HW[(size_t)(base+i)*DD + c0 + lane] = v;
  }
}

// ---------------- hs[i] = h[i,:] . w  (one wave per node) ----------------
__global__ __launch_bounds__(256) void gemv_kernel(const float* __restrict__ h,
    const float* __restrict__ wv, float* __restrict__ out, int n) {
  int node = blockIdx.x*4 + (threadIdx.x >> 6);
  int lane = threadIdx.x & 63;
  if (node >= n) return;
  const float* row = h + (size_t)node*DD;
  float acc = 0.f;
  for (int d = lane; d < DD; d += 64) acc += row[d]*wv[d];
  acc = wave_sum(acc);
  if (lane == 0) out[node] = acc;
}

// ---------------- SAGPool scalar score: agg + hs*dis^2 + b ----------------
__global__ __launch_bounds__(64) void score_kernel(const int* __restrict__ src,
    const int* __restrict__ dst, const float* __restrict__ coef,
    const float* __restrict__ dis, const float* __restrict__ hsv,
    const float* __restrict__ pb, float* __restrict__ sc, int NP) {
  int g = blockIdx.x;
  int lane = threadIdx.x;
  __shared__ float hss[NNODE], ag[NNODE];
  __shared__ int se[EPG], sd[EPG];
  __shared__ float scf[EPG];
  int base = g*NP;
  if (lane < NP) { hss[lane] = hsv[base+lane]; ag[lane] = 0.f; }
  int e0 = g*EPG;
  for (int e = lane; e < EPG; e += 64) {
    se[e] = src[e0+e]-base; sd[e] = dst[e0+e]-base; scf[e] = coef[e0+e];
  }
  __syncthreads();
  if (lane == 0) {
    for (int e = 0; e < EPG; ++e) {
      float cf = scf[e];
      if (cf != 0.f) ag[sd[e]] += cf*hss[se[e]];
    }
  }
  __syncthreads();
  if (lane < NP) {
    float d = dis[base+lane];
    sc[base+lane] = ag[lane] + hss[lane]*d*d + pb[0];
  }
}

// ---------------- per-graph top-k (descending, min-index tie-break) ----------------
__global__ __launch_bounds__(64) void topk_kernel(const float* __restrict__ sc,
    int* __restrict__ perm, int NP, int KK) {
  int g = blockIdx.x, lane = threadIdx.x;
  float v = (lane < NP) ? sc[g*NP+lane] : -FLT_MAX;
  for (int r = 0; r < KK; ++r) {
    float bv = v; int bi = lane;
    for (int off = 32; off; off >>= 1) {
      float ov = __shfl_xor(bv, off);
      int oi = __shfl_xor(bi, off);
      if (ov > bv || (ov == bv && oi < bi)) { bv = ov; bi = oi; }
    }
    if (lane == 0) perm[g*KK + r] = bi;
    if (lane == bi) v = -FLT_MAX;
  }
}

// ---------------- gather pooled nodes: xn = h[perm] * tanh(score[perm]) ----------------
__global__ __launch_bounds__(256) void gather_kernel(const float* __restrict__ h,
    const float* __restrict__ sc, const int* __restrict__ perm,
    float* __restrict__ xn, int NP, int KK) {
  int j = blockIdx.x;
  int g = j / KK;
  int pi = perm[j];
  float t = tanhf(sc[g*NP + pi]);
  const float* srow = h + (size_t)(g*NP + pi)*DD;
  float* drow = xn + (size_t)j*DD;
  drow[threadIdx.x] = srow[threadIdx.x]*t;
  drow[threadIdx.x+256] = srow[threadIdx.x+256]*t;
}

__global__ void nmap_scatter_kernel(const int* __restrict__ perm, int* __restrict__ nmap) {
  int j = blockIdx.x*256 + threadIdx.x;
  if (j < MG*KP1) nmap[(j/KP1)*NNODE + perm[j]] = j;
}

__global__ void filter_kernel(const int* __restrict__ src0, const int* __restrict__ dst0,
    const int* __restrict__ nmap, int* __restrict__ es, int* __restrict__ ed,
    int* __restrict__ keep, int* __restrict__ deg1) {
  int e = blockIdx.x*256+threadIdx.x;
  if (e >= NEDGE) return;
  int ns = nmap[src0[e]], nd = nmap[dst0[e]];
  int k = (ns >= 0) && (nd >= 0);
  es[e] = k ? ns : 0;
  ed[e] = k ? nd : 0;
  keep[e] = k;
  if (k) atomicAdd(&deg1[nd], 1);
}

// ---------------- readout: gmp || gap, optional accumulate ----------------
__global__ __launch_bounds__(256) void readout_kernel(const float* __restrict__ h,
    float* __restrict__ z, int KK, int acc) {
  int g = blockIdx.x;
  for (int c = threadIdx.x; c < DD; c += 256) {
    float mx = -FLT_MAX, sm = 0.f;
    for (int r = 0; r < KK; ++r) {
      float v = h[(size_t)(g*KK+r)*DD + c];
      mx = fmaxf(mx, v); sm += v;
    }
    float mean = sm / (float)KK;
    if (acc) { z[(size_t)g*1024 + c] += mx; z[(size_t)g*1024 + 512 + c] += mean; }
    else     { z[(size_t)g*1024 + c]  = mx; z[(size_t)g*1024 + 512 + c]  = mean; }
  }
}

extern "C" void kernel_launch(void* const* d_in, const int* in_sizes, int n_in,
                              void* d_out, int out_size, void* d_ws, size_t ws_size,
                              hipStream_t stream) {
  const float* x       = (const float*)d_in[0];
  const int*   edge    = (const int*)d_in[1];
  const float* bn_g    = (const float*)d_in[2];
  const float* bn_b    = (const float*)d_in[3];
  const float* W_emb   = (const float*)d_in[4];
  const float* Wqkv    = (const float*)d_in[5];
  const float* bqkv    = (const float*)d_in[6];
  const float* Wo      = (const float*)d_in[7];
  const float* bo      = (const float*)d_in[8];
  const float* W1      = (const float*)d_in[9];
  const float* b1      = (const float*)d_in[10];
  const float* W2      = (const float*)d_in[11];
  const float* b2      = (const float*)d_in[12];
  const float* g1      = (const float*)d_in[13];
  const float* be1     = (const float*)d_in[14];
  const float* g2      = (const float*)d_in[15];
  const float* be2     = (const float*)d_in[16];
  const float* W_emb1  = (const float*)d_in[17];
  const float* conv1_W = (const float*)d_in[18];
  const float* conv1_b = (const float*)d_in[19];
  const float* convs_W = (const float*)d_in[20];
  const float* convs_b = (const float*)d_in[21];
  const float* pool1_W = (const float*)d_in[22];
  const float* pool1_b = (const float*)d_in[23];
  const float* pool2_W = (const float*)d_in[24];
  const float* pool2_b = (const float*)d_in[25];
  const float* fc1_W   = (const float*)d_in[26];
  const float* fc1_b   = (const float*)d_in[27];
  const float* fc2_W   = (const float*)d_in[28];
  const float* fc2_b   = (const float*)d_in[29];
  const float* fc3_W   = (const float*)d_in[30];
  const float* fc3_b   = (const float*)d_in[31];
  (void)in_sizes; (void)n_in; (void)out_size; (void)ws_size;

  const int* srcp = edge;
  const int* dstp = edge + NEDGE;

  char* wsb = (char*)d_ws;
  size_t off = 0;
  auto alloc = [&](size_t bytes)->void* {
    void* p = wsb + off;
    off += (bytes + 255) & ~(size_t)255;
    return p;
  };
  float* T    = (float*)alloc((size_t)NTOK*DD*4);
  float* TMP1 = (float*)alloc((size_t)NTOK*DD*4);
  float* TMP2 = (float*)alloc((size_t)NTOK*DD*4);
  float* BIG  = (float*)alloc((size_t)NTOK*DFF*4);
  float* XG   = (float*)alloc((size_t)NTOK*NNODE*4);
  float* MU   = (float*)alloc(NNODE*4);
  float* RS   = (float*)alloc(NNODE*4);
  int*   DEG0 = (int*)alloc(NTOK*4);
  float* DIS0 = (float*)alloc(NTOK*4);
  float* COEF0= (float*)alloc(NEDGE*4);
  float* HS   = (float*)alloc(NTOK*4);
  float* SC   = (float*)alloc(NTOK*4);
  int*   PERM1= (int*)alloc(MG*KP1*4);
  int*   NMAP = (int*)alloc(NTOK*4);
  int*   ES1  = (int*)alloc(NEDGE*4);
  int*   ED1  = (int*)alloc(NEDGE*4);
  int*   KEEP1= (int*)alloc(NEDGE*4);
  int*   DEG1 = (int*)alloc(MG*KP1*4);
  float* DIS1 = (float*)alloc(MG*KP1*4);
  float* COEF1= (float*)alloc(NEDGE*4);
  int*   PERM2= (int*)alloc(MG*KP2*4);
  float* Z    = (float*)alloc(MG*1024*4);
  float* Z1   = (float*)alloc(MG*DD*4);
  float* Z2   = (float*)alloc(MG*256*4);

  auto gemm = [&](const float* A, const float* B, const float* bias, float* C,
                  int Mm, int Nn, int Kk, bool relu) {
    dim3 grid((Nn+63)/64, (Mm+63)/64);
    if (relu) gemm_kernel<true><<<grid, 256, 0, stream>>>(A, B, bias, C, Mm, Nn, Kk);
    else      gemm_kernel<false><<<grid, 256, 0, stream>>>(A, B, bias, C, Mm, Nn, Kk);
  };

  // ---- BN + embed ----
  bn_stats_kernel<<<NNODE, 256, 0, stream>>>(x, MU, RS);
  embed_kernel<<<NTOK, 256, 0, stream>>>(x, MU, RS, bn_g, bn_b, W_emb, T);

  // ---- graph structure (independent of features) ----
  fill_int_kernel<<<(NTOK+255)/256, 256, 0, stream>>>(DEG0, 1, NTOK);
  count_deg_kernel<<<(NEDGE+255)/256, 256, 0, stream>>>(dstp, DEG0, NEDGE);
  dis_kernel<<<(NTOK+255)/256, 256, 0, stream>>>(DEG0, DIS0, NTOK);
  coef0_kernel<<<(NEDGE+255)/256, 256, 0, stream>>>(srcp, dstp, DIS0, COEF0);

  // ---- transformer encoder ----
  for (int l = 0; l < NLAYER; ++l) {
    gemm(T, Wqkv + (size_t)l*DD*3*DD, bqkv + (size_t)l*3*DD, BIG, NTOK, 3*DD, DD, false);
    attn_kernel<<<MG*NH, 256, 0, stream>>>(BIG, TMP1);
    gemm(TMP1, Wo + (size_t)l*DD*DD, bo + (size_t)l*DD, TMP2, NTOK, DD, DD, false);
    add_ln_kernel<<<NTOK, 256, 0, stream>>>(T, TMP2, g1 + (size_t)l*DD, be1 + (size_t)l*DD);
    gemm(T, W1 + (size_t)l*DD*DFF, b1 + (size_t)l*DFF, BIG, NTOK, DFF, DD, true);
    gemm(BIG, W2 + (size_t)l*DFF*DD, b2 + (size_t)l*DD, TMP2, NTOK, DD, DFF, false);
    add_ln_kernel<<<NTOK, 256, 0, stream>>>(T, TMP2, g2 + (size_t)l*DD, be2 + (size_t)l*DD);
  }

  // ---- xg (faithful reshape: row order already s*128+b) ----
  gemm(T, W_emb1, nullptr, XG, NTOK, NNODE, DD, false);

  // ---- conv1 + relu ----
  gemm(XG, conv1_W, nullptr, TMP1, NTOK, DD, NNODE, false);
  gcn_agg_kernel<<<MG*8, 64, 0, stream>>>(srcp, dstp, COEF0, DIS0, conv1_b, TMP1, NNODE, 1);

  // ---- SAGPool 1 ----
  gemv_kernel<<<(NTOK+3)/4, 256, 0, stream>>>(TMP1, pool1_W, HS, NTOK);
  score_kernel<<<MG, 64, 0, stream>>>(srcp, dstp, COEF0, DIS0, HS, pool1_b, SC, NNODE);
  topk_kernel<<<MG, 64, 0, stream>>>(SC, PERM1, NNODE, KP1);
  gather_kernel<<<MG*KP1, 256, 0, stream>>>(TMP1, SC, PERM1, TMP2, NNODE, KP1);
  readout_kernel<<<MG, 256, 0, stream>>>(TMP2, Z, KP1, 0);

  // ---- filter_adj ----
  fill_int_kernel<<<(NTOK+255)/256, 256, 0, stream>>>(NMAP, -1, NTOK);
  nmap_scatter_kernel<<<(MG*KP1+255)/256, 256, 0, stream>>>(PERM1, NMAP);
  fill_int_kernel<<<(MG*KP1+255)/256, 256, 0, stream>>>(DEG1, 1, MG*KP1);
  filter_kernel<<<(NEDGE+255)/256, 256, 0, stream>>>(srcp, dstp, NMAP, ES1, ED1, KEEP1, DEG1);
  dis_kernel<<<(MG*KP1+255)/256, 256, 0, stream>>>(DEG1, DIS1, MG*KP1);
  coef1_kernel<<<(NEDGE+255)/256, 256, 0, stream>>>(ES1, ED1, KEEP1, DIS1, COEF1);

  // ---- 3 GCN layers on pooled graph (ping-pong TMP2 <-> TMP1) ----
  const float* hin = TMP2; float* hout = TMP1;
  for (int l = 0; l < NLAYER-1; ++l) {
    gemm(hin, convs_W + (size_t)l*DD*DD, nullptr, hout, MG*KP1, DD, DD, false);
    gcn_agg_kernel<<<MG*8, 64, 0, stream>>>(ES1, ED1, COEF1, DIS1, convs_b + (size_t)l*DD, hout, KP1, 1);
    const float* t2 = hin; hin = hout; hout = (float*)t2;
  }
  // hin == TMP1 (final h), hout == TMP2 (free)

  // ---- SAGPool 2 (edges not needed afterwards) ----
  gemv_kernel<<<(MG*KP1+3)/4, 256, 0, stream>>>(hin, pool2_W, HS, MG*KP1);
  score_kernel<<<MG, 64, 0, stream>>>(ES1, ED1, COEF1, DIS1, HS, pool2_b, SC, KP1);
  topk_kernel<<<MG, 64, 0, stream>>>(SC, PERM2, KP1, KP2);
  gather_kernel<<<MG*KP2, 256, 0, stream>>>(hin, SC, PERM2, hout, KP1, KP2);
  readout_kernel<<<MG, 256, 0, stream>>>(hout, Z, KP2, 1);  // z = x1 + x2

  // ---- MLP head ----
  gemm(Z,  fc1_W, fc1_b, Z1, MG, DD,   2*DD, true);
  gemm(Z1, fc2_W, fc2_b, Z2, MG, DD/2, DD,   true);
  gemm(Z2, fc3_W, fc3_b, (float*)d_out, MG, 2, DD/2, false);
}

// Round 2
// 2551.798 us; speedup vs baseline: 2.5844x; 2.5844x over previous
//
#include <hip/hip_runtime.h>
#include <float.h>
#include <math.h>

#define MG 128
#define NNODE 62
#define DD 512
#define NH 8
#define DH 64
#define DFF 2048
#define NLAYER 4
#define EPG 600
#define KP1 50
#define KP2 40
#define NTOK (MG*NNODE)      // 7936
#define NEDGE (MG*EPG)       // 76800
#define EPSV 1e-5f

typedef unsigned short u16;
using bf16x8 = __attribute__((ext_vector_type(8))) short;
using f32x4  = __attribute__((ext_vector_type(4))) float;

__device__ __forceinline__ float wave_sum(float v) {
  for (int off = 32; off; off >>= 1) v += __shfl_xor(v, off);
  return v;
}
__device__ __forceinline__ float wave_max(float v) {
  for (int off = 32; off; off >>= 1) v = fmaxf(v, __shfl_xor(v, off));
  return v;
}
__device__ __forceinline__ u16 f2b(float x) {
  union { float f; unsigned u; } v; v.f = x;
  unsigned r = v.u + 0x7fffu + ((v.u >> 16) & 1u);
  return (u16)(r >> 16);
}
__device__ __forceinline__ float b2f(u16 h) {
  union { float f; unsigned u; } v; v.u = ((unsigned)h) << 16;
  return v.f;
}
__device__ __forceinline__ void f2bsplit(float x, u16& h, u16& l) {
  h = f2b(x);
  l = f2b(x - b2f(h));
}

// ---------------- BatchNorm stats ----------------
__global__ __launch_bounds__(256) void bn_stats_kernel(const float* __restrict__ x,
    float* __restrict__ mu, float* __restrict__ rs) {
  int s = blockIdx.x;
  float sum = 0.f, sq = 0.f;
  for (int i = threadIdx.x; i < MG*NNODE; i += 256) {
    int b = i / NNODE, j = i - b*NNODE;
    float v = x[(size_t)(b*NNODE + s)*NNODE + j];
    sum += v; sq += v*v;
  }
  __shared__ float r1[4], r2[4];
  sum = wave_sum(sum); sq = wave_sum(sq);
  int wv = threadIdx.x >> 6, lane = threadIdx.x & 63;
  if (lane == 0) { r1[wv] = sum; r2[wv] = sq; }
  __syncthreads();
  if (threadIdx.x == 0) {
    float S = r1[0]+r1[1]+r1[2]+r1[3];
    float Q = r2[0]+r2[1]+r2[2]+r2[3];
    float m = S / (float)(MG*NNODE);
    float var = Q / (float)(MG*NNODE) - m*m;
    mu[s] = m;
    rs[s] = rsqrtf(var + EPSV);
  }
}

// ---------------- embed: T fp32 + split bf16 ----------------
__global__ __launch_bounds__(256) void embed_kernel(const float* __restrict__ x,
    const float* __restrict__ mu, const float* __restrict__ rs,
    const float* __restrict__ gg, const float* __restrict__ bb,
    const float* __restrict__ W, float* __restrict__ T,
    u16* __restrict__ Th, u16* __restrict__ Tl) {
  int tok = blockIdx.x;
  int s = tok >> 7, b = tok & 127;
  __shared__ float xb[NNODE];
  if (threadIdx.x < NNODE) {
    float v = x[(size_t)(b*NNODE + s)*NNODE + threadIdx.x];
    xb[threadIdx.x] = (v - mu[s]) * rs[s] * gg[s] + bb[s];
  }
  __syncthreads();
  int d = threadIdx.x;
  float a0 = 0.f, a1 = 0.f;
  for (int j = 0; j < NNODE; ++j) {
    float xv = xb[j];
    a0 += xv * W[(size_t)j*DD + d];
    a1 += xv * W[(size_t)j*DD + d + 256];
  }
  size_t o = (size_t)tok*DD + d;
  T[o] = a0; T[o+256] = a1;
  u16 h, l;
  f2bsplit(a0, h, l); Th[o] = h; Tl[o] = l;
  f2bsplit(a1, h, l); Th[o+256] = h; Tl[o+256] = l;
}

// ---------------- fp32 GEMM (small: fc layers only) ----------------
template<bool RELU>
__global__ __launch_bounds__(256) void gemm_kernel(const float* __restrict__ A,
    const float* __restrict__ B, const float* __restrict__ bias, float* __restrict__ C,
    int M, int N, int K) {
  __shared__ float As[16][68];
  __shared__ float Bs[16][68];
  int bm = blockIdx.y * 64, bn = blockIdx.x * 64;
  int tid = threadIdx.x;
  int tx = tid & 15, ty = tid >> 4;
  float acc[4][4] = {};
  for (int k0 = 0; k0 < K; k0 += 16) {
    {
      int row = tid >> 2; int kk = (tid & 3) * 4;
      int gm = bm + row;
      #pragma unroll
      for (int i = 0; i < 4; ++i) {
        int gk = k0 + kk + i;
        As[kk+i][row] = (gm < M && gk < K) ? A[(size_t)gm*K + gk] : 0.f;
      }
    }
    {
      int krow = tid >> 4; int nn = (tid & 15) * 4;
      int gk = k0 + krow;
      #pragma unroll
      for (int i = 0; i < 4; ++i) {
        int gn = bn + nn + i;
        Bs[krow][nn+i] = (gk < K && gn < N) ? B[(size_t)gk*N + gn] : 0.f;
      }
    }
    __syncthreads();
    #pragma unroll
    for (int k = 0; k < 16; ++k) {
      float a[4], bb2[4];
      #pragma unroll
      for (int i = 0; i < 4; ++i) a[i] = As[k][ty*4+i];
      #pragma unroll
      for (int j = 0; j < 4; ++j) bb2[j] = Bs[k][tx*4+j];
      #pragma unroll
      for (int i = 0; i < 4; ++i)
        #pragma unroll
        for (int j = 0; j < 4; ++j) acc[i][j] += a[i]*bb2[j];
    }
    __syncthreads();
  }
  #pragma unroll
  for (int i = 0; i < 4; ++i) {
    int gm = bm + ty*4 + i;
    if (gm >= M) continue;
    #pragma unroll
    for (int j = 0; j < 4; ++j) {
      int gn = bn + tx*4 + j;
      if (gn >= N) continue;
      float v = acc[i][j] + (bias ? bias[gn] : 0.f);
      if (RELU) v = fmaxf(v, 0.f);
      C[(size_t)gm*N + gn] = v;
    }
  }
}

// ---------------- weight transpose + split: W[K][N] fp32 -> WT hi/lo [Npad][Kp] bf16 ----------------
__global__ __launch_bounds__(256) void convT_kernel(const float* __restrict__ W,
    u16* __restrict__ WTh, u16* __restrict__ WTl, int K, int N, int Npad, int Kp) {
  __shared__ float t[64][65];
  int k0 = blockIdx.y*64, n0 = blockIdx.x*64;
  for (int i = threadIdx.x; i < 64*64; i += 256) {
    int r = i >> 6, c = i & 63;
    int gk = k0 + r, gn = n0 + c;
    t[r][c] = (gk < K && gn < N) ? W[(size_t)gk*N + gn] : 0.f;
  }
  __syncthreads();
  for (int i = threadIdx.x; i < 64*64; i += 256) {
    int r = i >> 6, c = i & 63;
    int gn = n0 + r, gk = k0 + c;
    if (gn < Npad && gk < Kp) {
      u16 h, l; f2bsplit(t[c][r], h, l);
      WTh[(size_t)gn*Kp + gk] = h;
      WTl[(size_t)gn*Kp + gk] = l;
    }
  }
}

// ---------------- split-bf16 MFMA GEMM: C = (Ah+Al) @ (Bh+Bl)^T ----------------
// A hi/lo: [M][Kp] bf16, BT hi/lo: [Npad][Kp] bf16 (Npad = gridDim.x*128, zero-padded)
// 128x128 tile, 4 waves of 64x64, BK=32, 3 MFMA per fragment pair (hh, hl, lh)
// OUTMODE 0: fp32 C[M][Nstride] (Nstride==Nreal); 1: split-bf16 Ch/Cl, pad cols zeroed
template<bool RELU, int OUTMODE>
__global__ __launch_bounds__(256) void gemm3_kernel(
    const u16* __restrict__ Ah, const u16* __restrict__ Al,
    const u16* __restrict__ Bh, const u16* __restrict__ Bl,
    const float* __restrict__ bias,
    float* __restrict__ Cf, u16* __restrict__ Ch, u16* __restrict__ Cl,
    int Nreal, int Nstride, int Kp) {
  __shared__ u16 As[2][128][40];
  __shared__ u16 Bs[2][128][40];
  int bm = blockIdx.y * 128, bn = blockIdx.x * 128;
  int tid = threadIdx.x;
  int wv = tid >> 6, lane = tid & 63;
  int wr = (wv >> 1) * 64, wc = (wv & 1) * 64;
  f32x4 acc[4][4];
  #pragma unroll
  for (int i = 0; i < 4; ++i)
    #pragma unroll
    for (int j = 0; j < 4; ++j) acc[i][j] = (f32x4){0.f,0.f,0.f,0.f};

  int srow = tid >> 2, sko = (tid & 3) * 8;       // chunk 0
  int srow1 = (tid + 256) >> 2, sko1 = ((tid + 256) & 3) * 8;
  int fr = lane & 15, fo = (lane >> 4) * 8;

  for (int k0 = 0; k0 < Kp; k0 += 32) {
    size_t ga0 = (size_t)(bm + srow)*Kp + k0 + sko;
    size_t ga1 = (size_t)(bm + srow1)*Kp + k0 + sko1;
    size_t gb0 = (size_t)(bn + srow)*Kp + k0 + sko;
    size_t gb1 = (size_t)(bn + srow1)*Kp + k0 + sko1;
    *(bf16x8*)&As[0][srow ][sko ] = *(const bf16x8*)(Ah + ga0);
    *(bf16x8*)&As[0][srow1][sko1] = *(const bf16x8*)(Ah + ga1);
    *(bf16x8*)&As[1][srow ][sko ] = *(const bf16x8*)(Al + ga0);
    *(bf16x8*)&As[1][srow1][sko1] = *(const bf16x8*)(Al + ga1);
    *(bf16x8*)&Bs[0][srow ][sko ] = *(const bf16x8*)(Bh + gb0);
    *(bf16x8*)&Bs[0][srow1][sko1] = *(const bf16x8*)(Bh + gb1);
    *(bf16x8*)&Bs[1][srow ][sko ] = *(const bf16x8*)(Bl + gb0);
    *(bf16x8*)&Bs[1][srow1][sko1] = *(const bf16x8*)(Bl + gb1);
    __syncthreads();
    bf16x8 ah[4], al[4], bh[4], bl[4];
    #pragma unroll
    for (int i = 0; i < 4; ++i) {
      ah[i] = *(const bf16x8*)&As[0][wr + i*16 + fr][fo];
      al[i] = *(const bf16x8*)&As[1][wr + i*16 + fr][fo];
      bh[i] = *(const bf16x8*)&Bs[0][wc + i*16 + fr][fo];
      bl[i] = *(const bf16x8*)&Bs[1][wc + i*16 + fr][fo];
    }
    #pragma unroll
    for (int i = 0; i < 4; ++i)
      #pragma unroll
      for (int j = 0; j < 4; ++j) {
        acc[i][j] = __builtin_amdgcn_mfma_f32_16x16x32_bf16(ah[i], bh[j], acc[i][j], 0, 0, 0);
        acc[i][j] = __builtin_amdgcn_mfma_f32_16x16x32_bf16(ah[i], bl[j], acc[i][j], 0, 0, 0);
        acc[i][j] = __builtin_amdgcn_mfma_f32_16x16x32_bf16(al[i], bh[j], acc[i][j], 0, 0, 0);
      }
    __syncthreads();
  }
  // epilogue: C/D layout col=lane&15, row=(lane>>4)*4+reg
  int cr = (lane >> 4) * 4, cc = lane & 15;
  #pragma unroll
  for (int i = 0; i < 4; ++i) {
    #pragma unroll
    for (int j = 0; j < 4; ++j) {
      int gn = bn + wc + j*16 + cc;
      if (gn >= Nstride) continue;
      #pragma unroll
      for (int q = 0; q < 4; ++q) {
        int gm = bm + wr + i*16 + cr + q;
        float v = acc[i][j][q];
        if (gn < Nreal) { if (bias) v += bias[gn]; } else v = 0.f;
        if (RELU) v = fmaxf(v, 0.f);
        size_t o = (size_t)gm*Nstride + gn;
        if (OUTMODE == 0) {
          Cf[o] = v;
        } else {
          u16 h, l; f2bsplit(v, h, l);
          Ch[o] = h; Cl[o] = l;
        }
      }
    }
  }
}

// ---------------- fused attention per (b,h): fp32, writes split-bf16 O ----------------
__global__ __launch_bounds__(256) void attn_kernel(const float* __restrict__ QKV,
    u16* __restrict__ Oh, u16* __restrict__ Ol) {
  int b = blockIdx.x >> 3, h = blockIdx.x & 7;
  __shared__ float qs[NNODE][DH+1];
  __shared__ float ks[NNODE][DH+1];
  __shared__ float ps[NNODE][DH+1];
  for (int i = threadIdx.x; i < NNODE*DH; i += 256) {
    int s = i >> 6, d = i & 63;
    size_t base = ((size_t)(s*MG + b))*(3*DD) + h*DH + d;
    qs[s][d] = QKV[base];
    ks[s][d] = QKV[base + DD];
  }
  __syncthreads();
  int lane = threadIdx.x & 63, wv = threadIdx.x >> 6;
  for (int s = wv; s < NNODE; s += 4) {
    float acc = -FLT_MAX;
    if (lane < NNODE) {
      float a = 0.f;
      #pragma unroll
      for (int d = 0; d < DH; ++d) a += qs[s][d]*ks[lane][d];
      acc = a * 0.125f;
    }
    float mx = wave_max(acc);
    float e = (lane < NNODE) ? expf(acc - mx) : 0.f;
    float sm = wave_sum(e);
    ps[s][lane] = e / sm;
  }
  __syncthreads();
  for (int i = threadIdx.x; i < NNODE*DH; i += 256) {
    int s = i >> 6, d = i & 63;
    qs[s][d] = QKV[((size_t)(s*MG + b))*(3*DD) + 2*DD + h*DH + d];
  }
  __syncthreads();
  for (int s = wv; s < NNODE; s += 4) {
    float acc = 0.f;
    for (int t = 0; t < NNODE; ++t) acc += ps[s][t]*qs[t][lane];
    size_t o = ((size_t)(s*MG + b))*DD + h*DH + lane;
    u16 hh, ll; f2bsplit(acc, hh, ll);
    Oh[o] = hh; Ol[o] = ll;
  }
}

// ---------------- X = LayerNorm(X + R), writes fp32 + split bf16 ----------------
__global__ __launch_bounds__(256) void add_ln_kernel(float* __restrict__ X,
    const float* __restrict__ R, const float* __restrict__ gg, const float* __restrict__ bb,
    u16* __restrict__ Xh, u16* __restrict__ Xl) {
  size_t row = blockIdx.x;
  int t = threadIdx.x;
  float v0 = X[row*DD + t] + R[row*DD + t];
  float v1 = X[row*DD + t + 256] + R[row*DD + t + 256];
  __shared__ float red[4];
  float s = wave_sum(v0 + v1);
  int wv = t >> 6, lane = t & 63;
  if (lane == 0) red[wv] = s;
  __syncthreads();
  float mu = (red[0]+red[1]+red[2]+red[3]) * (1.f/DD);
  float d0 = v0 - mu, d1 = v1 - mu;
  float q = wave_sum(d0*d0 + d1*d1);
  __syncthreads();
  if (lane == 0) red[wv] = q;
  __syncthreads();
  float var = (red[0]+red[1]+red[2]+red[3]) * (1.f/DD);
  float rs = rsqrtf(var + EPSV);
  float o0 = d0*rs*gg[t] + bb[t];
  float o1 = d1*rs*gg[t+256] + bb[t+256];
  X[row*DD + t] = o0;
  X[row*DD + t+256] = o1;
  u16 h, l;
  f2bsplit(o0, h, l); Xh[row*DD + t] = h; Xl[row*DD + t] = l;
  f2bsplit(o1, h, l); Xh[row*DD + t+256] = h; Xl[row*DD + t+256] = l;
}

// ---------------- graph-structure helpers ----------------
__global__ void fill_int_kernel(int* p, int v, int n) {
  int i = blockIdx.x*256 + threadIdx.x;
  if (i < n) p[i] = v;
}
__global__ void count_deg_kernel(const int* __restrict__ dst, int* deg, int n) {
  int e = blockIdx.x*256 + threadIdx.x;
  if (e < n) atomicAdd(&deg[dst[e]], 1);
}
__global__ void dis_kernel(const int* __restrict__ deg, float* dis, int n) {
  int i = blockIdx.x*256+threadIdx.x;
  if (i < n) dis[i] = rsqrtf((float)deg[i]);
}
__global__ void coef0_kernel(const int* __restrict__ src, const int* __restrict__ dst,
                             const float* __restrict__ dis, float* coef) {
  int e = blockIdx.x*256+threadIdx.x;
  if (e < NEDGE) coef[e] = dis[src[e]]*dis[dst[e]];
}
__global__ void coef1_kernel(const int* __restrict__ src, const int* __restrict__ dst,
                             const int* __restrict__ keep,
                             const float* __restrict__ dis, float* coef) {
  int e = blockIdx.x*256+threadIdx.x;
  if (e < NEDGE) coef[e] = keep[e] ? dis[src[e]]*dis[dst[e]] : 0.f;
}

// ---------------- GCN aggregation in-place; optional split-bf16 copy ----------------
__global__ __launch_bounds__(64) void gcn_agg_kernel(const int* __restrict__ src,
    const int* __restrict__ dst, const float* __restrict__ coef,
    const float* __restrict__ dis, const float* __restrict__ bias,
    float* __restrict__ HW, int NP, int relu,
    u16* __restrict__ outh, u16* __restrict__ outl) {
  int g = blockIdx.x >> 3;
  int c0 = (blockIdx.x & 7) * 64;
  int lane = threadIdx.x;
  __shared__ float hs[NNODE][64];
  __shared__ float as[NNODE][64];
  __shared__ int se[EPG], sd[EPG];
  __shared__ float scf[EPG];
  int base = g * NP;
  for (int i = 0; i < NP; ++i) {
    hs[i][lane] = HW[(size_t)(base+i)*DD + c0 + lane];
    as[i][lane] = 0.f;
  }
  int e0 = g * EPG;
  for (int e = lane; e < EPG; e += 64) {
    se[e] = src[e0+e] - base;
    sd[e] = dst[e0+e] - base;
    scf[e] = coef[e0+e];
  }
  __syncthreads();
  for (int e = 0; e < EPG; ++e) {
    float cf = scf[e];
    if (cf != 0.f) as[sd[e]][lane] += cf * hs[se[e]][lane];
  }
  __syncthreads();
  for (int i = 0; i < NP; ++i) {
    float d = dis[base+i]; float d2 = d*d;
    float v = as[i][lane] + hs[i][lane]*d2 + bias[c0+lane];
    if (relu) v = fmaxf(v, 0.f);
    size_t o = (size_t)(base+i)*DD + c0 + lane;
    HW[o] = v;
    if (outh) { u16 h, l; f2bsplit(v, h, l); outh[o] = h; outl[o] = l; }
  }
}

// ---------------- gemv: hs[i] = h[i,:] . w ----------------
__global__ __launch_bounds__(256) void gemv_kernel(const float* __restrict__ h,
    const float* __restrict__ wv, float* __restrict__ out, int n) {
  int node = blockIdx.x*4 + (threadIdx.x >> 6);
  int lane = threadIdx.x & 63;
  if (node >= n) return;
  const float* row = h + (size_t)node*DD;
  float acc = 0.f;
  for (int d = lane; d < DD; d += 64) acc += row[d]*wv[d];
  acc = wave_sum(acc);
  if (lane == 0) out[node] = acc;
}

// ---------------- SAGPool scalar score ----------------
__global__ __launch_bounds__(64) void score_kernel(const int* __restrict__ src,
    const int* __restrict__ dst, const float* __restrict__ coef,
    const float* __restrict__ dis, const float* __restrict__ hsv,
    const float* __restrict__ pb, float* __restrict__ sc, int NP) {
  int g = blockIdx.x;
  int lane = threadIdx.x;
  __shared__ float hss[NNODE], ag[NNODE];
  __shared__ int se[EPG], sd[EPG];
  __shared__ float scf[EPG];
  int base = g*NP;
  if (lane < NP) { hss[lane] = hsv[base+lane]; ag[lane] = 0.f; }
  int e0 = g*EPG;
  for (int e = lane; e < EPG; e += 64) {
    se[e] = src[e0+e]-base; sd[e] = dst[e0+e]-base; scf[e] = coef[e0+e];
  }
  __syncthreads();
  if (lane == 0) {
    for (int e = 0; e < EPG; ++e) {
      float cf = scf[e];
      if (cf != 0.f) ag[sd[e]] += cf*hss[se[e]];
    }
  }
  __syncthreads();
  if (lane < NP) {
    float d = dis[base+lane];
    sc[base+lane] = ag[lane] + hss[lane]*d*d + pb[0];
  }
}

// ---------------- per-graph top-k ----------------
__global__ __launch_bounds__(64) void topk_kernel(const float* __restrict__ sc,
    int* __restrict__ perm, int NP, int KK) {
  int g = blockIdx.x, lane = threadIdx.x;
  float v = (lane < NP) ? sc[g*NP+lane] : -FLT_MAX;
  for (int r = 0; r < KK; ++r) {
    float bv = v; int bi = lane;
    for (int off = 32; off; off >>= 1) {
      float ov = __shfl_xor(bv, off);
      int oi = __shfl_xor(bi, off);
      if (ov > bv || (ov == bv && oi < bi)) { bv = ov; bi = oi; }
    }
    if (lane == 0) perm[g*KK + r] = bi;
    if (lane == bi) v = -FLT_MAX;
  }
}

// ---------------- gather pooled: xn = h[perm]*tanh(score[perm]); optional bf16 copy ----------------
__global__ __launch_bounds__(256) void gather_kernel(const float* __restrict__ h,
    const float* __restrict__ sc, const int* __restrict__ perm,
    float* __restrict__ xn, u16* __restrict__ outh, u16* __restrict__ outl,
    int NP, int KK) {
  int j = blockIdx.x;
  int g = j / KK;
  int pi = perm[j];
  float t = tanhf(sc[g*NP + pi]);
  const float* srow = h + (size_t)(g*NP + pi)*DD;
  size_t o = (size_t)j*DD + threadIdx.x;
  float v0 = srow[threadIdx.x]*t;
  float v1 = srow[threadIdx.x+256]*t;
  xn[o] = v0; xn[o+256] = v1;
  if (outh) {
    u16 hh, ll;
    f2bsplit(v0, hh, ll); outh[o] = hh; outl[o] = ll;
    f2bsplit(v1, hh, ll); outh[o+256] = hh; outl[o+256] = ll;
  }
}

__global__ void nmap_scatter_kernel(const int* __restrict__ perm, int* __restrict__ nmap) {
  int j = blockIdx.x*256 + threadIdx.x;
  if (j < MG*KP1) nmap[(j/KP1)*NNODE + perm[j]] = j;
}

__global__ void filter_kernel(const int* __restrict__ src0, const int* __restrict__ dst0,
    const int* __restrict__ nmap, int* __restrict__ es, int* __restrict__ ed,
    int* __restrict__ keep, int* __restrict__ deg1) {
  int e = blockIdx.x*256+threadIdx.x;
  if (e >= NEDGE) return;
  int ns = nmap[src0[e]], nd = nmap[dst0[e]];
  int k = (ns >= 0) && (nd >= 0);
  es[e] = k ? ns : 0;
  ed[e] = k ? nd : 0;
  keep[e] = k;
  if (k) atomicAdd(&deg1[nd], 1);
}

// ---------------- readout: gmp || gap ----------------
__global__ __launch_bounds__(256) void readout_kernel(const float* __restrict__ h,
    float* __restrict__ z, int KK, int acc) {
  int g = blockIdx.x;
  for (int c = threadIdx.x; c < DD; c += 256) {
    float mx = -FLT_MAX, sm = 0.f;
    for (int r = 0; r < KK; ++r) {
      float v = h[(size_t)(g*KK+r)*DD + c];
      mx = fmaxf(mx, v); sm += v;
    }
    float mean = sm / (float)KK;
    if (acc) { z[(size_t)g*1024 + c] += mx; z[(size_t)g*1024 + 512 + c] += mean; }
    else     { z[(size_t)g*1024 + c]  = mx; z[(size_t)g*1024 + 512 + c]  = mean; }
  }
}

extern "C" void kernel_launch(void* const* d_in, const int* in_sizes, int n_in,
                              void* d_out, int out_size, void* d_ws, size_t ws_size,
                              hipStream_t stream) {
  const float* x       = (const float*)d_in[0];
  const int*   edge    = (const int*)d_in[1];
  const float* bn_g    = (const float*)d_in[2];
  const float* bn_b    = (const float*)d_in[3];
  const float* W_emb   = (const float*)d_in[4];
  const float* Wqkv    = (const float*)d_in[5];
  const float* bqkv    = (const float*)d_in[6];
  const float* Wo      = (const float*)d_in[7];
  const float* bo      = (const float*)d_in[8];
  const float* W1      = (const float*)d_in[9];
  const float* b1      = (const float*)d_in[10];
  const float* W2      = (const float*)d_in[11];
  const float* b2      = (const float*)d_in[12];
  const float* g1      = (const float*)d_in[13];
  const float* be1     = (const float*)d_in[14];
  const float* g2      = (const float*)d_in[15];
  const float* be2     = (const float*)d_in[16];
  const float* W_emb1  = (const float*)d_in[17];
  const float* conv1_W = (const float*)d_in[18];
  const float* conv1_b = (const float*)d_in[19];
  const float* convs_W = (const float*)d_in[20];
  const float* convs_b = (const float*)d_in[21];
  const float* pool1_W = (const float*)d_in[22];
  const float* pool1_b = (const float*)d_in[23];
  const float* pool2_W = (const float*)d_in[24];
  const float* pool2_b = (const float*)d_in[25];
  const float* fc1_W   = (const float*)d_in[26];
  const float* fc1_b   = (const float*)d_in[27];
  const float* fc2_W   = (const float*)d_in[28];
  const float* fc2_b   = (const float*)d_in[29];
  const float* fc3_W   = (const float*)d_in[30];
  const float* fc3_b   = (const float*)d_in[31];
  (void)in_sizes; (void)n_in; (void)out_size; (void)ws_size;

  const int* srcp = edge;
  const int* dstp = edge + NEDGE;

  char* wsb = (char*)d_ws;
  size_t off = 0;
  auto alloc = [&](size_t bytes)->void* {
    void* p = wsb + off;
    off += (bytes + 255) & ~(size_t)255;
    return p;
  };
  float* T    = (float*)alloc((size_t)NTOK*DD*4);
  float* TMP1 = (float*)alloc((size_t)NTOK*DD*4);
  float* TMP2 = (float*)alloc((size_t)NTOK*DD*4);
  // union: QKV fp32 out (48.7MB) OR FFN1 split-bf16 out (65MB)
  size_t qkvB = (size_t)NTOK*3*DD*4, ffnB = (size_t)NTOK*DFF*2*2;
  char* BIGU  = (char*)alloc(qkvB > ffnB ? qkvB : ffnB);
  float* QKVf = (float*)BIGU;
  u16* BIGh   = (u16*)BIGU;
  u16* BIGl   = BIGh + (size_t)NTOK*DFF;
  u16* Th   = (u16*)alloc((size_t)NTOK*DD*2);
  u16* Tl   = (u16*)alloc((size_t)NTOK*DD*2);
  u16* ATh  = (u16*)alloc((size_t)NTOK*DD*2);
  u16* ATl  = (u16*)alloc((size_t)NTOK*DD*2);
  u16* XGh  = (u16*)alloc((size_t)NTOK*64*2);
  u16* XGl  = (u16*)alloc((size_t)NTOK*64*2);
  u16* Hh   = (u16*)alloc((size_t)MG*KP1*DD*2);
  u16* Hl   = (u16*)alloc((size_t)MG*KP1*DD*2);
  u16* WTh  = (u16*)alloc((size_t)1048576*2);   // max 2048x512 / 512x2048
  u16* WTl  = (u16*)alloc((size_t)1048576*2);
  u16* E1h  = (u16*)alloc((size_t)128*512*2);
  u16* E1l  = (u16*)alloc((size_t)128*512*2);
  u16* C1h  = (u16*)alloc((size_t)512*64*2);
  u16* C1l  = (u16*)alloc((size_t)512*64*2);
  float* MU   = (float*)alloc(NNODE*4);
  float* RS   = (float*)alloc(NNODE*4);
  int*   DEG0 = (int*)alloc(NTOK*4);
  float* DIS0 = (float*)alloc(NTOK*4);
  float* COEF0= (float*)alloc(NEDGE*4);
  float* HS   = (float*)alloc(NTOK*4);
  float* SC   = (float*)alloc(NTOK*4);
  int*   PERM1= (int*)alloc(MG*KP1*4);
  int*   NMAP = (int*)alloc(NTOK*4);
  int*   ES1  = (int*)alloc(NEDGE*4);
  int*   ED1  = (int*)alloc(NEDGE*4);
  int*   KEEP1= (int*)alloc(NEDGE*4);
  int*   DEG1 = (int*)alloc(MG*KP1*4);
  float* DIS1 = (float*)alloc(MG*KP1*4);
  float* COEF1= (float*)alloc(NEDGE*4);
  int*   PERM2= (int*)alloc(MG*KP2*4);
  float* Z    = (float*)alloc(MG*1024*4);
  float* Z1   = (float*)alloc(MG*DD*4);
  float* Z2   = (float*)alloc(MG*256*4);

  auto gemmf = [&](const float* A, const float* B, const float* bias, float* C,
                   int Mm, int Nn, int Kk, bool relu) {
    dim3 grid((Nn+63)/64, (Mm+63)/64);
    if (relu) gemm_kernel<true><<<grid, 256, 0, stream>>>(A, B, bias, C, Mm, Nn, Kk);
    else      gemm_kernel<false><<<grid, 256, 0, stream>>>(A, B, bias, C, Mm, Nn, Kk);
  };
  auto convT = [&](const float* W, u16* th, u16* tl, int K, int N, int Npad, int Kp) {
    convT_kernel<<<dim3((Npad+63)/64, (Kp+63)/64), 256, 0, stream>>>(W, th, tl, K, N, Npad, Kp);
  };

  // ---- BN + embed ----
  bn_stats_kernel<<<NNODE, 256, 0, stream>>>(x, MU, RS);
  embed_kernel<<<NTOK, 256, 0, stream>>>(x, MU, RS, bn_g, bn_b, W_emb, T, Th, Tl);

  // ---- graph structure ----
  fill_int_kernel<<<(NTOK+255)/256, 256, 0, stream>>>(DEG0, 1, NTOK);
  count_deg_kernel<<<(NEDGE+255)/256, 256, 0, stream>>>(dstp, DEG0, NEDGE);
  dis_kernel<<<(NTOK+255)/256, 256, 0, stream>>>(DEG0, DIS0, NTOK);
  coef0_kernel<<<(NEDGE+255)/256, 256, 0, stream>>>(srcp, dstp, DIS0, COEF0);

  // ---- transformer encoder ----
  for (int l = 0; l < NLAYER; ++l) {
    convT(Wqkv + (size_t)l*DD*3*DD, WTh, WTl, DD, 3*DD, 3*DD, DD);
    gemm3_kernel<false,0><<<dim3(12,62), 256, 0, stream>>>(Th, Tl, WTh, WTl,
        bqkv + (size_t)l*3*DD, QKVf, nullptr, nullptr, 3*DD, 3*DD, DD);
    attn_kernel<<<MG*NH, 256, 0, stream>>>(QKVf, ATh, ATl);
    convT(Wo + (size_t)l*DD*DD, WTh, WTl, DD, DD, DD, DD);
    gemm3_kernel<false,0><<<dim3(4,62), 256, 0, stream>>>(ATh, ATl, WTh, WTl,
        bo + (size_t)l*DD, TMP2, nullptr, nullptr, DD, DD, DD);
    add_ln_kernel<<<NTOK, 256, 0, stream>>>(T, TMP2, g1 + (size_t)l*DD, be1 + (size_t)l*DD, Th, Tl);
    convT(W1 + (size_t)l*DD*DFF, WTh, WTl, DD, DFF, DFF, DD);
    gemm3_kernel<true,1><<<dim3(16,62), 256, 0, stream>>>(Th, Tl, WTh, WTl,
        b1 + (size_t)l*DFF, nullptr, BIGh, BIGl, DFF, DFF, DD);
    convT(W2 + (size_t)l*DFF*DD, WTh, WTl, DFF, DD, DD, DFF);
    gemm3_kernel<false,0><<<dim3(4,62), 256, 0, stream>>>(BIGh, BIGl, WTh, WTl,
        b2 + (size_t)l*DD, TMP2, nullptr, nullptr, DD, DD, DFF);
    add_ln_kernel<<<NTOK, 256, 0, stream>>>(T, TMP2, g2 + (size_t)l*DD, be2 + (size_t)l*DD, Th, Tl);
  }

  // ---- xg = t @ W_emb1 (split-bf16 out, [NTOK][64] stride, cols 62/63 zero) ----
  convT(W_emb1, E1h, E1l, DD, NNODE, 128, DD);
  gemm3_kernel<false,1><<<dim3(1,62), 256, 0, stream>>>(Th, Tl, E1h, E1l,
      nullptr, nullptr, XGh, XGl, NNODE, 64, DD);

  // ---- conv1 + relu ----
  convT(conv1_W, C1h, C1l, NNODE, DD, DD, 64);
  gemm3_kernel<false,0><<<dim3(4,62), 256, 0, stream>>>(XGh, XGl, C1h, C1l,
      nullptr, TMP1, nullptr, nullptr, DD, DD, 64);
  gcn_agg_kernel<<<MG*8, 64, 0, stream>>>(srcp, dstp, COEF0, DIS0, conv1_b, TMP1, NNODE, 1, nullptr, nullptr);

  // ---- SAGPool 1 ----
  gemv_kernel<<<(NTOK+3)/4, 256, 0, stream>>>(TMP1, pool1_W, HS, NTOK);
  score_kernel<<<MG, 64, 0, stream>>>(srcp, dstp, COEF0, DIS0, HS, pool1_b, SC, NNODE);
  topk_kernel<<<MG, 64, 0, stream>>>(SC, PERM1, NNODE, KP1);
  gather_kernel<<<MG*KP1, 256, 0, stream>>>(TMP1, SC, PERM1, TMP2, Hh, Hl, NNODE, KP1);
  readout_kernel<<<MG, 256, 0, stream>>>(TMP2, Z, KP1, 0);

  // ---- filter_adj ----
  fill_int_kernel<<<(NTOK+255)/256, 256, 0, stream>>>(NMAP, -1, NTOK);
  nmap_scatter_kernel<<<(MG*KP1+255)/256, 256, 0, stream>>>(PERM1, NMAP);
  fill_int_kernel<<<(MG*KP1+255)/256, 256, 0, stream>>>(DEG1, 1, MG*KP1);
  filter_kernel<<<(NEDGE+255)/256, 256, 0, stream>>>(srcp, dstp, NMAP, ES1, ED1, KEEP1, DEG1);
  dis_kernel<<<(MG*KP1+255)/256, 256, 0, stream>>>(DEG1, DIS1, MG*KP1);
  coef1_kernel<<<(NEDGE+255)/256, 256, 0, stream>>>(ES1, ED1, KEEP1, DIS1, COEF1);

  // ---- 3 GCN layers on pooled graph ----
  float* hin = TMP2; float* hout = TMP1;
  for (int l = 0; l < NLAYER-1; ++l) {
    convT(convs_W + (size_t)l*DD*DD, WTh, WTl, DD, DD, DD, DD);
    gemm3_kernel<false,0><<<dim3(4,50), 256, 0, stream>>>(Hh, Hl, WTh, WTl,
        nullptr, hout, nullptr, nullptr, DD, DD, DD);
    gcn_agg_kernel<<<MG*8, 64, 0, stream>>>(ES1, ED1, COEF1, DIS1, convs_b + (size_t)l*DD, hout, KP1, 1, Hh, Hl);
    float* t2 = hin; hin = hout; hout = t2;
  }
  // hin = final pooled h (fp32), mirrored in Hh/Hl

  // ---- SAGPool 2 ----
  gemv_kernel<<<(MG*KP1+3)/4, 256, 0, stream>>>(hin, pool2_W, HS, MG*KP1);
  score_kernel<<<MG, 64, 0, stream>>>(ES1, ED1, COEF1, DIS1, HS, pool2_b, SC, KP1);
  topk_kernel<<<MG, 64, 0, stream>>>(SC, PERM2, KP1, KP2);
  gather_kernel<<<MG*KP2, 256, 0, stream>>>(hin, SC, PERM2, hout, nullptr, nullptr, KP1, KP2);
  readout_kernel<<<MG, 256, 0, stream>>>(hout, Z, KP2, 1);

  // ---- MLP head (fp32) ----
  gemmf(Z,  fc1_W, fc1_b, Z1, MG, DD,   2*DD, true);
  gemmf(Z1, fc2_W, fc2_b, Z2, MG, DD/2, DD,   true);
  gemmf(Z2, fc3_W, fc3_b, (float*)d_out, MG, 2, DD/2, false);
}

// Round 3
// 2501.521 us; speedup vs baseline: 2.6363x; 1.0201x over previous
//
#include <hip/hip_runtime.h>
#include <float.h>
#include <math.h>

#define MG 128
#define NNODE 62
#define DD 512
#define NH 8
#define DH 64
#define DFF 2048
#define NLAYER 4
#define EPG 600
#define KP1 50
#define KP2 40
#define NTOK (MG*NNODE)      // 7936
#define NEDGE (MG*EPG)       // 76800
#define EPSV 1e-5f

typedef unsigned short u16;
using bf16x8 = __attribute__((ext_vector_type(8))) short;
using f32x4  = __attribute__((ext_vector_type(4))) float;

__device__ __forceinline__ float wave_sum(float v) {
  for (int off = 32; off; off >>= 1) v += __shfl_xor(v, off);
  return v;
}
__device__ __forceinline__ float wave_max(float v) {
  for (int off = 32; off; off >>= 1) v = fmaxf(v, __shfl_xor(v, off));
  return v;
}
__device__ __forceinline__ u16 f2b(float x) {
  union { float f; unsigned u; } v; v.f = x;
  unsigned r = v.u + 0x7fffu + ((v.u >> 16) & 1u);
  return (u16)(r >> 16);
}
__device__ __forceinline__ float b2f(u16 h) {
  union { float f; unsigned u; } v; v.u = ((unsigned)h) << 16;
  return v.f;
}
__device__ __forceinline__ void f2bsplit(float x, u16& h, u16& l) {
  h = f2b(x);
  l = f2b(x - b2f(h));
}
// async global->LDS, 16B per lane; LDS dest is wave-uniform-base + lane*16
__device__ __forceinline__ void load_lds16(const u16* g, u16* l) {
  __builtin_amdgcn_global_load_lds(
      (const __attribute__((address_space(1))) unsigned int*)(const void*)g,
      (__attribute__((address_space(3))) unsigned int*)(void*)l, 16, 0, 0);
}

// ---------------- BatchNorm stats ----------------
__global__ __launch_bounds__(256) void bn_stats_kernel(const float* __restrict__ x,
    float* __restrict__ mu, float* __restrict__ rs) {
  int s = blockIdx.x;
  float sum = 0.f, sq = 0.f;
  for (int i = threadIdx.x; i < MG*NNODE; i += 256) {
    int b = i / NNODE, j = i - b*NNODE;
    float v = x[(size_t)(b*NNODE + s)*NNODE + j];
    sum += v; sq += v*v;
  }
  __shared__ float r1[4], r2[4];
  sum = wave_sum(sum); sq = wave_sum(sq);
  int wv = threadIdx.x >> 6, lane = threadIdx.x & 63;
  if (lane == 0) { r1[wv] = sum; r2[wv] = sq; }
  __syncthreads();
  if (threadIdx.x == 0) {
    float S = r1[0]+r1[1]+r1[2]+r1[3];
    float Q = r2[0]+r2[1]+r2[2]+r2[3];
    float m = S / (float)(MG*NNODE);
    float var = Q / (float)(MG*NNODE) - m*m;
    mu[s] = m;
    rs[s] = rsqrtf(var + EPSV);
  }
}

// ---------------- embed: T fp32 + split bf16 ----------------
__global__ __launch_bounds__(256) void embed_kernel(const float* __restrict__ x,
    const float* __restrict__ mu, const float* __restrict__ rs,
    const float* __restrict__ gg, const float* __restrict__ bb,
    const float* __restrict__ W, float* __restrict__ T,
    u16* __restrict__ Th, u16* __restrict__ Tl) {
  int tok = blockIdx.x;
  int s = tok >> 7, b = tok & 127;
  __shared__ float xb[NNODE];
  if (threadIdx.x < NNODE) {
    float v = x[(size_t)(b*NNODE + s)*NNODE + threadIdx.x];
    xb[threadIdx.x] = (v - mu[s]) * rs[s] * gg[s] + bb[s];
  }
  __syncthreads();
  int d = threadIdx.x;
  float a0 = 0.f, a1 = 0.f;
  for (int j = 0; j < NNODE; ++j) {
    float xv = xb[j];
    a0 += xv * W[(size_t)j*DD + d];
    a1 += xv * W[(size_t)j*DD + d + 256];
  }
  size_t o = (size_t)tok*DD + d;
  T[o] = a0; T[o+256] = a1;
  u16 h, l;
  f2bsplit(a0, h, l); Th[o] = h; Tl[o] = l;
  f2bsplit(a1, h, l); Th[o+256] = h; Tl[o+256] = l;
}

// ---------------- weight transpose + split ----------------
__global__ __launch_bounds__(256) void convT_kernel(const float* __restrict__ W,
    u16* __restrict__ WTh, u16* __restrict__ WTl, int K, int N, int Npad, int Kp) {
  __shared__ float t[64][65];
  int k0 = blockIdx.y*64, n0 = blockIdx.x*64;
  for (int i = threadIdx.x; i < 64*64; i += 256) {
    int r = i >> 6, c = i & 63;
    int gk = k0 + r, gn = n0 + c;
    t[r][c] = (gk < K && gn < N) ? W[(size_t)gk*N + gn] : 0.f;
  }
  __syncthreads();
  for (int i = threadIdx.x; i < 64*64; i += 256) {
    int r = i >> 6, c = i & 63;
    int gn = n0 + r, gk = k0 + c;
    if (gn < Npad && gk < Kp) {
      u16 h, l; f2bsplit(t[c][r], h, l);
      WTh[(size_t)gn*Kp + gk] = h;
      WTl[(size_t)gn*Kp + gk] = l;
    }
  }
}

// ---------------- split-bf16 MFMA GEMM via global_load_lds + XOR swizzle ----------------
// A hi/lo: [M][Kp] bf16, BT hi/lo: [Npad][Kp] bf16; 128x128 tile, 4 waves, BK=32.
// LDS linear [128][32] per buffer; swizzle: elem(R,f) = R*32 + (f ^ (((R>>1)&3)<<3)),
// applied to the READ side and (inverse==same XOR) to the global SOURCE column so
// the linear gload_lds writes land where swizzled reads expect (rule #21).
template<bool RELU, int OUTMODE>
__global__ __launch_bounds__(256) void gemm3_kernel(
    const u16* __restrict__ Ah, const u16* __restrict__ Al,
    const u16* __restrict__ Bh, const u16* __restrict__ Bl,
    const float* __restrict__ bias,
    float* __restrict__ Cf, u16* __restrict__ Ch, u16* __restrict__ Cl,
    int Nreal, int Nstride, int Kp) {
  __shared__ alignas(16) u16 sAh[128*32];
  __shared__ alignas(16) u16 sAl[128*32];
  __shared__ alignas(16) u16 sBh[128*32];
  __shared__ alignas(16) u16 sBl[128*32];
  int bm = blockIdx.y * 128, bn = blockIdx.x * 128;
  int tid = threadIdx.x;
  int wv = tid >> 6, lane = tid & 63;
  int wr = (wv >> 1) * 64, wc = (wv & 1) * 64;
  f32x4 acc[4][4];
  #pragma unroll
  for (int i = 0; i < 4; ++i)
    #pragma unroll
    for (int j = 0; j < 4; ++j) acc[i][j] = (f32x4){0.f,0.f,0.f,0.f};

  // staging geometry: thread covers 16B at linear LDS elem tid*8 (and +2048)
  int r0 = tid >> 2;                 // rows 0..63
  int lin = (tid & 3) * 8;
  int c0 = lin ^ (((r0 >> 1) & 3) << 3);
  int r1 = r0 + 64;                  // rows 64..127
  int c1 = lin ^ (((r1 >> 1) & 3) << 3);
  int fr = lane & 15, fo = (lane >> 4) * 8;

  for (int k0 = 0; k0 < Kp; k0 += 32) {
    size_t a0 = (size_t)(bm + r0)*Kp + k0 + c0;
    size_t a1 = (size_t)(bm + r1)*Kp + k0 + c1;
    size_t b0 = (size_t)(bn + r0)*Kp + k0 + c0;
    size_t b1 = (size_t)(bn + r1)*Kp + k0 + c1;
    load_lds16(Ah + a0, &sAh[tid*8]);
    load_lds16(Ah + a1, &sAh[2048 + tid*8]);
    load_lds16(Al + a0, &sAl[tid*8]);
    load_lds16(Al + a1, &sAl[2048 + tid*8]);
    load_lds16(Bh + b0, &sBh[tid*8]);
    load_lds16(Bh + b1, &sBh[2048 + tid*8]);
    load_lds16(Bl + b0, &sBl[tid*8]);
    load_lds16(Bl + b1, &sBl[2048 + tid*8]);
    __syncthreads();   // drains vmcnt -> LDS tiles complete
    bf16x8 ah[4], al[4], bh[4], bl[4];
    #pragma unroll
    for (int i = 0; i < 4; ++i) {
      int ra = wr + i*16 + fr;
      int ea = ra*32 + (fo ^ (((ra >> 1) & 3) << 3));
      ah[i] = *(const bf16x8*)&sAh[ea];
      al[i] = *(const bf16x8*)&sAl[ea];
      int rb = wc + i*16 + fr;
      int eb = rb*32 + (fo ^ (((rb >> 1) & 3) << 3));
      bh[i] = *(const bf16x8*)&sBh[eb];
      bl[i] = *(const bf16x8*)&sBl[eb];
    }
    #pragma unroll
    for (int i = 0; i < 4; ++i)
      #pragma unroll
      for (int j = 0; j < 4; ++j) {
        acc[i][j] = __builtin_amdgcn_mfma_f32_16x16x32_bf16(ah[i], bh[j], acc[i][j], 0, 0, 0);
        acc[i][j] = __builtin_amdgcn_mfma_f32_16x16x32_bf16(ah[i], bl[j], acc[i][j], 0, 0, 0);
        acc[i][j] = __builtin_amdgcn_mfma_f32_16x16x32_bf16(al[i], bh[j], acc[i][j], 0, 0, 0);
      }
    __syncthreads();
  }
  // epilogue: C/D layout col=lane&15, row=(lane>>4)*4+reg
  int cr = (lane >> 4) * 4, cc = lane & 15;
  #pragma unroll
  for (int i = 0; i < 4; ++i) {
    #pragma unroll
    for (int j = 0; j < 4; ++j) {
      int gn = bn + wc + j*16 + cc;
      if (gn >= Nstride) continue;
      #pragma unroll
      for (int q = 0; q < 4; ++q) {
        int gm = bm + wr + i*16 + cr + q;
        float v = acc[i][j][q];
        if (gn < Nreal) { if (bias) v += bias[gn]; } else v = 0.f;
        if (RELU) v = fmaxf(v, 0.f);
        size_t o = (size_t)gm*Nstride + gn;
        if (OUTMODE == 0) {
          Cf[o] = v;
        } else {
          u16 h, l; f2bsplit(v, h, l);
          Ch[o] = h; Cl[o] = l;
        }
      }
    }
  }
}

// ---------------- fused attention per (b,h) ----------------
__global__ __launch_bounds__(256) void attn_kernel(const float* __restrict__ QKV,
    u16* __restrict__ Oh, u16* __restrict__ Ol) {
  int b = blockIdx.x >> 3, h = blockIdx.x & 7;
  __shared__ float qs[NNODE][DH+1];
  __shared__ float ks[NNODE][DH+1];
  __shared__ float ps[NNODE][DH+1];
  for (int i = threadIdx.x; i < NNODE*DH; i += 256) {
    int s = i >> 6, d = i & 63;
    size_t base = ((size_t)(s*MG + b))*(3*DD) + h*DH + d;
    qs[s][d] = QKV[base];
    ks[s][d] = QKV[base + DD];
  }
  __syncthreads();
  int lane = threadIdx.x & 63, wv = threadIdx.x >> 6;
  for (int s = wv; s < NNODE; s += 4) {
    float acc = -FLT_MAX;
    if (lane < NNODE) {
      float a = 0.f;
      #pragma unroll
      for (int d = 0; d < DH; ++d) a += qs[s][d]*ks[lane][d];
      acc = a * 0.125f;
    }
    float mx = wave_max(acc);
    float e = (lane < NNODE) ? expf(acc - mx) : 0.f;
    float sm = wave_sum(e);
    ps[s][lane] = e / sm;
  }
  __syncthreads();
  for (int i = threadIdx.x; i < NNODE*DH; i += 256) {
    int s = i >> 6, d = i & 63;
    qs[s][d] = QKV[((size_t)(s*MG + b))*(3*DD) + 2*DD + h*DH + d];
  }
  __syncthreads();
  for (int s = wv; s < NNODE; s += 4) {
    float acc = 0.f;
    for (int t = 0; t < NNODE; ++t) acc += ps[s][t]*qs[t][lane];
    size_t o = ((size_t)(s*MG + b))*DD + h*DH + lane;
    u16 hh, ll; f2bsplit(acc, hh, ll);
    Oh[o] = hh; Ol[o] = ll;
  }
}

// ---------------- X = LayerNorm(X + R), fp32 + split bf16 ----------------
__global__ __launch_bounds__(256) void add_ln_kernel(float* __restrict__ X,
    const float* __restrict__ R, const float* __restrict__ gg, const float* __restrict__ bb,
    u16* __restrict__ Xh, u16* __restrict__ Xl) {
  size_t row = blockIdx.x;
  int t = threadIdx.x;
  float v0 = X[row*DD + t] + R[row*DD + t];
  float v1 = X[row*DD + t + 256] + R[row*DD + t + 256];
  __shared__ float red[4];
  float s = wave_sum(v0 + v1);
  int wv = t >> 6, lane = t & 63;
  if (lane == 0) red[wv] = s;
  __syncthreads();
  float mu = (red[0]+red[1]+red[2]+red[3]) * (1.f/DD);
  float d0 = v0 - mu, d1 = v1 - mu;
  float q = wave_sum(d0*d0 + d1*d1);
  __syncthreads();
  if (lane == 0) red[wv] = q;
  __syncthreads();
  float var = (red[0]+red[1]+red[2]+red[3]) * (1.f/DD);
  float rs = rsqrtf(var + EPSV);
  float o0 = d0*rs*gg[t] + bb[t];
  float o1 = d1*rs*gg[t+256] + bb[t+256];
  X[row*DD + t] = o0;
  X[row*DD + t+256] = o1;
  u16 h, l;
  f2bsplit(o0, h, l); Xh[row*DD + t] = h; Xl[row*DD + t] = l;
  f2bsplit(o1, h, l); Xh[row*DD + t+256] = h; Xl[row*DD + t+256] = l;
}

// ---------------- graph-structure helpers ----------------
__global__ void fill_int_kernel(int* p, int v, int n) {
  int i = blockIdx.x*256 + threadIdx.x;
  if (i < n) p[i] = v;
}
__global__ void count_deg_kernel(const int* __restrict__ dst, int* deg, int n) {
  int e = blockIdx.x*256 + threadIdx.x;
  if (e < n) atomicAdd(&deg[dst[e]], 1);
}
__global__ void dis_kernel(const int* __restrict__ deg, float* dis, int n) {
  int i = blockIdx.x*256+threadIdx.x;
  if (i < n) dis[i] = rsqrtf((float)deg[i]);
}
__global__ void coef0_kernel(const int* __restrict__ src, const int* __restrict__ dst,
                             const float* __restrict__ dis, float* coef) {
  int e = blockIdx.x*256+threadIdx.x;
  if (e < NEDGE) coef[e] = dis[src[e]]*dis[dst[e]];
}
__global__ void coef1_kernel(const int* __restrict__ src, const int* __restrict__ dst,
                             const int* __restrict__ keep,
                             const float* __restrict__ dis, float* coef) {
  int e = blockIdx.x*256+threadIdx.x;
  if (e < NEDGE) coef[e] = keep[e] ? dis[src[e]]*dis[dst[e]] : 0.f;
}

// ---------------- GCN aggregation: 2 waves, per-wave accumulators (deterministic) ----------------
__global__ __launch_bounds__(128) void gcn_agg_kernel(const int* __restrict__ src,
    const int* __restrict__ dst, const float* __restrict__ coef,
    const float* __restrict__ dis, const float* __restrict__ bias,
    float* __restrict__ HW, int NP, int relu,
    u16* __restrict__ outh, u16* __restrict__ outl) {
  int g = blockIdx.x >> 3;
  int c0 = (blockIdx.x & 7) * 64;
  int lane = threadIdx.x & 63, wv = threadIdx.x >> 6;   // 2 waves
  __shared__ float hs[NNODE][64];
  __shared__ float as[2][NNODE][64];
  __shared__ int se[EPG], sd[EPG];
  __shared__ float scf[EPG];
  int base = g * NP;
  for (int i = wv; i < NP; i += 2)
    hs[i][lane] = HW[(size_t)(base+i)*DD + c0 + lane];
  for (int i = 0; i < NP; ++i) as[wv][i][lane] = 0.f;
  int e0 = g * EPG;
  for (int e = threadIdx.x; e < EPG; e += 128) {
    se[e] = src[e0+e] - base;
    sd[e] = dst[e0+e] - base;
    scf[e] = coef[e0+e];
  }
  __syncthreads();
  int eb = wv * (EPG/2), ee = eb + (EPG/2);
  for (int e = eb; e < ee; ++e) {
    float cf = scf[e];
    if (cf != 0.f) as[wv][sd[e]][lane] += cf * hs[se[e]][lane];
  }
  __syncthreads();
  for (int i = wv; i < NP; i += 2) {
    float d = dis[base+i]; float d2 = d*d;
    float v = as[0][i][lane] + as[1][i][lane] + hs[i][lane]*d2 + bias[c0+lane];
    if (relu) v = fmaxf(v, 0.f);
    size_t o = (size_t)(base+i)*DD + c0 + lane;
    HW[o] = v;
    if (outh) { u16 h, l; f2bsplit(v, h, l); outh[o] = h; outl[o] = l; }
  }
}

// ---------------- gemv: hs[i] = h[i,:] . w ----------------
__global__ __launch_bounds__(256) void gemv_kernel(const float* __restrict__ h,
    const float* __restrict__ wv, float* __restrict__ out, int n) {
  int node = blockIdx.x*4 + (threadIdx.x >> 6);
  int lane = threadIdx.x & 63;
  if (node >= n) return;
  const float* row = h + (size_t)node*DD;
  float acc = 0.f;
  for (int d = lane; d < DD; d += 64) acc += row[d]*wv[d];
  acc = wave_sum(acc);
  if (lane == 0) out[node] = acc;
}

// ---------------- SAGPool scalar score (unchanged: protects topk margin) ----------------
__global__ __launch_bounds__(64) void score_kernel(const int* __restrict__ src,
    const int* __restrict__ dst, const float* __restrict__ coef,
    const float* __restrict__ dis, const float* __restrict__ hsv,
    const float* __restrict__ pb, float* __restrict__ sc, int NP) {
  int g = blockIdx.x;
  int lane = threadIdx.x;
  __shared__ float hss[NNODE], ag[NNODE];
  __shared__ int se[EPG], sd[EPG];
  __shared__ float scf[EPG];
  int base = g*NP;
  if (lane < NP) { hss[lane] = hsv[base+lane]; ag[lane] = 0.f; }
  int e0 = g*EPG;
  for (int e = lane; e < EPG; e += 64) {
    se[e] = src[e0+e]-base; sd[e] = dst[e0+e]-base; scf[e] = coef[e0+e];
  }
  __syncthreads();
  if (lane == 0) {
    for (int e = 0; e < EPG; ++e) {
      float cf = scf[e];
      if (cf != 0.f) ag[sd[e]] += cf*hss[se[e]];
    }
  }
  __syncthreads();
  if (lane < NP) {
    float d = dis[base+lane];
    sc[base+lane] = ag[lane] + hss[lane]*d*d + pb[0];
  }
}

// ---------------- per-graph top-k ----------------
__global__ __launch_bounds__(64) void topk_kernel(const float* __restrict__ sc,
    int* __restrict__ perm, int NP, int KK) {
  int g = blockIdx.x, lane = threadIdx.x;
  float v = (lane < NP) ? sc[g*NP+lane] : -FLT_MAX;
  for (int r = 0; r < KK; ++r) {
    float bv = v; int bi = lane;
    for (int off = 32; off; off >>= 1) {
      float ov = __shfl_xor(bv, off);
      int oi = __shfl_xor(bi, off);
      if (ov > bv || (ov == bv && oi < bi)) { bv = ov; bi = oi; }
    }
    if (lane == 0) perm[g*KK + r] = bi;
    if (lane == bi) v = -FLT_MAX;
  }
}

// ---------------- gather pooled ----------------
__global__ __launch_bounds__(256) void gather_kernel(const float* __restrict__ h,
    const float* __restrict__ sc, const int* __restrict__ perm,
    float* __restrict__ xn, u16* __restrict__ outh, u16* __restrict__ outl,
    int NP, int KK) {
  int j = blockIdx.x;
  int g = j / KK;
  int pi = perm[j];
  float t = tanhf(sc[g*NP + pi]);
  const float* srow = h + (size_t)(g*NP + pi)*DD;
  size_t o = (size_t)j*DD + threadIdx.x;
  float v0 = srow[threadIdx.x]*t;
  float v1 = srow[threadIdx.x+256]*t;
  xn[o] = v0; xn[o+256] = v1;
  if (outh) {
    u16 hh, ll;
    f2bsplit(v0, hh, ll); outh[o] = hh; outl[o] = ll;
    f2bsplit(v1, hh, ll); outh[o+256] = hh; outl[o+256] = ll;
  }
}

__global__ void nmap_scatter_kernel(const int* __restrict__ perm, int* __restrict__ nmap) {
  int j = blockIdx.x*256 + threadIdx.x;
  if (j < MG*KP1) nmap[(j/KP1)*NNODE + perm[j]] = j;
}

__global__ void filter_kernel(const int* __restrict__ src0, const int* __restrict__ dst0,
    const int* __restrict__ nmap, int* __restrict__ es, int* __restrict__ ed,
    int* __restrict__ keep, int* __restrict__ deg1) {
  int e = blockIdx.x*256+threadIdx.x;
  if (e >= NEDGE) return;
  int ns = nmap[src0[e]], nd = nmap[dst0[e]];
  int k = (ns >= 0) && (nd >= 0);
  es[e] = k ? ns : 0;
  ed[e] = k ? nd : 0;
  keep[e] = k;
  if (k) atomicAdd(&deg1[nd], 1);
}

// ---------------- readout: gmp || gap ----------------
__global__ __launch_bounds__(256) void readout_kernel(const float* __restrict__ h,
    float* __restrict__ z, int KK, int acc) {
  int g = blockIdx.x;
  for (int c = threadIdx.x; c < DD; c += 256) {
    float mx = -FLT_MAX, sm = 0.f;
    for (int r = 0; r < KK; ++r) {
      float v = h[(size_t)(g*KK+r)*DD + c];
      mx = fmaxf(mx, v); sm += v;
    }
    float mean = sm / (float)KK;
    if (acc) { z[(size_t)g*1024 + c] += mx; z[(size_t)g*1024 + 512 + c] += mean; }
    else     { z[(size_t)g*1024 + c]  = mx; z[(size_t)g*1024 + 512 + c]  = mean; }
  }
}

// ---------------- fused MLP head: z[1024] -> 512 relu -> 256 relu -> 2 ----------------
__global__ __launch_bounds__(256) void mlp_kernel(const float* __restrict__ Z,
    const float* __restrict__ W1, const float* __restrict__ b1,
    const float* __restrict__ W2, const float* __restrict__ b2,
    const float* __restrict__ W3, const float* __restrict__ b3,
    float* __restrict__ out) {
  int g = blockIdx.x;
  __shared__ float z[1024];
  __shared__ float h1[512];
  __shared__ float h2[256];
  for (int i = threadIdx.x; i < 1024; i += 256) z[i] = Z[(size_t)g*1024 + i];
  __syncthreads();
  #pragma unroll
  for (int half = 0; half < 2; ++half) {
    int n = threadIdx.x + half*256;
    float a0 = 0.f, a1 = 0.f;
    for (int k = 0; k < 1024; k += 2) {
      a0 += z[k]   * W1[(size_t)k*512 + n];
      a1 += z[k+1] * W1[(size_t)(k+1)*512 + n];
    }
    h1[n] = fmaxf(a0 + a1 + b1[n], 0.f);
  }
  __syncthreads();
  {
    int n = threadIdx.x;
    float a0 = 0.f, a1 = 0.f;
    for (int k = 0; k < 512; k += 2) {
      a0 += h1[k]   * W2[(size_t)k*256 + n];
      a1 += h1[k+1] * W2[(size_t)(k+1)*256 + n];
    }
    h2[n] = fmaxf(a0 + a1 + b2[n], 0.f);
  }
  __syncthreads();
  int wv = threadIdx.x >> 6, lane = threadIdx.x & 63;
  if (wv < 2) {
    float acc = 0.f;
    for (int k = lane; k < 256; k += 64) acc += h2[k]*W3[(size_t)k*2 + wv];
    acc = wave_sum(acc);
    if (lane == 0) out[(size_t)g*2 + wv] = acc + b3[wv];
  }
}

extern "C" void kernel_launch(void* const* d_in, const int* in_sizes, int n_in,
                              void* d_out, int out_size, void* d_ws, size_t ws_size,
                              hipStream_t stream) {
  const float* x       = (const float*)d_in[0];
  const int*   edge    = (const int*)d_in[1];
  const float* bn_g    = (const float*)d_in[2];
  const float* bn_b    = (const float*)d_in[3];
  const float* W_emb   = (const float*)d_in[4];
  const float* Wqkv    = (const float*)d_in[5];
  const float* bqkv    = (const float*)d_in[6];
  const float* Wo      = (const float*)d_in[7];
  const float* bo      = (const float*)d_in[8];
  const float* W1      = (const float*)d_in[9];
  const float* b1      = (const float*)d_in[10];
  const float* W2      = (const float*)d_in[11];
  const float* b2      = (const float*)d_in[12];
  const float* g1      = (const float*)d_in[13];
  const float* be1     = (const float*)d_in[14];
  const float* g2      = (const float*)d_in[15];
  const float* be2     = (const float*)d_in[16];
  const float* W_emb1  = (const float*)d_in[17];
  const float* conv1_W = (const float*)d_in[18];
  const float* conv1_b = (const float*)d_in[19];
  const float* convs_W = (const float*)d_in[20];
  const float* convs_b = (const float*)d_in[21];
  const float* pool1_W = (const float*)d_in[22];
  const float* pool1_b = (const float*)d_in[23];
  const float* pool2_W = (const float*)d_in[24];
  const float* pool2_b = (const float*)d_in[25];
  const float* fc1_W   = (const float*)d_in[26];
  const float* fc1_b   = (const float*)d_in[27];
  const float* fc2_W   = (const float*)d_in[28];
  const float* fc2_b   = (const float*)d_in[29];
  const float* fc3_W   = (const float*)d_in[30];
  const float* fc3_b   = (const float*)d_in[31];
  (void)in_sizes; (void)n_in; (void)out_size; (void)ws_size;

  const int* srcp = edge;
  const int* dstp = edge + NEDGE;

  char* wsb = (char*)d_ws;
  size_t off = 0;
  auto alloc = [&](size_t bytes)->void* {
    void* p = wsb + off;
    off += (bytes + 255) & ~(size_t)255;
    return p;
  };
  float* T    = (float*)alloc((size_t)NTOK*DD*4);
  float* TMP1 = (float*)alloc((size_t)NTOK*DD*4);
  float* TMP2 = (float*)alloc((size_t)NTOK*DD*4);
  size_t qkvB = (size_t)NTOK*3*DD*4, ffnB = (size_t)NTOK*DFF*2*2;
  char* BIGU  = (char*)alloc(qkvB > ffnB ? qkvB : ffnB);
  float* QKVf = (float*)BIGU;
  u16* BIGh   = (u16*)BIGU;
  u16* BIGl   = BIGh + (size_t)NTOK*DFF;
  u16* Th   = (u16*)alloc((size_t)NTOK*DD*2);
  u16* Tl   = (u16*)alloc((size_t)NTOK*DD*2);
  u16* ATh  = (u16*)alloc((size_t)NTOK*DD*2);
  u16* ATl  = (u16*)alloc((size_t)NTOK*DD*2);
  u16* XGh  = (u16*)alloc((size_t)NTOK*64*2);
  u16* XGl  = (u16*)alloc((size_t)NTOK*64*2);
  u16* Hh   = (u16*)alloc((size_t)MG*KP1*DD*2);
  u16* Hl   = (u16*)alloc((size_t)MG*KP1*DD*2);
  u16* WTh  = (u16*)alloc((size_t)1048576*2);
  u16* WTl  = (u16*)alloc((size_t)1048576*2);
  u16* E1h  = (u16*)alloc((size_t)128*512*2);
  u16* E1l  = (u16*)alloc((size_t)128*512*2);
  u16* C1h  = (u16*)alloc((size_t)512*64*2);
  u16* C1l  = (u16*)alloc((size_t)512*64*2);
  float* MU   = (float*)alloc(NNODE*4);
  float* RS   = (float*)alloc(NNODE*4);
  int*   DEG0 = (int*)alloc(NTOK*4);
  float* DIS0 = (float*)alloc(NTOK*4);
  float* COEF0= (float*)alloc(NEDGE*4);
  float* HS   = (float*)alloc(NTOK*4);
  float* SC   = (float*)alloc(NTOK*4);
  int*   PERM1= (int*)alloc(MG*KP1*4);
  int*   NMAP = (int*)alloc(NTOK*4);
  int*   ES1  = (int*)alloc(NEDGE*4);
  int*   ED1  = (int*)alloc(NEDGE*4);
  int*   KEEP1= (int*)alloc(NEDGE*4);
  int*   DEG1 = (int*)alloc(MG*KP1*4);
  float* DIS1 = (float*)alloc(MG*KP1*4);
  float* COEF1= (float*)alloc(NEDGE*4);
  int*   PERM2= (int*)alloc(MG*KP2*4);
  float* Z    = (float*)alloc(MG*1024*4);

  auto convT = [&](const float* W, u16* th, u16* tl, int K, int N, int Npad, int Kp) {
    convT_kernel<<<dim3((Npad+63)/64, (Kp+63)/64), 256, 0, stream>>>(W, th, tl, K, N, Npad, Kp);
  };

  // ---- BN + embed ----
  bn_stats_kernel<<<NNODE, 256, 0, stream>>>(x, MU, RS);
  embed_kernel<<<NTOK, 256, 0, stream>>>(x, MU, RS, bn_g, bn_b, W_emb, T, Th, Tl);

  // ---- graph structure ----
  fill_int_kernel<<<(NTOK+255)/256, 256, 0, stream>>>(DEG0, 1, NTOK);
  count_deg_kernel<<<(NEDGE+255)/256, 256, 0, stream>>>(dstp, DEG0, NEDGE);
  dis_kernel<<<(NTOK+255)/256, 256, 0, stream>>>(DEG0, DIS0, NTOK);
  coef0_kernel<<<(NEDGE+255)/256, 256, 0, stream>>>(srcp, dstp, DIS0, COEF0);

  // ---- transformer encoder ----
  for (int l = 0; l < NLAYER; ++l) {
    convT(Wqkv + (size_t)l*DD*3*DD, WTh, WTl, DD, 3*DD, 3*DD, DD);
    gemm3_kernel<false,0><<<dim3(12,62), 256, 0, stream>>>(Th, Tl, WTh, WTl,
        bqkv + (size_t)l*3*DD, QKVf, nullptr, nullptr, 3*DD, 3*DD, DD);
    attn_kernel<<<MG*NH, 256, 0, stream>>>(QKVf, ATh, ATl);
    convT(Wo + (size_t)l*DD*DD, WTh, WTl, DD, DD, DD, DD);
    gemm3_kernel<false,0><<<dim3(4,62), 256, 0, stream>>>(ATh, ATl, WTh, WTl,
        bo + (size_t)l*DD, TMP2, nullptr, nullptr, DD, DD, DD);
    add_ln_kernel<<<NTOK, 256, 0, stream>>>(T, TMP2, g1 + (size_t)l*DD, be1 + (size_t)l*DD, Th, Tl);
    convT(W1 + (size_t)l*DD*DFF, WTh, WTl, DD, DFF, DFF, DD);
    gemm3_kernel<true,1><<<dim3(16,62), 256, 0, stream>>>(Th, Tl, WTh, WTl,
        b1 + (size_t)l*DFF, nullptr, BIGh, BIGl, DFF, DFF, DD);
    convT(W2 + (size_t)l*DFF*DD, WTh, WTl, DFF, DD, DD, DFF);
    gemm3_kernel<false,0><<<dim3(4,62), 256, 0, stream>>>(BIGh, BIGl, WTh, WTl,
        b2 + (size_t)l*DD, TMP2, nullptr, nullptr, DD, DD, DFF);
    add_ln_kernel<<<NTOK, 256, 0, stream>>>(T, TMP2, g2 + (size_t)l*DD, be2 + (size_t)l*DD, Th, Tl);
  }

  // ---- xg = t @ W_emb1 ----
  convT(W_emb1, E1h, E1l, DD, NNODE, 128, DD);
  gemm3_kernel<false,1><<<dim3(1,62), 256, 0, stream>>>(Th, Tl, E1h, E1l,
      nullptr, nullptr, XGh, XGl, NNODE, 64, DD);

  // ---- conv1 + relu ----
  convT(conv1_W, C1h, C1l, NNODE, DD, DD, 64);
  gemm3_kernel<false,0><<<dim3(4,62), 256, 0, stream>>>(XGh, XGl, C1h, C1l,
      nullptr, TMP1, nullptr, nullptr, DD, DD, 64);
  gcn_agg_kernel<<<MG*8, 128, 0, stream>>>(srcp, dstp, COEF0, DIS0, conv1_b, TMP1, NNODE, 1, nullptr, nullptr);

  // ---- SAGPool 1 ----
  gemv_kernel<<<(NTOK+3)/4, 256, 0, stream>>>(TMP1, pool1_W, HS, NTOK);
  score_kernel<<<MG, 64, 0, stream>>>(srcp, dstp, COEF0, DIS0, HS, pool1_b, SC, NNODE);
  topk_kernel<<<MG, 64, 0, stream>>>(SC, PERM1, NNODE, KP1);
  gather_kernel<<<MG*KP1, 256, 0, stream>>>(TMP1, SC, PERM1, TMP2, Hh, Hl, NNODE, KP1);
  readout_kernel<<<MG, 256, 0, stream>>>(TMP2, Z, KP1, 0);

  // ---- filter_adj ----
  fill_int_kernel<<<(NTOK+255)/256, 256, 0, stream>>>(NMAP, -1, NTOK);
  nmap_scatter_kernel<<<(MG*KP1+255)/256, 256, 0, stream>>>(PERM1, NMAP);
  fill_int_kernel<<<(MG*KP1+255)/256, 256, 0, stream>>>(DEG1, 1, MG*KP1);
  filter_kernel<<<(NEDGE+255)/256, 256, 0, stream>>>(srcp, dstp, NMAP, ES1, ED1, KEEP1, DEG1);
  dis_kernel<<<(MG*KP1+255)/256, 256, 0, stream>>>(DEG1, DIS1, MG*KP1);
  coef1_kernel<<<(NEDGE+255)/256, 256, 0, stream>>>(ES1, ED1, KEEP1, DIS1, COEF1);

  // ---- 3 GCN layers on pooled graph ----
  float* hin = TMP2; float* hout = TMP1;
  for (int l = 0; l < NLAYER-1; ++l) {
    convT(convs_W + (size_t)l*DD*DD, WTh, WTl, DD, DD, DD, DD);
    gemm3_kernel<false,0><<<dim3(4,50), 256, 0, stream>>>(Hh, Hl, WTh, WTl,
        nullptr, hout, nullptr, nullptr, DD, DD, DD);
    gcn_agg_kernel<<<MG*8, 128, 0, stream>>>(ES1, ED1, COEF1, DIS1, convs_b + (size_t)l*DD, hout, KP1, 1, Hh, Hl);
    float* t2 = hin; hin = hout; hout = t2;
  }

  // ---- SAGPool 2 ----
  gemv_kernel<<<(MG*KP1+3)/4, 256, 0, stream>>>(hin, pool2_W, HS, MG*KP1);
  score_kernel<<<MG, 64, 0, stream>>>(ES1, ED1, COEF1, DIS1, HS, pool2_b, SC, KP1);
  topk_kernel<<<MG, 64, 0, stream>>>(SC, PERM2, KP1, KP2);
  gather_kernel<<<MG*KP2, 256, 0, stream>>>(hin, SC, PERM2, hout, nullptr, nullptr, KP1, KP2);
  readout_kernel<<<MG, 256, 0, stream>>>(hout, Z, KP2, 1);

  // ---- fused MLP head ----
  mlp_kernel<<<MG, 256, 0, stream>>>(Z, fc1_W, fc1_b, fc2_W, fc2_b, fc3_W, fc3_b, (float*)d_out);
}

// Round 4
// 2319.041 us; speedup vs baseline: 2.8438x; 1.0787x over previous
//
#include <hip/hip_runtime.h>
#include <float.h>
#include <math.h>

#define MG 128
#define NNODE 62
#define DD 512
#define NH 8
#define DH 64
#define DFF 2048
#define NLAYER 4
#define EPG 600
#define KP1 50
#define KP2 40
#define NTOK (MG*NNODE)      // 7936
#define NEDGE (MG*EPG)       // 76800
#define EPSV 1e-5f

typedef unsigned short u16;
using bf16x8 = __attribute__((ext_vector_type(8))) short;
using f32x4  = __attribute__((ext_vector_type(4))) float;

__device__ __forceinline__ float wave_sum(float v) {
  for (int off = 32; off; off >>= 1) v += __shfl_xor(v, off);
  return v;
}
__device__ __forceinline__ float wave_max(float v) {
  for (int off = 32; off; off >>= 1) v = fmaxf(v, __shfl_xor(v, off));
  return v;
}
__device__ __forceinline__ u16 f2b(float x) {
  union { float f; unsigned u; } v; v.f = x;
  unsigned r = v.u + 0x7fffu + ((v.u >> 16) & 1u);
  return (u16)(r >> 16);
}
__device__ __forceinline__ float b2f(u16 h) {
  union { float f; unsigned u; } v; v.u = ((unsigned)h) << 16;
  return v.f;
}
__device__ __forceinline__ void f2bsplit(float x, u16& h, u16& l) {
  h = f2b(x);
  l = f2b(x - b2f(h));
}
__device__ __forceinline__ void load_lds16(const u16* g, u16* l) {
  __builtin_amdgcn_global_load_lds(
      (const __attribute__((address_space(1))) unsigned int*)(const void*)g,
      (__attribute__((address_space(3))) unsigned int*)(void*)l, 16, 0, 0);
}

// ---------------- BatchNorm stats ----------------
__global__ __launch_bounds__(256) void bn_stats_kernel(const float* __restrict__ x,
    float* __restrict__ mu, float* __restrict__ rs) {
  int s = blockIdx.x;
  float sum = 0.f, sq = 0.f;
  for (int i = threadIdx.x; i < MG*NNODE; i += 256) {
    int b = i / NNODE, j = i - b*NNODE;
    float v = x[(size_t)(b*NNODE + s)*NNODE + j];
    sum += v; sq += v*v;
  }
  __shared__ float r1[4], r2[4];
  sum = wave_sum(sum); sq = wave_sum(sq);
  int wv = threadIdx.x >> 6, lane = threadIdx.x & 63;
  if (lane == 0) { r1[wv] = sum; r2[wv] = sq; }
  __syncthreads();
  if (threadIdx.x == 0) {
    float S = r1[0]+r1[1]+r1[2]+r1[3];
    float Q = r2[0]+r2[1]+r2[2]+r2[3];
    float m = S / (float)(MG*NNODE);
    float var = Q / (float)(MG*NNODE) - m*m;
    mu[s] = m;
    rs[s] = rsqrtf(var + EPSV);
  }
}

// ---------------- embed: T fp32 + split bf16 ----------------
__global__ __launch_bounds__(256) void embed_kernel(const float* __restrict__ x,
    const float* __restrict__ mu, const float* __restrict__ rs,
    const float* __restrict__ gg, const float* __restrict__ bb,
    const float* __restrict__ W, float* __restrict__ T,
    u16* __restrict__ Th, u16* __restrict__ Tl) {
  int tok = blockIdx.x;
  int s = tok >> 7, b = tok & 127;
  __shared__ float xb[NNODE];
  if (threadIdx.x < NNODE) {
    float v = x[(size_t)(b*NNODE + s)*NNODE + threadIdx.x];
    xb[threadIdx.x] = (v - mu[s]) * rs[s] * gg[s] + bb[s];
  }
  __syncthreads();
  int d = threadIdx.x;
  float a0 = 0.f, a1 = 0.f;
  for (int j = 0; j < NNODE; ++j) {
    float xv = xb[j];
    a0 += xv * W[(size_t)j*DD + d];
    a1 += xv * W[(size_t)j*DD + d + 256];
  }
  size_t o = (size_t)tok*DD + d;
  T[o] = a0; T[o+256] = a1;
  u16 h, l;
  f2bsplit(a0, h, l); Th[o] = h; Tl[o] = l;
  f2bsplit(a1, h, l); Th[o+256] = h; Tl[o+256] = l;
}

// ---------------- fp32 GEMM (only for Wcomb = W_emb1 @ conv1_W) ----------------
__global__ __launch_bounds__(256) void gemm_kernel(const float* __restrict__ A,
    const float* __restrict__ B, float* __restrict__ C, int M, int N, int K) {
  __shared__ float As[16][68];
  __shared__ float Bs[16][68];
  int bm = blockIdx.y * 64, bn = blockIdx.x * 64;
  int tid = threadIdx.x;
  int tx = tid & 15, ty = tid >> 4;
  float acc[4][4] = {};
  for (int k0 = 0; k0 < K; k0 += 16) {
    {
      int row = tid >> 2; int kk = (tid & 3) * 4;
      int gm = bm + row;
      #pragma unroll
      for (int i = 0; i < 4; ++i) {
        int gk = k0 + kk + i;
        As[kk+i][row] = (gm < M && gk < K) ? A[(size_t)gm*K + gk] : 0.f;
      }
    }
    {
      int krow = tid >> 4; int nn = (tid & 15) * 4;
      int gk = k0 + krow;
      #pragma unroll
      for (int i = 0; i < 4; ++i) {
        int gn = bn + nn + i;
        Bs[krow][nn+i] = (gk < K && gn < N) ? B[(size_t)gk*N + gn] : 0.f;
      }
    }
    __syncthreads();
    #pragma unroll
    for (int k = 0; k < 16; ++k) {
      float a[4], bb2[4];
      #pragma unroll
      for (int i = 0; i < 4; ++i) a[i] = As[k][ty*4+i];
      #pragma unroll
      for (int j = 0; j < 4; ++j) bb2[j] = Bs[k][tx*4+j];
      #pragma unroll
      for (int i = 0; i < 4; ++i)
        #pragma unroll
        for (int j = 0; j < 4; ++j) acc[i][j] += a[i]*bb2[j];
    }
    __syncthreads();
  }
  #pragma unroll
  for (int i = 0; i < 4; ++i) {
    int gm = bm + ty*4 + i;
    if (gm >= M) continue;
    #pragma unroll
    for (int j = 0; j < 4; ++j) {
      int gn = bn + tx*4 + j;
      if (gn >= N) continue;
      C[(size_t)gm*N + gn] = acc[i][j];
    }
  }
}

// ---------------- transpose+split tile helper ----------------
__device__ __forceinline__ void transpose_split_tile(const float* __restrict__ W,
    u16* __restrict__ th, u16* __restrict__ tl,
    int K, int N, int Kp, int bx, int by, float (*t)[65]) {
  int k0 = by*64, n0 = bx*64;
  for (int i = threadIdx.x; i < 64*64; i += 256) {
    int r = i >> 6, c = i & 63;
    int gk = k0 + r, gn = n0 + c;
    t[r][c] = (gk < K && gn < N) ? W[(size_t)gk*N + gn] : 0.f;
  }
  __syncthreads();
  for (int i = threadIdx.x; i < 64*64; i += 256) {
    int r = i >> 6, c = i & 63;
    int gn = n0 + r, gk = k0 + c;
    u16 h, l; f2bsplit(t[c][r], h, l);
    th[(size_t)gn*Kp + gk] = h;
    tl[(size_t)gn*Kp + gk] = l;
  }
}

// ---------------- per-layer batched weight transpose (Wqkv, Wo, W1, W2) ----------------
__global__ __launch_bounds__(256) void layerT_kernel(
    const float* __restrict__ Wqkv, const float* __restrict__ Wo,
    const float* __restrict__ W1, const float* __restrict__ W2,
    u16* WQh, u16* WQl, u16* WOh, u16* WOl,
    u16* W1h, u16* W1l, u16* W2h, u16* W2l) {
  __shared__ float t[64][65];
  int b = blockIdx.x;
  if (b < 192)      transpose_split_tile(Wqkv, WQh, WQl, 512, 1536, 512, b % 24, b / 24, t);
  else if (b < 256) { int q = b - 192; transpose_split_tile(Wo, WOh, WOl, 512, 512, 512, q % 8, q / 8, t); }
  else if (b < 512) { int q = b - 256; transpose_split_tile(W1, W1h, W1l, 512, 2048, 512, q % 32, q / 32, t); }
  else              { int q = b - 512; transpose_split_tile(W2, W2h, W2l, 2048, 512, 2048, q % 8, q / 8, t); }
}

// ---------------- GCN weights transpose (Wcomb, convs_W[0..2]) ----------------
__global__ __launch_bounds__(256) void gcnT_kernel(
    const float* __restrict__ WC, const float* __restrict__ convs_W,
    u16* CTh, u16* CTl, u16* CVh, u16* CVl) {
  __shared__ float t[64][65];
  int job = blockIdx.x >> 6, q = blockIdx.x & 63;
  int bx = q % 8, by = q / 8;
  if (job == 0) transpose_split_tile(WC, CTh, CTl, 512, 512, 512, bx, by, t);
  else {
    int l = job - 1;
    transpose_split_tile(convs_W + (size_t)l*DD*DD,
        CVh + (size_t)l*DD*DD, CVl + (size_t)l*DD*DD, 512, 512, 512, bx, by, t);
  }
}

// ---------------- split-bf16 MFMA GEMM, global_load_lds + XOR swizzle, split-K ----------------
// grid.z = K-chunks, each covers KC; chunk z writes Cf + z*(gridDim.y*128)*Nstride.
// bias added by chunk 0 only. RELU/OUTMODE=1 only used unsplit.
template<bool RELU, int OUTMODE>
__global__ __launch_bounds__(256) void gemm3_kernel(
    const u16* __restrict__ Ah, const u16* __restrict__ Al,
    const u16* __restrict__ Bh, const u16* __restrict__ Bl,
    const float* __restrict__ bias,
    float* __restrict__ Cf, u16* __restrict__ Ch, u16* __restrict__ Cl,
    int Nreal, int Nstride, int Kp, int KC) {
  __shared__ alignas(16) u16 sAh[128*32];
  __shared__ alignas(16) u16 sAl[128*32];
  __shared__ alignas(16) u16 sBh[128*32];
  __shared__ alignas(16) u16 sBl[128*32];
  int bm = blockIdx.y * 128, bn = blockIdx.x * 128;
  int z = blockIdx.z;
  int tid = threadIdx.x;
  int wv = tid >> 6, lane = tid & 63;
  int wr = (wv >> 1) * 64, wc = (wv & 1) * 64;
  f32x4 acc[4][4];
  #pragma unroll
  for (int i = 0; i < 4; ++i)
    #pragma unroll
    for (int j = 0; j < 4; ++j) acc[i][j] = (f32x4){0.f,0.f,0.f,0.f};

  int r0 = tid >> 2;
  int lin = (tid & 3) * 8;
  int c0 = lin ^ (((r0 >> 1) & 3) << 3);
  int r1 = r0 + 64;
  int c1 = lin ^ (((r1 >> 1) & 3) << 3);
  int fr = lane & 15, fo = (lane >> 4) * 8;

  int kbeg = z * KC, kend = kbeg + KC;
  for (int k0 = kbeg; k0 < kend; k0 += 32) {
    size_t a0 = (size_t)(bm + r0)*Kp + k0 + c0;
    size_t a1 = (size_t)(bm + r1)*Kp + k0 + c1;
    size_t b0 = (size_t)(bn + r0)*Kp + k0 + c0;
    size_t b1 = (size_t)(bn + r1)*Kp + k0 + c1;
    load_lds16(Ah + a0, &sAh[tid*8]);
    load_lds16(Ah + a1, &sAh[2048 + tid*8]);
    load_lds16(Al + a0, &sAl[tid*8]);
    load_lds16(Al + a1, &sAl[2048 + tid*8]);
    load_lds16(Bh + b0, &sBh[tid*8]);
    load_lds16(Bh + b1, &sBh[2048 + tid*8]);
    load_lds16(Bl + b0, &sBl[tid*8]);
    load_lds16(Bl + b1, &sBl[2048 + tid*8]);
    __syncthreads();
    bf16x8 ah[4], al[4], bh[4], bl[4];
    #pragma unroll
    for (int i = 0; i < 4; ++i) {
      int ra = wr + i*16 + fr;
      int ea = ra*32 + (fo ^ (((ra >> 1) & 3) << 3));
      ah[i] = *(const bf16x8*)&sAh[ea];
      al[i] = *(const bf16x8*)&sAl[ea];
      int rb = wc + i*16 + fr;
      int eb = rb*32 + (fo ^ (((rb >> 1) & 3) << 3));
      bh[i] = *(const bf16x8*)&sBh[eb];
      bl[i] = *(const bf16x8*)&sBl[eb];
    }
    #pragma unroll
    for (int i = 0; i < 4; ++i)
      #pragma unroll
      for (int j = 0; j < 4; ++j) {
        acc[i][j] = __builtin_amdgcn_mfma_f32_16x16x32_bf16(ah[i], bh[j], acc[i][j], 0, 0, 0);
        acc[i][j] = __builtin_amdgcn_mfma_f32_16x16x32_bf16(ah[i], bl[j], acc[i][j], 0, 0, 0);
        acc[i][j] = __builtin_amdgcn_mfma_f32_16x16x32_bf16(al[i], bh[j], acc[i][j], 0, 0, 0);
      }
    __syncthreads();
  }
  size_t pstride = (size_t)gridDim.y * 128 * Nstride;
  int cr = (lane >> 4) * 4, cc = lane & 15;
  #pragma unroll
  for (int i = 0; i < 4; ++i) {
    #pragma unroll
    for (int j = 0; j < 4; ++j) {
      int gn = bn + wc + j*16 + cc;
      if (gn >= Nstride) continue;
      #pragma unroll
      for (int q = 0; q < 4; ++q) {
        int gm = bm + wr + i*16 + cr + q;
        float v = acc[i][j][q];
        if (gn < Nreal) { if (bias && z == 0) v += bias[gn]; } else v = 0.f;
        if (RELU) v = fmaxf(v, 0.f);
        size_t o = (size_t)z*pstride + (size_t)gm*Nstride + gn;
        if (OUTMODE == 0) {
          Cf[o] = v;
        } else {
          u16 h, l; f2bsplit(v, h, l);
          Ch[o] = h; Cl[o] = l;
        }
      }
    }
  }
}

// ---------------- fused attention per (b,h) ----------------
__global__ __launch_bounds__(256) void attn_kernel(const float* __restrict__ QKV,
    u16* __restrict__ Oh, u16* __restrict__ Ol) {
  int b = blockIdx.x >> 3, h = blockIdx.x & 7;
  __shared__ float qs[NNODE][DH+1];
  __shared__ float ks[NNODE][DH+1];
  __shared__ float ps[NNODE][DH+1];
  for (int i = threadIdx.x; i < NNODE*DH; i += 256) {
    int s = i >> 6, d = i & 63;
    size_t base = ((size_t)(s*MG + b))*(3*DD) + h*DH + d;
    qs[s][d] = QKV[base];
    ks[s][d] = QKV[base + DD];
  }
  __syncthreads();
  int lane = threadIdx.x & 63, wv = threadIdx.x >> 6;
  for (int s = wv; s < NNODE; s += 4) {
    float acc = -FLT_MAX;
    if (lane < NNODE) {
      float a = 0.f;
      #pragma unroll
      for (int d = 0; d < DH; ++d) a += qs[s][d]*ks[lane][d];
      acc = a * 0.125f;
    }
    float mx = wave_max(acc);
    float e = (lane < NNODE) ? expf(acc - mx) : 0.f;
    float sm = wave_sum(e);
    ps[s][lane] = e / sm;
  }
  __syncthreads();
  for (int i = threadIdx.x; i < NNODE*DH; i += 256) {
    int s = i >> 6, d = i & 63;
    qs[s][d] = QKV[((size_t)(s*MG + b))*(3*DD) + 2*DD + h*DH + d];
  }
  __syncthreads();
  for (int s = wv; s < NNODE; s += 4) {
    float acc = 0.f;
    for (int t = 0; t < NNODE; ++t) acc += ps[s][t]*qs[t][lane];
    size_t o = ((size_t)(s*MG + b))*DD + h*DH + lane;
    u16 hh, ll; f2bsplit(acc, hh, ll);
    Oh[o] = hh; Ol[o] = ll;
  }
}

// ---------------- X = LayerNorm(X + sum_z PART[z]) ----------------
__global__ __launch_bounds__(256) void add_ln_kernel(float* __restrict__ X,
    const float* __restrict__ P, int nchunk,
    const float* __restrict__ gg, const float* __restrict__ bb,
    u16* __restrict__ Xh, u16* __restrict__ Xl) {
  size_t row = blockIdx.x;
  int t = threadIdx.x;
  const size_t MN = (size_t)NTOK*DD;
  float r0 = 0.f, r1 = 0.f;
  for (int z = 0; z < nchunk; ++z) {
    r0 += P[z*MN + row*DD + t];
    r1 += P[z*MN + row*DD + t + 256];
  }
  float v0 = X[row*DD + t] + r0;
  float v1 = X[row*DD + t + 256] + r1;
  __shared__ float red[4];
  float s = wave_sum(v0 + v1);
  int wv = t >> 6, lane = t & 63;
  if (lane == 0) red[wv] = s;
  __syncthreads();
  float mu = (red[0]+red[1]+red[2]+red[3]) * (1.f/DD);
  float d0 = v0 - mu, d1 = v1 - mu;
  float q = wave_sum(d0*d0 + d1*d1);
  __syncthreads();
  if (lane == 0) red[wv] = q;
  __syncthreads();
  float var = (red[0]+red[1]+red[2]+red[3]) * (1.f/DD);
  float rs = rsqrtf(var + EPSV);
  float o0 = d0*rs*gg[t] + bb[t];
  float o1 = d1*rs*gg[t+256] + bb[t+256];
  X[row*DD + t] = o0;
  X[row*DD + t+256] = o1;
  u16 h, l;
  f2bsplit(o0, h, l); Xh[row*DD + t] = h; Xl[row*DD + t] = l;
  f2bsplit(o1, h, l); Xh[row*DD + t+256] = h; Xl[row*DD + t+256] = l;
}

// ---------------- graph-structure helpers ----------------
__global__ void fill_int_kernel(int* p, int v, int n) {
  int i = blockIdx.x*256 + threadIdx.x;
  if (i < n) p[i] = v;
}
__global__ void count_deg_kernel(const int* __restrict__ dst, int* deg, int n) {
  int e = blockIdx.x*256 + threadIdx.x;
  if (e < n) atomicAdd(&deg[dst[e]], 1);
}
__global__ void dis_kernel(const int* __restrict__ deg, float* dis, int n) {
  int i = blockIdx.x*256+threadIdx.x;
  if (i < n) dis[i] = rsqrtf((float)deg[i]);
}
__global__ void coef0_kernel(const int* __restrict__ src, const int* __restrict__ dst,
                             const float* __restrict__ dis, float* coef) {
  int e = blockIdx.x*256+threadIdx.x;
  if (e < NEDGE) coef[e] = dis[src[e]]*dis[dst[e]];
}
__global__ void coef1_kernel(const int* __restrict__ src, const int* __restrict__ dst,
                             const int* __restrict__ keep,
                             const float* __restrict__ dis, float* coef) {
  int e = blockIdx.x*256+threadIdx.x;
  if (e < NEDGE) coef[e] = keep[e] ? dis[src[e]]*dis[dst[e]] : 0.f;
}

// ---------------- GCN aggregation; input = sum of split-K partials; self-slice-safe ----------------
__global__ __launch_bounds__(128) void gcn_agg_kernel(const int* __restrict__ src,
    const int* __restrict__ dst, const float* __restrict__ coef,
    const float* __restrict__ dis, const float* __restrict__ bias,
    const float* __restrict__ P, int nchunk, size_t mn,
    float* __restrict__ HWout, int NP, int relu,
    u16* __restrict__ outh, u16* __restrict__ outl) {
  int g = blockIdx.x >> 3;
  int c0 = (blockIdx.x & 7) * 64;
  int lane = threadIdx.x & 63, wv = threadIdx.x >> 6;
  __shared__ float hs[NNODE][64];
  __shared__ float as[2][NNODE][64];
  __shared__ int se[EPG], sd[EPG];
  __shared__ float scf[EPG];
  int base = g * NP;
  for (int i = wv; i < NP; i += 2) {
    float v = 0.f;
    for (int z = 0; z < nchunk; ++z)
      v += P[z*mn + (size_t)(base+i)*DD + c0 + lane];
    hs[i][lane] = v;
  }
  for (int i = 0; i < NP; ++i) as[wv][i][lane] = 0.f;
  int e0 = g * EPG;
  for (int e = threadIdx.x; e < EPG; e += 128) {
    se[e] = src[e0+e] - base;
    sd[e] = dst[e0+e] - base;
    scf[e] = coef[e0+e];
  }
  __syncthreads();
  int eb = wv * (EPG/2), ee = eb + (EPG/2);
  for (int e = eb; e < ee; ++e) {
    float cf = scf[e];
    if (cf != 0.f) as[wv][sd[e]][lane] += cf * hs[se[e]][lane];
  }
  __syncthreads();
  for (int i = wv; i < NP; i += 2) {
    float d = dis[base+i]; float d2 = d*d;
    float v = as[0][i][lane] + as[1][i][lane] + hs[i][lane]*d2 + bias[c0+lane];
    if (relu) v = fmaxf(v, 0.f);
    size_t o = (size_t)(base+i)*DD + c0 + lane;
    HWout[o] = v;
    if (outh) { u16 h, l; f2bsplit(v, h, l); outh[o] = h; outl[o] = l; }
  }
}

// ---------------- gemv: hs[i] = h[i,:] . w ----------------
__global__ __launch_bounds__(256) void gemv_kernel(const float* __restrict__ h,
    const float* __restrict__ wv, float* __restrict__ out, int n) {
  int node = blockIdx.x*4 + (threadIdx.x >> 6);
  int lane = threadIdx.x & 63;
  if (node >= n) return;
  const float* row = h + (size_t)node*DD;
  float acc = 0.f;
  for (int d = lane; d < DD; d += 64) acc += row[d]*wv[d];
  acc = wave_sum(acc);
  if (lane == 0) out[node] = acc;
}

// ---------------- SAGPool scalar score ----------------
__global__ __launch_bounds__(64) void score_kernel(const int* __restrict__ src,
    const int* __restrict__ dst, const float* __restrict__ coef,
    const float* __restrict__ dis, const float* __restrict__ hsv,
    const float* __restrict__ pb, float* __restrict__ sc, int NP) {
  int g = blockIdx.x;
  int lane = threadIdx.x;
  __shared__ float hss[NNODE], ag[NNODE];
  __shared__ int se[EPG], sd[EPG];
  __shared__ float scf[EPG];
  int base = g*NP;
  if (lane < NP) { hss[lane] = hsv[base+lane]; ag[lane] = 0.f; }
  int e0 = g*EPG;
  for (int e = lane; e < EPG; e += 64) {
    se[e] = src[e0+e]-base; sd[e] = dst[e0+e]-base; scf[e] = coef[e0+e];
  }
  __syncthreads();
  if (lane == 0) {
    for (int e = 0; e < EPG; ++e) {
      float cf = scf[e];
      if (cf != 0.f) ag[sd[e]] += cf*hss[se[e]];
    }
  }
  __syncthreads();
  if (lane < NP) {
    float d = dis[base+lane];
    sc[base+lane] = ag[lane] + hss[lane]*d*d + pb[0];
  }
}

// ---------------- per-graph top-k ----------------
__global__ __launch_bounds__(64) void topk_kernel(const float* __restrict__ sc,
    int* __restrict__ perm, int NP, int KK) {
  int g = blockIdx.x, lane = threadIdx.x;
  float v = (lane < NP) ? sc[g*NP+lane] : -FLT_MAX;
  for (int r = 0; r < KK; ++r) {
    float bv = v; int bi = lane;
    for (int off = 32; off; off >>= 1) {
      float ov = __shfl_xor(bv, off);
      int oi = __shfl_xor(bi, off);
      if (ov > bv || (ov == bv && oi < bi)) { bv = ov; bi = oi; }
    }
    if (lane == 0) perm[g*KK + r] = bi;
    if (lane == bi) v = -FLT_MAX;
  }
}

// ---------------- gather pooled ----------------
__global__ __launch_bounds__(256) void gather_kernel(const float* __restrict__ h,
    const float* __restrict__ sc, const int* __restrict__ perm,
    float* __restrict__ xn, u16* __restrict__ outh, u16* __restrict__ outl,
    int NP, int KK) {
  int j = blockIdx.x;
  int g = j / KK;
  int pi = perm[j];
  float t = tanhf(sc[g*NP + pi]);
  const float* srow = h + (size_t)(g*NP + pi)*DD;
  size_t o = (size_t)j*DD + threadIdx.x;
  float v0 = srow[threadIdx.x]*t;
  float v1 = srow[threadIdx.x+256]*t;
  xn[o] = v0; xn[o+256] = v1;
  if (outh) {
    u16 hh, ll;
    f2bsplit(v0, hh, ll); outh[o] = hh; outl[o] = ll;
    f2bsplit(v1, hh, ll); outh[o+256] = hh; outl[o+256] = ll;
  }
}

__global__ void nmap_scatter_kernel(const int* __restrict__ perm, int* __restrict__ nmap) {
  int j = blockIdx.x*256 + threadIdx.x;
  if (j < MG*KP1) nmap[(j/KP1)*NNODE + perm[j]] = j;
}

__global__ void filter_kernel(const int* __restrict__ src0, const int* __restrict__ dst0,
    const int* __restrict__ nmap, int* __restrict__ es, int* __restrict__ ed,
    int* __restrict__ keep, int* __restrict__ deg1) {
  int e = blockIdx.x*256+threadIdx.x;
  if (e >= NEDGE) return;
  int ns = nmap[src0[e]], nd = nmap[dst0[e]];
  int k = (ns >= 0) && (nd >= 0);
  es[e] = k ? ns : 0;
  ed[e] = k ? nd : 0;
  keep[e] = k;
  if (k) atomicAdd(&deg1[nd], 1);
}

// ---------------- readout: gmp || gap ----------------
__global__ __launch_bounds__(256) void readout_kernel(const float* __restrict__ h,
    float* __restrict__ z, int KK, int acc) {
  int g = blockIdx.x;
  for (int c = threadIdx.x; c < DD; c += 256) {
    float mx = -FLT_MAX, sm = 0.f;
    for (int r = 0; r < KK; ++r) {
      float v = h[(size_t)(g*KK+r)*DD + c];
      mx = fmaxf(mx, v); sm += v;
    }
    float mean = sm / (float)KK;
    if (acc) { z[(size_t)g*1024 + c] += mx; z[(size_t)g*1024 + 512 + c] += mean; }
    else     { z[(size_t)g*1024 + c]  = mx; z[(size_t)g*1024 + 512 + c]  = mean; }
  }
}

// ---------------- fused MLP head ----------------
__global__ __launch_bounds__(256) void mlp_kernel(const float* __restrict__ Z,
    const float* __restrict__ W1, const float* __restrict__ b1,
    const float* __restrict__ W2, const float* __restrict__ b2,
    const float* __restrict__ W3, const float* __restrict__ b3,
    float* __restrict__ out) {
  int g = blockIdx.x;
  __shared__ float z[1024];
  __shared__ float h1[512];
  __shared__ float h2[256];
  for (int i = threadIdx.x; i < 1024; i += 256) z[i] = Z[(size_t)g*1024 + i];
  __syncthreads();
  #pragma unroll
  for (int half = 0; half < 2; ++half) {
    int n = threadIdx.x + half*256;
    float a0 = 0.f, a1 = 0.f;
    for (int k = 0; k < 1024; k += 2) {
      a0 += z[k]   * W1[(size_t)k*512 + n];
      a1 += z[k+1] * W1[(size_t)(k+1)*512 + n];
    }
    h1[n] = fmaxf(a0 + a1 + b1[n], 0.f);
  }
  __syncthreads();
  {
    int n = threadIdx.x;
    float a0 = 0.f, a1 = 0.f;
    for (int k = 0; k < 512; k += 2) {
      a0 += h1[k]   * W2[(size_t)k*256 + n];
      a1 += h1[k+1] * W2[(size_t)(k+1)*256 + n];
    }
    h2[n] = fmaxf(a0 + a1 + b2[n], 0.f);
  }
  __syncthreads();
  int wv = threadIdx.x >> 6, lane = threadIdx.x & 63;
  if (wv < 2) {
    float acc = 0.f;
    for (int k = lane; k < 256; k += 64) acc += h2[k]*W3[(size_t)k*2 + wv];
    acc = wave_sum(acc);
    if (lane == 0) out[(size_t)g*2 + wv] = acc + b3[wv];
  }
}

extern "C" void kernel_launch(void* const* d_in, const int* in_sizes, int n_in,
                              void* d_out, int out_size, void* d_ws, size_t ws_size,
                              hipStream_t stream) {
  const float* x       = (const float*)d_in[0];
  const int*   edge    = (const int*)d_in[1];
  const float* bn_g    = (const float*)d_in[2];
  const float* bn_b    = (const float*)d_in[3];
  const float* W_emb   = (const float*)d_in[4];
  const float* Wqkv    = (const float*)d_in[5];
  const float* bqkv    = (const float*)d_in[6];
  const float* Wo      = (const float*)d_in[7];
  const float* bo      = (const float*)d_in[8];
  const float* W1      = (const float*)d_in[9];
  const float* b1      = (const float*)d_in[10];
  const float* W2      = (const float*)d_in[11];
  const float* b2      = (const float*)d_in[12];
  const float* g1      = (const float*)d_in[13];
  const float* be1     = (const float*)d_in[14];
  const float* g2      = (const float*)d_in[15];
  const float* be2     = (const float*)d_in[16];
  const float* W_emb1  = (const float*)d_in[17];
  const float* conv1_W = (const float*)d_in[18];
  const float* conv1_b = (const float*)d_in[19];
  const float* convs_W = (const float*)d_in[20];
  const float* convs_b = (const float*)d_in[21];
  const float* pool1_W = (const float*)d_in[22];
  const float* pool1_b = (const float*)d_in[23];
  const float* pool2_W = (const float*)d_in[24];
  const float* pool2_b = (const float*)d_in[25];
  const float* fc1_W   = (const float*)d_in[26];
  const float* fc1_b   = (const float*)d_in[27];
  const float* fc2_W   = (const float*)d_in[28];
  const float* fc2_b   = (const float*)d_in[29];
  const float* fc3_W   = (const float*)d_in[30];
  const float* fc3_b   = (const float*)d_in[31];
  (void)in_sizes; (void)n_in; (void)out_size; (void)ws_size;

  const int* srcp = edge;
  const int* dstp = edge + NEDGE;

  char* wsb = (char*)d_ws;
  size_t off = 0;
  auto alloc = [&](size_t bytes)->void* {
    void* p = wsb + off;
    off += (bytes + 255) & ~(size_t)255;
    return p;
  };
  const size_t MN = (size_t)NTOK*DD;
  float* T    = (float*)alloc(MN*4);
  size_t qkvB = (size_t)NTOK*3*DD*4, ffnB = (size_t)NTOK*DFF*2*2;
  char* BIGU  = (char*)alloc(qkvB > ffnB ? qkvB : ffnB);
  float* QKVf = (float*)BIGU;
  u16* BIGh   = (u16*)BIGU;
  u16* BIGl   = BIGh + (size_t)NTOK*DFF;
  float* PART = (float*)alloc(4*MN*4);          // 4 fp32 regions R0..R3
  u16* Th   = (u16*)alloc(MN*2);
  u16* Tl   = (u16*)alloc(MN*2);
  u16* ATh  = (u16*)alloc(MN*2);
  u16* ATl  = (u16*)alloc(MN*2);
  u16* Hh   = (u16*)alloc((size_t)MG*KP1*DD*2);
  u16* Hl   = (u16*)alloc((size_t)MG*KP1*DD*2);
  // per-layer (reused) transposed weights
  u16* WQh  = (u16*)alloc((size_t)1536*512*2);
  u16* WQl  = (u16*)alloc((size_t)1536*512*2);
  u16* WOh  = (u16*)alloc((size_t)512*512*2);
  u16* WOl  = (u16*)alloc((size_t)512*512*2);
  u16* W1h  = (u16*)alloc((size_t)2048*512*2);
  u16* W1l  = (u16*)alloc((size_t)2048*512*2);
  u16* W2h  = (u16*)alloc((size_t)512*2048*2);
  u16* W2l  = (u16*)alloc((size_t)512*2048*2);
  // GCN weights (persistent)
  float* WCf = (float*)alloc((size_t)512*512*4);
  u16* CTh  = (u16*)alloc((size_t)512*512*2);
  u16* CTl  = (u16*)alloc((size_t)512*512*2);
  u16* CVh  = (u16*)alloc((size_t)3*512*512*2);
  u16* CVl  = (u16*)alloc((size_t)3*512*512*2);
  float* MU   = (float*)alloc(NNODE*4);
  float* RS   = (float*)alloc(NNODE*4);
  int*   DEG0 = (int*)alloc(NTOK*4);
  float* DIS0 = (float*)alloc(NTOK*4);
  float* COEF0= (float*)alloc(NEDGE*4);
  float* HS   = (float*)alloc(NTOK*4);
  float* SC   = (float*)alloc(NTOK*4);
  int*   PERM1= (int*)alloc(MG*KP1*4);
  int*   NMAP = (int*)alloc(NTOK*4);
  int*   ES1  = (int*)alloc(NEDGE*4);
  int*   ED1  = (int*)alloc(NEDGE*4);
  int*   KEEP1= (int*)alloc(NEDGE*4);
  int*   DEG1 = (int*)alloc(MG*KP1*4);
  float* DIS1 = (float*)alloc(MG*KP1*4);
  float* COEF1= (float*)alloc(NEDGE*4);
  int*   PERM2= (int*)alloc(MG*KP2*4);
  float* Z    = (float*)alloc(MG*1024*4);

  float* PA = PART;                 // regions 0,1
  float* PB = PART + 2*MN;          // regions 2,3

  // ---- BN + embed + graph structure + GCN weight prep ----
  bn_stats_kernel<<<NNODE, 256, 0, stream>>>(x, MU, RS);
  embed_kernel<<<NTOK, 256, 0, stream>>>(x, MU, RS, bn_g, bn_b, W_emb, T, Th, Tl);
  fill_int_kernel<<<(NTOK+255)/256, 256, 0, stream>>>(DEG0, 1, NTOK);
  count_deg_kernel<<<(NEDGE+255)/256, 256, 0, stream>>>(dstp, DEG0, NEDGE);
  dis_kernel<<<(NTOK+255)/256, 256, 0, stream>>>(DEG0, DIS0, NTOK);
  coef0_kernel<<<(NEDGE+255)/256, 256, 0, stream>>>(srcp, dstp, DIS0, COEF0);
  // Wcomb = W_emb1[512x62] @ conv1_W[62x512]  (exact fp32; associativity shift ~1e-6)
  gemm_kernel<<<dim3(8,8), 256, 0, stream>>>(W_emb1, conv1_W, WCf, 512, 512, NNODE);
  gcnT_kernel<<<256, 256, 0, stream>>>(WCf, convs_W, CTh, CTl, CVh, CVl);

  // ---- transformer encoder ----
  for (int l = 0; l < NLAYER; ++l) {
    layerT_kernel<<<768, 256, 0, stream>>>(
        Wqkv + (size_t)l*DD*3*DD, Wo + (size_t)l*DD*DD,
        W1 + (size_t)l*DD*DFF, W2 + (size_t)l*DFF*DD,
        WQh, WQl, WOh, WOl, W1h, W1l, W2h, W2l);
    gemm3_kernel<false,0><<<dim3(12,62,1), 256, 0, stream>>>(Th, Tl, WQh, WQl,
        bqkv + (size_t)l*3*DD, QKVf, nullptr, nullptr, 3*DD, 3*DD, DD, DD);
    attn_kernel<<<MG*NH, 256, 0, stream>>>(QKVf, ATh, ATl);
    gemm3_kernel<false,0><<<dim3(4,62,2), 256, 0, stream>>>(ATh, ATl, WOh, WOl,
        bo + (size_t)l*DD, PART, nullptr, nullptr, DD, DD, DD, 256);
    add_ln_kernel<<<NTOK, 256, 0, stream>>>(T, PART, 2,
        g1 + (size_t)l*DD, be1 + (size_t)l*DD, Th, Tl);
    gemm3_kernel<true,1><<<dim3(16,62,1), 256, 0, stream>>>(Th, Tl, W1h, W1l,
        b1 + (size_t)l*DFF, nullptr, BIGh, BIGl, DFF, DFF, DD, DD);
    gemm3_kernel<false,0><<<dim3(4,62,4), 256, 0, stream>>>(BIGh, BIGl, W2h, W2l,
        b2 + (size_t)l*DD, PART, nullptr, nullptr, DD, DD, DFF, 512);
    add_ln_kernel<<<NTOK, 256, 0, stream>>>(T, PART, 4,
        g2 + (size_t)l*DD, be2 + (size_t)l*DD, Th, Tl);
  }

  // ---- conv1 = t @ Wcomb (+agg +relu); h fp32 -> R0 (self-slice safe) ----
  gemm3_kernel<false,0><<<dim3(4,62,2), 256, 0, stream>>>(Th, Tl, CTh, CTl,
      nullptr, PA, nullptr, nullptr, DD, DD, DD, 256);
  gcn_agg_kernel<<<MG*8, 128, 0, stream>>>(srcp, dstp, COEF0, DIS0, conv1_b,
      PA, 2, MN, PA, NNODE, 1, nullptr, nullptr);

  // ---- SAGPool 1 ----
  gemv_kernel<<<(NTOK+3)/4, 256, 0, stream>>>(PA, pool1_W, HS, NTOK);
  score_kernel<<<MG, 64, 0, stream>>>(srcp, dstp, COEF0, DIS0, HS, pool1_b, SC, NNODE);
  topk_kernel<<<MG, 64, 0, stream>>>(SC, PERM1, NNODE, KP1);
  gather_kernel<<<MG*KP1, 256, 0, stream>>>(PA, SC, PERM1, PA + MN, Hh, Hl, NNODE, KP1);
  readout_kernel<<<MG, 256, 0, stream>>>(PA + MN, Z, KP1, 0);

  // ---- filter_adj ----
  fill_int_kernel<<<(NTOK+255)/256, 256, 0, stream>>>(NMAP, -1, NTOK);
  nmap_scatter_kernel<<<(MG*KP1+255)/256, 256, 0, stream>>>(PERM1, NMAP);
  fill_int_kernel<<<(MG*KP1+255)/256, 256, 0, stream>>>(DEG1, 1, MG*KP1);
  filter_kernel<<<(NEDGE+255)/256, 256, 0, stream>>>(srcp, dstp, NMAP, ES1, ED1, KEEP1, DEG1);
  dis_kernel<<<(MG*KP1+255)/256, 256, 0, stream>>>(DEG1, DIS1, MG*KP1);
  coef1_kernel<<<(NEDGE+255)/256, 256, 0, stream>>>(ES1, ED1, KEEP1, DIS1, COEF1);

  // ---- 3 GCN layers on pooled graph (M=6400); partials ping-pong PB/PA ----
  const size_t MNP = (size_t)MG*KP1*DD;
  float* bases[3] = { PB, PA, PB };
  float* hfin = nullptr;
  for (int l = 0; l < NLAYER-1; ++l) {
    float* Pb = bases[l];
    gemm3_kernel<false,0><<<dim3(4,50,2), 256, 0, stream>>>(Hh, Hl, CVh + (size_t)l*DD*DD,
        CVl + (size_t)l*DD*DD, nullptr, Pb, nullptr, nullptr, DD, DD, DD, 256);
    gcn_agg_kernel<<<MG*8, 128, 0, stream>>>(ES1, ED1, COEF1, DIS1, convs_b + (size_t)l*DD,
        Pb, 2, MNP, Pb, KP1, 1, (l < NLAYER-2) ? Hh : nullptr, (l < NLAYER-2) ? Hl : nullptr);
    hfin = Pb;
  }

  // ---- SAGPool 2 ----
  gemv_kernel<<<(MG*KP1+3)/4, 256, 0, stream>>>(hfin, pool2_W, HS, MG*KP1);
  score_kernel<<<MG, 64, 0, stream>>>(ES1, ED1, COEF1, DIS1, HS, pool2_b, SC, KP1);
  topk_kernel<<<MG, 64, 0, stream>>>(SC, PERM2, KP1, KP2);
  gather_kernel<<<MG*KP2, 256, 0, stream>>>(hfin, SC, PERM2, PA, nullptr, nullptr, KP1, KP2);
  readout_kernel<<<MG, 256, 0, stream>>>(PA, Z, KP2, 1);

  // ---- fused MLP head ----
  mlp_kernel<<<MG, 256, 0, stream>>>(Z, fc1_W, fc1_b, fc2_W, fc2_b, fc3_W, fc3_b, (float*)d_out);
}

// Round 5
// 1925.452 us; speedup vs baseline: 3.4251x; 1.2044x over previous
//
#include <hip/hip_runtime.h>
#include <float.h>
#include <math.h>

#define MG 128
#define NNODE 62
#define DD 512
#define NH 8
#define DH 64
#define DFF 2048
#define NLAYER 4
#define EPG 600
#define KP1 50
#define KP2 40
#define NTOK (MG*NNODE)      // 7936
#define NEDGE (MG*EPG)       // 76800
#define EPSV 1e-5f

typedef unsigned short u16;
using bf16x8 = __attribute__((ext_vector_type(8))) short;
using f32x4  = __attribute__((ext_vector_type(4))) float;

__device__ __forceinline__ float wave_sum(float v) {
  for (int off = 32; off; off >>= 1) v += __shfl_xor(v, off);
  return v;
}
__device__ __forceinline__ float wave_max(float v) {
  for (int off = 32; off; off >>= 1) v = fmaxf(v, __shfl_xor(v, off));
  return v;
}
__device__ __forceinline__ u16 f2b(float x) {
  union { float f; unsigned u; } v; v.f = x;
  unsigned r = v.u + 0x7fffu + ((v.u >> 16) & 1u);
  return (u16)(r >> 16);
}
__device__ __forceinline__ float b2f(u16 h) {
  union { float f; unsigned u; } v; v.u = ((unsigned)h) << 16;
  return v.f;
}
__device__ __forceinline__ void f2bsplit(float x, u16& h, u16& l) {
  h = f2b(x);
  l = f2b(x - b2f(h));
}
__device__ __forceinline__ void load_lds16(const u16* g, u16* l) {
  __builtin_amdgcn_global_load_lds(
      (const __attribute__((address_space(1))) unsigned int*)(const void*)g,
      (__attribute__((address_space(3))) unsigned int*)(void*)l, 16, 0, 0);
}

// ---------------- BatchNorm stats ----------------
__global__ __launch_bounds__(256) void bn_stats_kernel(const float* __restrict__ x,
    float* __restrict__ mu, float* __restrict__ rs) {
  int s = blockIdx.x;
  float sum = 0.f, sq = 0.f;
  for (int i = threadIdx.x; i < MG*NNODE; i += 256) {
    int b = i / NNODE, j = i - b*NNODE;
    float v = x[(size_t)(b*NNODE + s)*NNODE + j];
    sum += v; sq += v*v;
  }
  __shared__ float r1[4], r2[4];
  sum = wave_sum(sum); sq = wave_sum(sq);
  int wv = threadIdx.x >> 6, lane = threadIdx.x & 63;
  if (lane == 0) { r1[wv] = sum; r2[wv] = sq; }
  __syncthreads();
  if (threadIdx.x == 0) {
    float S = r1[0]+r1[1]+r1[2]+r1[3];
    float Q = r2[0]+r2[1]+r2[2]+r2[3];
    float m = S / (float)(MG*NNODE);
    float var = Q / (float)(MG*NNODE) - m*m;
    mu[s] = m;
    rs[s] = rsqrtf(var + EPSV);
  }
}

// ---------------- embed: T fp32 + split bf16 ----------------
__global__ __launch_bounds__(256) void embed_kernel(const float* __restrict__ x,
    const float* __restrict__ mu, const float* __restrict__ rs,
    const float* __restrict__ gg, const float* __restrict__ bb,
    const float* __restrict__ W, float* __restrict__ T,
    u16* __restrict__ Th, u16* __restrict__ Tl) {
  int tok = blockIdx.x;
  int s = tok >> 7, b = tok & 127;
  __shared__ float xb[NNODE];
  if (threadIdx.x < NNODE) {
    float v = x[(size_t)(b*NNODE + s)*NNODE + threadIdx.x];
    xb[threadIdx.x] = (v - mu[s]) * rs[s] * gg[s] + bb[s];
  }
  __syncthreads();
  int d = threadIdx.x;
  float a0 = 0.f, a1 = 0.f;
  for (int j = 0; j < NNODE; ++j) {
    float xv = xb[j];
    a0 += xv * W[(size_t)j*DD + d];
    a1 += xv * W[(size_t)j*DD + d + 256];
  }
  size_t o = (size_t)tok*DD + d;
  T[o] = a0; T[o+256] = a1;
  u16 h, l;
  f2bsplit(a0, h, l); Th[o] = h; Tl[o] = l;
  f2bsplit(a1, h, l); Th[o+256] = h; Tl[o+256] = l;
}

// ---------------- fp32 GEMM (only for Wcomb = W_emb1 @ conv1_W) ----------------
__global__ __launch_bounds__(256) void gemm_kernel(const float* __restrict__ A,
    const float* __restrict__ B, float* __restrict__ C, int M, int N, int K) {
  __shared__ float As[16][68];
  __shared__ float Bs[16][68];
  int bm = blockIdx.y * 64, bn = blockIdx.x * 64;
  int tid = threadIdx.x;
  int tx = tid & 15, ty = tid >> 4;
  float acc[4][4] = {};
  for (int k0 = 0; k0 < K; k0 += 16) {
    {
      int row = tid >> 2; int kk = (tid & 3) * 4;
      int gm = bm + row;
      #pragma unroll
      for (int i = 0; i < 4; ++i) {
        int gk = k0 + kk + i;
        As[kk+i][row] = (gm < M && gk < K) ? A[(size_t)gm*K + gk] : 0.f;
      }
    }
    {
      int krow = tid >> 4; int nn = (tid & 15) * 4;
      int gk = k0 + krow;
      #pragma unroll
      for (int i = 0; i < 4; ++i) {
        int gn = bn + nn + i;
        Bs[krow][nn+i] = (gk < K && gn < N) ? B[(size_t)gk*N + gn] : 0.f;
      }
    }
    __syncthreads();
    #pragma unroll
    for (int k = 0; k < 16; ++k) {
      float a[4], bb2[4];
      #pragma unroll
      for (int i = 0; i < 4; ++i) a[i] = As[k][ty*4+i];
      #pragma unroll
      for (int j = 0; j < 4; ++j) bb2[j] = Bs[k][tx*4+j];
      #pragma unroll
      for (int i = 0; i < 4; ++i)
        #pragma unroll
        for (int j = 0; j < 4; ++j) acc[i][j] += a[i]*bb2[j];
    }
    __syncthreads();
  }
  #pragma unroll
  for (int i = 0; i < 4; ++i) {
    int gm = bm + ty*4 + i;
    if (gm >= M) continue;
    #pragma unroll
    for (int j = 0; j < 4; ++j) {
      int gn = bn + tx*4 + j;
      if (gn >= N) continue;
      C[(size_t)gm*N + gn] = acc[i][j];
    }
  }
}

// ---------------- transpose+split tile helper ----------------
__device__ __forceinline__ void transpose_split_tile(const float* __restrict__ W,
    u16* __restrict__ th, u16* __restrict__ tl,
    int K, int N, int Kp, int bx, int by, float (*t)[65]) {
  int k0 = by*64, n0 = bx*64;
  for (int i = threadIdx.x; i < 64*64; i += 256) {
    int r = i >> 6, c = i & 63;
    int gk = k0 + r, gn = n0 + c;
    t[r][c] = (gk < K && gn < N) ? W[(size_t)gk*N + gn] : 0.f;
  }
  __syncthreads();
  for (int i = threadIdx.x; i < 64*64; i += 256) {
    int r = i >> 6, c = i & 63;
    int gn = n0 + r, gk = k0 + c;
    u16 h, l; f2bsplit(t[c][r], h, l);
    th[(size_t)gn*Kp + gk] = h;
    tl[(size_t)gn*Kp + gk] = l;
  }
}

// ---------------- per-layer batched weight transpose ----------------
__global__ __launch_bounds__(256) void layerT_kernel(
    const float* __restrict__ Wqkv, const float* __restrict__ Wo,
    const float* __restrict__ W1, const float* __restrict__ W2,
    u16* WQh, u16* WQl, u16* WOh, u16* WOl,
    u16* W1h, u16* W1l, u16* W2h, u16* W2l) {
  __shared__ float t[64][65];
  int b = blockIdx.x;
  if (b < 192)      transpose_split_tile(Wqkv, WQh, WQl, 512, 1536, 512, b % 24, b / 24, t);
  else if (b < 256) { int q = b - 192; transpose_split_tile(Wo, WOh, WOl, 512, 512, 512, q % 8, q / 8, t); }
  else if (b < 512) { int q = b - 256; transpose_split_tile(W1, W1h, W1l, 512, 2048, 512, q % 32, q / 32, t); }
  else              { int q = b - 512; transpose_split_tile(W2, W2h, W2l, 2048, 512, 2048, q % 8, q / 8, t); }
}

// ---------------- GCN weights transpose (Wcomb, convs_W[0..2]) ----------------
__global__ __launch_bounds__(256) void gcnT_kernel(
    const float* __restrict__ WC, const float* __restrict__ convs_W,
    u16* CTh, u16* CTl, u16* CVh, u16* CVl) {
  __shared__ float t[64][65];
  int job = blockIdx.x >> 6, q = blockIdx.x & 63;
  int bx = q % 8, by = q / 8;
  if (job == 0) transpose_split_tile(WC, CTh, CTl, 512, 512, 512, bx, by, t);
  else {
    int l = job - 1;
    transpose_split_tile(convs_W + (size_t)l*DD*DD,
        CVh + (size_t)l*DD*DD, CVl + (size_t)l*DD*DD, 512, 512, 512, bx, by, t);
  }
}

// ---------------- split-bf16 MFMA GEMM, global_load_lds + XOR swizzle, split-K ----------------
template<bool RELU, int OUTMODE>
__global__ __launch_bounds__(256) void gemm3_kernel(
    const u16* __restrict__ Ah, const u16* __restrict__ Al,
    const u16* __restrict__ Bh, const u16* __restrict__ Bl,
    const float* __restrict__ bias,
    float* __restrict__ Cf, u16* __restrict__ Ch, u16* __restrict__ Cl,
    int Nreal, int Nstride, int Kp, int KC) {
  __shared__ alignas(16) u16 sAh[128*32];
  __shared__ alignas(16) u16 sAl[128*32];
  __shared__ alignas(16) u16 sBh[128*32];
  __shared__ alignas(16) u16 sBl[128*32];
  int bm = blockIdx.y * 128, bn = blockIdx.x * 128;
  int z = blockIdx.z;
  int tid = threadIdx.x;
  int wv = tid >> 6, lane = tid & 63;
  int wr = (wv >> 1) * 64, wc = (wv & 1) * 64;
  f32x4 acc[4][4];
  #pragma unroll
  for (int i = 0; i < 4; ++i)
    #pragma unroll
    for (int j = 0; j < 4; ++j) acc[i][j] = (f32x4){0.f,0.f,0.f,0.f};

  int r0 = tid >> 2;
  int lin = (tid & 3) * 8;
  int c0 = lin ^ (((r0 >> 1) & 3) << 3);
  int r1 = r0 + 64;
  int c1 = lin ^ (((r1 >> 1) & 3) << 3);
  int fr = lane & 15, fo = (lane >> 4) * 8;

  int kbeg = z * KC, kend = kbeg + KC;
  for (int k0 = kbeg; k0 < kend; k0 += 32) {
    size_t a0 = (size_t)(bm + r0)*Kp + k0 + c0;
    size_t a1 = (size_t)(bm + r1)*Kp + k0 + c1;
    size_t b0 = (size_t)(bn + r0)*Kp + k0 + c0;
    size_t b1 = (size_t)(bn + r1)*Kp + k0 + c1;
    load_lds16(Ah + a0, &sAh[tid*8]);
    load_lds16(Ah + a1, &sAh[2048 + tid*8]);
    load_lds16(Al + a0, &sAl[tid*8]);
    load_lds16(Al + a1, &sAl[2048 + tid*8]);
    load_lds16(Bh + b0, &sBh[tid*8]);
    load_lds16(Bh + b1, &sBh[2048 + tid*8]);
    load_lds16(Bl + b0, &sBl[tid*8]);
    load_lds16(Bl + b1, &sBl[2048 + tid*8]);
    __syncthreads();
    bf16x8 ah[4], al[4], bh[4], bl[4];
    #pragma unroll
    for (int i = 0; i < 4; ++i) {
      int ra = wr + i*16 + fr;
      int ea = ra*32 + (fo ^ (((ra >> 1) & 3) << 3));
      ah[i] = *(const bf16x8*)&sAh[ea];
      al[i] = *(const bf16x8*)&sAl[ea];
      int rb = wc + i*16 + fr;
      int eb = rb*32 + (fo ^ (((rb >> 1) & 3) << 3));
      bh[i] = *(const bf16x8*)&sBh[eb];
      bl[i] = *(const bf16x8*)&sBl[eb];
    }
    #pragma unroll
    for (int i = 0; i < 4; ++i)
      #pragma unroll
      for (int j = 0; j < 4; ++j) {
        acc[i][j] = __builtin_amdgcn_mfma_f32_16x16x32_bf16(ah[i], bh[j], acc[i][j], 0, 0, 0);
        acc[i][j] = __builtin_amdgcn_mfma_f32_16x16x32_bf16(ah[i], bl[j], acc[i][j], 0, 0, 0);
        acc[i][j] = __builtin_amdgcn_mfma_f32_16x16x32_bf16(al[i], bh[j], acc[i][j], 0, 0, 0);
      }
    __syncthreads();
  }
  size_t pstride = (size_t)gridDim.y * 128 * Nstride;
  int cr = (lane >> 4) * 4, cc = lane & 15;
  #pragma unroll
  for (int i = 0; i < 4; ++i) {
    #pragma unroll
    for (int j = 0; j < 4; ++j) {
      int gn = bn + wc + j*16 + cc;
      if (gn >= Nstride) continue;
      #pragma unroll
      for (int q = 0; q < 4; ++q) {
        int gm = bm + wr + i*16 + cr + q;
        float v = acc[i][j][q];
        if (gn < Nreal) { if (bias && z == 0) v += bias[gn]; } else v = 0.f;
        if (RELU) v = fmaxf(v, 0.f);
        size_t o = (size_t)z*pstride + (size_t)gm*Nstride + gn;
        if (OUTMODE == 0) {
          Cf[o] = v;
        } else {
          u16 h, l; f2bsplit(v, h, l);
          Ch[o] = h; Cl[o] = l;
        }
      }
    }
  }
}

// ---------------- fused attention per (b,h) ----------------
__global__ __launch_bounds__(256) void attn_kernel(const float* __restrict__ QKV,
    u16* __restrict__ Oh, u16* __restrict__ Ol) {
  int b = blockIdx.x >> 3, h = blockIdx.x & 7;
  __shared__ float qs[NNODE][DH+1];
  __shared__ float ks[NNODE][DH+1];
  __shared__ float ps[NNODE][DH+1];
  for (int i = threadIdx.x; i < NNODE*DH; i += 256) {
    int s = i >> 6, d = i & 63;
    size_t base = ((size_t)(s*MG + b))*(3*DD) + h*DH + d;
    qs[s][d] = QKV[base];
    ks[s][d] = QKV[base + DD];
  }
  __syncthreads();
  int lane = threadIdx.x & 63, wv = threadIdx.x >> 6;
  for (int s = wv; s < NNODE; s += 4) {
    float acc = -FLT_MAX;
    if (lane < NNODE) {
      float a = 0.f;
      #pragma unroll
      for (int d = 0; d < DH; ++d) a += qs[s][d]*ks[lane][d];
      acc = a * 0.125f;
    }
    float mx = wave_max(acc);
    float e = (lane < NNODE) ? expf(acc - mx) : 0.f;
    float sm = wave_sum(e);
    ps[s][lane] = e / sm;
  }
  __syncthreads();
  for (int i = threadIdx.x; i < NNODE*DH; i += 256) {
    int s = i >> 6, d = i & 63;
    qs[s][d] = QKV[((size_t)(s*MG + b))*(3*DD) + 2*DD + h*DH + d];
  }
  __syncthreads();
  for (int s = wv; s < NNODE; s += 4) {
    float acc = 0.f;
    for (int t = 0; t < NNODE; ++t) acc += ps[s][t]*qs[t][lane];
    size_t o = ((size_t)(s*MG + b))*DD + h*DH + lane;
    u16 hh, ll; f2bsplit(acc, hh, ll);
    Oh[o] = hh; Ol[o] = ll;
  }
}

// ---------------- X = LayerNorm(X + sum_z PART[z]) ----------------
__global__ __launch_bounds__(256) void add_ln_kernel(float* __restrict__ X,
    const float* __restrict__ P, int nchunk,
    const float* __restrict__ gg, const float* __restrict__ bb,
    u16* __restrict__ Xh, u16* __restrict__ Xl) {
  size_t row = blockIdx.x;
  int t = threadIdx.x;
  const size_t MN = (size_t)NTOK*DD;
  float r0 = 0.f, r1 = 0.f;
  for (int z = 0; z < nchunk; ++z) {
    r0 += P[z*MN + row*DD + t];
    r1 += P[z*MN + row*DD + t + 256];
  }
  float v0 = X[row*DD + t] + r0;
  float v1 = X[row*DD + t + 256] + r1;
  __shared__ float red[4];
  float s = wave_sum(v0 + v1);
  int wv = t >> 6, lane = t & 63;
  if (lane == 0) red[wv] = s;
  __syncthreads();
  float mu = (red[0]+red[1]+red[2]+red[3]) * (1.f/DD);
  float d0 = v0 - mu, d1 = v1 - mu;
  float q = wave_sum(d0*d0 + d1*d1);
  __syncthreads();
  if (lane == 0) red[wv] = q;
  __syncthreads();
  float var = (red[0]+red[1]+red[2]+red[3]) * (1.f/DD);
  float rs = rsqrtf(var + EPSV);
  float o0 = d0*rs*gg[t] + bb[t];
  float o1 = d1*rs*gg[t+256] + bb[t+256];
  X[row*DD + t] = o0;
  X[row*DD + t+256] = o1;
  u16 h, l;
  f2bsplit(o0, h, l); Xh[row*DD + t] = h; Xl[row*DD + t] = l;
  f2bsplit(o1, h, l); Xh[row*DD + t+256] = h; Xl[row*DD + t+256] = l;
}

// ---------------- graph-structure helpers ----------------
__global__ void fill_int_kernel(int* p, int v, int n) {
  int i = blockIdx.x*256 + threadIdx.x;
  if (i < n) p[i] = v;
}
__global__ void zero_f_kernel(float* p, int n) {
  int i = blockIdx.x*256 + threadIdx.x;
  if (i < n) p[i] = 0.f;
}
__global__ void count_deg_kernel(const int* __restrict__ dst, int* deg, int n) {
  int e = blockIdx.x*256 + threadIdx.x;
  if (e < n) atomicAdd(&deg[dst[e]], 1);
}
__global__ void dis_kernel(const int* __restrict__ deg, float* dis, int n) {
  int i = blockIdx.x*256+threadIdx.x;
  if (i < n) dis[i] = rsqrtf((float)deg[i]);
}
__global__ void coef0_kernel(const int* __restrict__ src, const int* __restrict__ dst,
                             const float* __restrict__ dis, float* coef) {
  int e = blockIdx.x*256+threadIdx.x;
  if (e < NEDGE) coef[e] = dis[src[e]]*dis[dst[e]];
}
__global__ void coef1_kernel(const int* __restrict__ src, const int* __restrict__ dst,
                             const int* __restrict__ keep,
                             const float* __restrict__ dis, float* coef) {
  int e = blockIdx.x*256+threadIdx.x;
  if (e < NEDGE) coef[e] = keep[e] ? dis[src[e]]*dis[dst[e]] : 0.f;
}

// ---------------- dense per-graph normalized adjacency build ----------------
// AG layout: [MG][64][64] row-major (row = dst, col = src). Deterministic:
// all atomicAdd contributions to one cell are bitwise-identical values.
__global__ __launch_bounds__(64) void diagA_kernel(const float* __restrict__ dis,
    float* __restrict__ AG, int NP) {
  int g = blockIdx.x, lane = threadIdx.x;
  if (lane < NP) {
    float d = dis[g*NP + lane];
    AG[(size_t)g*4096 + lane*64 + lane] = d*d;
  }
}
__global__ __launch_bounds__(256) void edgeA_kernel(const int* __restrict__ src,
    const int* __restrict__ dst, const float* __restrict__ coef,
    float* __restrict__ AG, int NP) {
  int e = blockIdx.x*256 + threadIdx.x;
  if (e >= NEDGE) return;
  float c = coef[e];
  if (c == 0.f) return;
  int g = e / EPG;
  int ls = src[e] - g*NP, ld = dst[e] - g*NP;
  atomicAdd(&AG[(size_t)g*4096 + ld*64 + ls], c);
}

// ---------------- dense GCN aggregation: out = A~ @ (sum_z P[z]) + bias (relu) ----------------
// block = (graph, 64-col tile); A~ transposed in LDS (stride 68, 16B-aligned b128 rows)
__global__ __launch_bounds__(256) void dense_agg_kernel(
    const float* __restrict__ AG,
    const float* __restrict__ P, int nchunk, size_t mn,
    const float* __restrict__ bias,
    float* __restrict__ Hout, int NP, int relu,
    u16* __restrict__ outh, u16* __restrict__ outl) {
  int g = blockIdx.x >> 3;
  int ct = (blockIdx.x & 7) * 64;
  __shared__ float hls[64*64];     // [j][c] row-major
  __shared__ float At[64*68];      // [j][i] transposed, pad 68
  int base = g * NP;
  for (int idx = threadIdx.x; idx < 64*64; idx += 256) {
    int r = idx >> 6, c = idx & 63;   // r = node row, c = col within tile
    float v = 0.f;
    if (r < NP) {
      for (int z = 0; z < nchunk; ++z)
        v += P[z*mn + (size_t)(base+r)*DD + ct + c];
    }
    hls[idx] = v;
    At[c*68 + r] = AG[(size_t)g*4096 + idx];   // At[j=c][i=r]
  }
  __syncthreads();
  int wv = threadIdx.x >> 6, lane = threadIdx.x & 63;
  int i0 = wv * 16;
  f32x4 acc[4];
  #pragma unroll
  for (int q = 0; q < 4; ++q) acc[q] = (f32x4){0.f,0.f,0.f,0.f};
  for (int j = 0; j < NP; ++j) {
    float hv = hls[j*64 + lane];
    const f32x4* ap = (const f32x4*)&At[j*68 + i0];
    f32x4 a0 = ap[0], a1 = ap[1], a2 = ap[2], a3 = ap[3];
    #pragma unroll
    for (int t = 0; t < 4; ++t) {
      acc[0][t] += a0[t] * hv;
      acc[1][t] += a1[t] * hv;
      acc[2][t] += a2[t] * hv;
      acc[3][t] += a3[t] * hv;
    }
  }
  float bv = bias[ct + lane];
  #pragma unroll
  for (int q = 0; q < 4; ++q) {
    #pragma unroll
    for (int t = 0; t < 4; ++t) {
      int i = i0 + q*4 + t;
      if (i < NP) {
        float v = acc[q][t] + bv;
        if (relu) v = fmaxf(v, 0.f);
        size_t o = (size_t)(base+i)*DD + ct + lane;
        Hout[o] = v;
        if (outh) { u16 h, l; f2bsplit(v, h, l); outh[o] = h; outl[o] = l; }
      }
    }
  }
}

// ---------------- dense SAGPool score: sc = A~ @ hs + b ----------------
__global__ __launch_bounds__(64) void dense_score_kernel(
    const float* __restrict__ AG, const float* __restrict__ hsv,
    const float* __restrict__ pb, float* __restrict__ sc, int NP) {
  int g = blockIdx.x, lane = threadIdx.x;
  __shared__ float hls[64];
  __shared__ float At[64*65];
  hls[lane] = (lane < NP) ? hsv[g*NP + lane] : 0.f;
  for (int idx = lane; idx < 64*64; idx += 64) {
    int i = idx >> 6, j = idx & 63;
    At[j*65 + i] = AG[(size_t)g*4096 + idx];
  }
  __syncthreads();
  if (lane < NP) {
    float acc = 0.f;
    for (int j = 0; j < NP; ++j) acc += At[j*65 + lane] * hls[j];
    sc[g*NP + lane] = acc + pb[0];
  }
}

// ---------------- gemv: hs[i] = h[i,:] . w ----------------
__global__ __launch_bounds__(256) void gemv_kernel(const float* __restrict__ h,
    const float* __restrict__ wv, float* __restrict__ out, int n) {
  int node = blockIdx.x*4 + (threadIdx.x >> 6);
  int lane = threadIdx.x & 63;
  if (node >= n) return;
  const float* row = h + (size_t)node*DD;
  float acc = 0.f;
  for (int d = lane; d < DD; d += 64) acc += row[d]*wv[d];
  acc = wave_sum(acc);
  if (lane == 0) out[node] = acc;
}

// ---------------- per-graph top-k ----------------
__global__ __launch_bounds__(64) void topk_kernel(const float* __restrict__ sc,
    int* __restrict__ perm, int NP, int KK) {
  int g = blockIdx.x, lane = threadIdx.x;
  float v = (lane < NP) ? sc[g*NP+lane] : -FLT_MAX;
  for (int r = 0; r < KK; ++r) {
    float bv = v; int bi = lane;
    for (int off = 32; off; off >>= 1) {
      float ov = __shfl_xor(bv, off);
      int oi = __shfl_xor(bi, off);
      if (ov > bv || (ov == bv && oi < bi)) { bv = ov; bi = oi; }
    }
    if (lane == 0) perm[g*KK + r] = bi;
    if (lane == bi) v = -FLT_MAX;
  }
}

// ---------------- gather pooled ----------------
__global__ __launch_bounds__(256) void gather_kernel(const float* __restrict__ h,
    const float* __restrict__ sc, const int* __restrict__ perm,
    float* __restrict__ xn, u16* __restrict__ outh, u16* __restrict__ outl,
    int NP, int KK) {
  int j = blockIdx.x;
  int g = j / KK;
  int pi = perm[j];
  float t = tanhf(sc[g*NP + pi]);
  const float* srow = h + (size_t)(g*NP + pi)*DD;
  size_t o = (size_t)j*DD + threadIdx.x;
  float v0 = srow[threadIdx.x]*t;
  float v1 = srow[threadIdx.x+256]*t;
  xn[o] = v0; xn[o+256] = v1;
  if (outh) {
    u16 hh, ll;
    f2bsplit(v0, hh, ll); outh[o] = hh; outl[o] = ll;
    f2bsplit(v1, hh, ll); outh[o+256] = hh; outl[o+256] = ll;
  }
}

__global__ void nmap_scatter_kernel(const int* __restrict__ perm, int* __restrict__ nmap) {
  int j = blockIdx.x*256 + threadIdx.x;
  if (j < MG*KP1) nmap[(j/KP1)*NNODE + perm[j]] = j;
}

__global__ void filter_kernel(const int* __restrict__ src0, const int* __restrict__ dst0,
    const int* __restrict__ nmap, int* __restrict__ es, int* __restrict__ ed,
    int* __restrict__ keep, int* __restrict__ deg1) {
  int e = blockIdx.x*256+threadIdx.x;
  if (e >= NEDGE) return;
  int ns = nmap[src0[e]], nd = nmap[dst0[e]];
  int k = (ns >= 0) && (nd >= 0);
  es[e] = k ? ns : 0;
  ed[e] = k ? nd : 0;
  keep[e] = k;
  if (k) atomicAdd(&deg1[nd], 1);
}

// ---------------- readout: gmp || gap ----------------
__global__ __launch_bounds__(256) void readout_kernel(const float* __restrict__ h,
    float* __restrict__ z, int KK, int acc) {
  int g = blockIdx.x;
  for (int c = threadIdx.x; c < DD; c += 256) {
    float mx = -FLT_MAX, sm = 0.f;
    for (int r = 0; r < KK; ++r) {
      float v = h[(size_t)(g*KK+r)*DD + c];
      mx = fmaxf(mx, v); sm += v;
    }
    float mean = sm / (float)KK;
    if (acc) { z[(size_t)g*1024 + c] += mx; z[(size_t)g*1024 + 512 + c] += mean; }
    else     { z[(size_t)g*1024 + c]  = mx; z[(size_t)g*1024 + 512 + c]  = mean; }
  }
}

// ---------------- fused MLP head ----------------
__global__ __launch_bounds__(256) void mlp_kernel(const float* __restrict__ Z,
    const float* __restrict__ W1, const float* __restrict__ b1,
    const float* __restrict__ W2, const float* __restrict__ b2,
    const float* __restrict__ W3, const float* __restrict__ b3,
    float* __restrict__ out) {
  int g = blockIdx.x;
  __shared__ float z[1024];
  __shared__ float h1[512];
  __shared__ float h2[256];
  for (int i = threadIdx.x; i < 1024; i += 256) z[i] = Z[(size_t)g*1024 + i];
  __syncthreads();
  #pragma unroll
  for (int half = 0; half < 2; ++half) {
    int n = threadIdx.x + half*256;
    float a0 = 0.f, a1 = 0.f;
    for (int k = 0; k < 1024; k += 2) {
      a0 += z[k]   * W1[(size_t)k*512 + n];
      a1 += z[k+1] * W1[(size_t)(k+1)*512 + n];
    }
    h1[n] = fmaxf(a0 + a1 + b1[n], 0.f);
  }
  __syncthreads();
  {
    int n = threadIdx.x;
    float a0 = 0.f, a1 = 0.f;
    for (int k = 0; k < 512; k += 2) {
      a0 += h1[k]   * W2[(size_t)k*256 + n];
      a1 += h1[k+1] * W2[(size_t)(k+1)*256 + n];
    }
    h2[n] = fmaxf(a0 + a1 + b2[n], 0.f);
  }
  __syncthreads();
  int wv = threadIdx.x >> 6, lane = threadIdx.x & 63;
  if (wv < 2) {
    float acc = 0.f;
    for (int k = lane; k < 256; k += 64) acc += h2[k]*W3[(size_t)k*2 + wv];
    acc = wave_sum(acc);
    if (lane == 0) out[(size_t)g*2 + wv] = acc + b3[wv];
  }
}

extern "C" void kernel_launch(void* const* d_in, const int* in_sizes, int n_in,
                              void* d_out, int out_size, void* d_ws, size_t ws_size,
                              hipStream_t stream) {
  const float* x       = (const float*)d_in[0];
  const int*   edge    = (const int*)d_in[1];
  const float* bn_g    = (const float*)d_in[2];
  const float* bn_b    = (const float*)d_in[3];
  const float* W_emb   = (const float*)d_in[4];
  const float* Wqkv    = (const float*)d_in[5];
  const float* bqkv    = (const float*)d_in[6];
  const float* Wo      = (const float*)d_in[7];
  const float* bo      = (const float*)d_in[8];
  const float* W1      = (const float*)d_in[9];
  const float* b1      = (const float*)d_in[10];
  const float* W2      = (const float*)d_in[11];
  const float* b2      = (const float*)d_in[12];
  const float* g1      = (const float*)d_in[13];
  const float* be1     = (const float*)d_in[14];
  const float* g2      = (const float*)d_in[15];
  const float* be2     = (const float*)d_in[16];
  const float* W_emb1  = (const float*)d_in[17];
  const float* conv1_W = (const float*)d_in[18];
  const float* conv1_b = (const float*)d_in[19];
  const float* convs_W = (const float*)d_in[20];
  const float* convs_b = (const float*)d_in[21];
  const float* pool1_W = (const float*)d_in[22];
  const float* pool1_b = (const float*)d_in[23];
  const float* pool2_W = (const float*)d_in[24];
  const float* pool2_b = (const float*)d_in[25];
  const float* fc1_W   = (const float*)d_in[26];
  const float* fc1_b   = (const float*)d_in[27];
  const float* fc2_W   = (const float*)d_in[28];
  const float* fc2_b   = (const float*)d_in[29];
  const float* fc3_W   = (const float*)d_in[30];
  const float* fc3_b   = (const float*)d_in[31];
  (void)in_sizes; (void)n_in; (void)out_size; (void)ws_size;

  const int* srcp = edge;
  const int* dstp = edge + NEDGE;

  char* wsb = (char*)d_ws;
  size_t off = 0;
  auto alloc = [&](size_t bytes)->void* {
    void* p = wsb + off;
    off += (bytes + 255) & ~(size_t)255;
    return p;
  };
  const size_t MN = (size_t)NTOK*DD;
  float* T    = (float*)alloc(MN*4);
  size_t qkvB = (size_t)NTOK*3*DD*4, ffnB = (size_t)NTOK*DFF*2*2;
  char* BIGU  = (char*)alloc(qkvB > ffnB ? qkvB : ffnB);
  float* QKVf = (float*)BIGU;
  u16* BIGh   = (u16*)BIGU;
  u16* BIGl   = BIGh + (size_t)NTOK*DFF;
  float* PART = (float*)alloc(4*MN*4);
  u16* Th   = (u16*)alloc(MN*2);
  u16* Tl   = (u16*)alloc(MN*2);
  u16* ATh  = (u16*)alloc(MN*2);
  u16* ATl  = (u16*)alloc(MN*2);
  u16* Hh   = (u16*)alloc((size_t)MG*KP1*DD*2);
  u16* Hl   = (u16*)alloc((size_t)MG*KP1*DD*2);
  u16* WQh  = (u16*)alloc((size_t)1536*512*2);
  u16* WQl  = (u16*)alloc((size_t)1536*512*2);
  u16* WOh  = (u16*)alloc((size_t)512*512*2);
  u16* WOl  = (u16*)alloc((size_t)512*512*2);
  u16* W1h  = (u16*)alloc((size_t)2048*512*2);
  u16* W1l  = (u16*)alloc((size_t)2048*512*2);
  u16* W2h  = (u16*)alloc((size_t)512*2048*2);
  u16* W2l  = (u16*)alloc((size_t)512*2048*2);
  float* WCf = (float*)alloc((size_t)512*512*4);
  u16* CTh  = (u16*)alloc((size_t)512*512*2);
  u16* CTl  = (u16*)alloc((size_t)512*512*2);
  u16* CVh  = (u16*)alloc((size_t)3*512*512*2);
  u16* CVl  = (u16*)alloc((size_t)3*512*512*2);
  float* AG0 = (float*)alloc((size_t)MG*4096*4);   // dense adj level 0
  float* AG1 = (float*)alloc((size_t)MG*4096*4);   // dense adj level 1
  float* MU   = (float*)alloc(NNODE*4);
  float* RS   = (float*)alloc(NNODE*4);
  int*   DEG0 = (int*)alloc(NTOK*4);
  float* DIS0 = (float*)alloc(NTOK*4);
  float* COEF0= (float*)alloc(NEDGE*4);
  float* HS   = (float*)alloc(NTOK*4);
  float* SC   = (float*)alloc(NTOK*4);
  int*   PERM1= (int*)alloc(MG*KP1*4);
  int*   NMAP = (int*)alloc(NTOK*4);
  int*   ES1  = (int*)alloc(NEDGE*4);
  int*   ED1  = (int*)alloc(NEDGE*4);
  int*   KEEP1= (int*)alloc(NEDGE*4);
  int*   DEG1 = (int*)alloc(MG*KP1*4);
  float* DIS1 = (float*)alloc(MG*KP1*4);
  float* COEF1= (float*)alloc(NEDGE*4);
  int*   PERM2= (int*)alloc(MG*KP2*4);
  float* Z    = (float*)alloc(MG*1024*4);

  float* PA = PART;
  float* PB = PART + 2*MN;

  // ---- BN + embed + graph structure + GCN weight prep ----
  bn_stats_kernel<<<NNODE, 256, 0, stream>>>(x, MU, RS);
  embed_kernel<<<NTOK, 256, 0, stream>>>(x, MU, RS, bn_g, bn_b, W_emb, T, Th, Tl);
  fill_int_kernel<<<(NTOK+255)/256, 256, 0, stream>>>(DEG0, 1, NTOK);
  count_deg_kernel<<<(NEDGE+255)/256, 256, 0, stream>>>(dstp, DEG0, NEDGE);
  dis_kernel<<<(NTOK+255)/256, 256, 0, stream>>>(DEG0, DIS0, NTOK);
  coef0_kernel<<<(NEDGE+255)/256, 256, 0, stream>>>(srcp, dstp, DIS0, COEF0);
  // dense adjacency level 0
  zero_f_kernel<<<(MG*4096+255)/256, 256, 0, stream>>>(AG0, MG*4096);
  diagA_kernel<<<MG, 64, 0, stream>>>(DIS0, AG0, NNODE);
  edgeA_kernel<<<(NEDGE+255)/256, 256, 0, stream>>>(srcp, dstp, COEF0, AG0, NNODE);
  // Wcomb = W_emb1 @ conv1_W
  gemm_kernel<<<dim3(8,8), 256, 0, stream>>>(W_emb1, conv1_W, WCf, 512, 512, NNODE);
  gcnT_kernel<<<256, 256, 0, stream>>>(WCf, convs_W, CTh, CTl, CVh, CVl);

  // ---- transformer encoder ----
  for (int l = 0; l < NLAYER; ++l) {
    layerT_kernel<<<768, 256, 0, stream>>>(
        Wqkv + (size_t)l*DD*3*DD, Wo + (size_t)l*DD*DD,
        W1 + (size_t)l*DD*DFF, W2 + (size_t)l*DFF*DD,
        WQh, WQl, WOh, WOl, W1h, W1l, W2h, W2l);
    gemm3_kernel<false,0><<<dim3(12,62,1), 256, 0, stream>>>(Th, Tl, WQh, WQl,
        bqkv + (size_t)l*3*DD, QKVf, nullptr, nullptr, 3*DD, 3*DD, DD, DD);
    attn_kernel<<<MG*NH, 256, 0, stream>>>(QKVf, ATh, ATl);
    gemm3_kernel<false,0><<<dim3(4,62,2), 256, 0, stream>>>(ATh, ATl, WOh, WOl,
        bo + (size_t)l*DD, PART, nullptr, nullptr, DD, DD, DD, 256);
    add_ln_kernel<<<NTOK, 256, 0, stream>>>(T, PART, 2,
        g1 + (size_t)l*DD, be1 + (size_t)l*DD, Th, Tl);
    gemm3_kernel<true,1><<<dim3(16,62,1), 256, 0, stream>>>(Th, Tl, W1h, W1l,
        b1 + (size_t)l*DFF, nullptr, BIGh, BIGl, DFF, DFF, DD, DD);
    gemm3_kernel<false,0><<<dim3(4,62,4), 256, 0, stream>>>(BIGh, BIGl, W2h, W2l,
        b2 + (size_t)l*DD, PART, nullptr, nullptr, DD, DD, DFF, 512);
    add_ln_kernel<<<NTOK, 256, 0, stream>>>(T, PART, 4,
        g2 + (size_t)l*DD, be2 + (size_t)l*DD, Th, Tl);
  }

  // ---- conv1 = relu(A~0 @ (t @ Wcomb) + b) ----
  gemm3_kernel<false,0><<<dim3(4,62,2), 256, 0, stream>>>(Th, Tl, CTh, CTl,
      nullptr, PA, nullptr, nullptr, DD, DD, DD, 256);
  dense_agg_kernel<<<MG*8, 256, 0, stream>>>(AG0, PA, 2, MN, conv1_b,
      PA, NNODE, 1, nullptr, nullptr);

  // ---- SAGPool 1 ----
  gemv_kernel<<<(NTOK+3)/4, 256, 0, stream>>>(PA, pool1_W, HS, NTOK);
  dense_score_kernel<<<MG, 64, 0, stream>>>(AG0, HS, pool1_b, SC, NNODE);
  topk_kernel<<<MG, 64, 0, stream>>>(SC, PERM1, NNODE, KP1);
  gather_kernel<<<MG*KP1, 256, 0, stream>>>(PA, SC, PERM1, PA + MN, Hh, Hl, NNODE, KP1);
  readout_kernel<<<MG, 256, 0, stream>>>(PA + MN, Z, KP1, 0);

  // ---- filter_adj + dense adjacency level 1 ----
  fill_int_kernel<<<(NTOK+255)/256, 256, 0, stream>>>(NMAP, -1, NTOK);
  nmap_scatter_kernel<<<(MG*KP1+255)/256, 256, 0, stream>>>(PERM1, NMAP);
  fill_int_kernel<<<(MG*KP1+255)/256, 256, 0, stream>>>(DEG1, 1, MG*KP1);
  filter_kernel<<<(NEDGE+255)/256, 256, 0, stream>>>(srcp, dstp, NMAP, ES1, ED1, KEEP1, DEG1);
  dis_kernel<<<(MG*KP1+255)/256, 256, 0, stream>>>(DEG1, DIS1, MG*KP1);
  coef1_kernel<<<(NEDGE+255)/256, 256, 0, stream>>>(ES1, ED1, KEEP1, DIS1, COEF1);
  zero_f_kernel<<<(MG*4096+255)/256, 256, 0, stream>>>(AG1, MG*4096);
  diagA_kernel<<<MG, 64, 0, stream>>>(DIS1, AG1, KP1);
  edgeA_kernel<<<(NEDGE+255)/256, 256, 0, stream>>>(ES1, ED1, COEF1, AG1, KP1);

  // ---- 3 GCN layers on pooled graph ----
  const size_t MNP = (size_t)MG*KP1*DD;
  float* bases[3] = { PB, PA, PB };
  float* hfin = nullptr;
  for (int l = 0; l < NLAYER-1; ++l) {
    float* Pb = bases[l];
    gemm3_kernel<false,0><<<dim3(4,50,2), 256, 0, stream>>>(Hh, Hl, CVh + (size_t)l*DD*DD,
        CVl + (size_t)l*DD*DD, nullptr, Pb, nullptr, nullptr, DD, DD, DD, 256);
    dense_agg_kernel<<<MG*8, 256, 0, stream>>>(AG1, Pb, 2, MNP, convs_b + (size_t)l*DD,
        Pb, KP1, 1, (l < NLAYER-2) ? Hh : nullptr, (l < NLAYER-2) ? Hl : nullptr);
    hfin = Pb;
  }

  // ---- SAGPool 2 ----
  gemv_kernel<<<(MG*KP1+3)/4, 256, 0, stream>>>(hfin, pool2_W, HS, MG*KP1);
  dense_score_kernel<<<MG, 64, 0, stream>>>(AG1, HS, pool2_b, SC, KP1);
  topk_kernel<<<MG, 64, 0, stream>>>(SC, PERM2, KP1, KP2);
  gather_kernel<<<MG*KP2, 256, 0, stream>>>(hfin, SC, PERM2, PA, nullptr, nullptr, KP1, KP2);
  readout_kernel<<<MG, 256, 0, stream>>>(PA, Z, KP2, 1);

  // ---- fused MLP head ----
  mlp_kernel<<<MG, 256, 0, stream>>>(Z, fc1_W, fc1_b, fc2_W, fc2_b, fc3_W, fc3_b, (float*)d_out);
}

// Round 6
// 1907.428 us; speedup vs baseline: 3.4574x; 1.0094x over previous
//
#include <hip/hip_runtime.h>
#include <float.h>
#include <math.h>

#define MG 128
#define NNODE 62
#define DD 512
#define NH 8
#define DH 64
#define DFF 2048
#define NLAYER 4
#define EPG 600
#define KP1 50
#define KP2 40
#define NTOK (MG*NNODE)      // 7936
#define NEDGE (MG*EPG)       // 76800
#define EPSV 1e-5f

typedef unsigned short u16;
using bf16x8 = __attribute__((ext_vector_type(8))) short;
using f32x4  = __attribute__((ext_vector_type(4))) float;

__device__ __forceinline__ float wave_sum(float v) {
  for (int off = 32; off; off >>= 1) v += __shfl_xor(v, off);
  return v;
}
__device__ __forceinline__ float wave_max(float v) {
  for (int off = 32; off; off >>= 1) v = fmaxf(v, __shfl_xor(v, off));
  return v;
}
__device__ __forceinline__ u16 f2b(float x) {
  union { float f; unsigned u; } v; v.f = x;
  unsigned r = v.u + 0x7fffu + ((v.u >> 16) & 1u);
  return (u16)(r >> 16);
}
__device__ __forceinline__ float b2f(u16 h) {
  union { float f; unsigned u; } v; v.u = ((unsigned)h) << 16;
  return v.f;
}
__device__ __forceinline__ void f2bsplit(float x, u16& h, u16& l) {
  h = f2b(x);
  l = f2b(x - b2f(h));
}
__device__ __forceinline__ void load_lds16(const u16* g, u16* l) {
  __builtin_amdgcn_global_load_lds(
      (const __attribute__((address_space(1))) unsigned int*)(const void*)g,
      (__attribute__((address_space(3))) unsigned int*)(void*)l, 16, 0, 0);
}

// ---------------- BatchNorm stats ----------------
__global__ __launch_bounds__(256) void bn_stats_kernel(const float* __restrict__ x,
    float* __restrict__ mu, float* __restrict__ rs) {
  int s = blockIdx.x;
  float sum = 0.f, sq = 0.f;
  for (int i = threadIdx.x; i < MG*NNODE; i += 256) {
    int b = i / NNODE, j = i - b*NNODE;
    float v = x[(size_t)(b*NNODE + s)*NNODE + j];
    sum += v; sq += v*v;
  }
  __shared__ float r1[4], r2[4];
  sum = wave_sum(sum); sq = wave_sum(sq);
  int wv = threadIdx.x >> 6, lane = threadIdx.x & 63;
  if (lane == 0) { r1[wv] = sum; r2[wv] = sq; }
  __syncthreads();
  if (threadIdx.x == 0) {
    float S = r1[0]+r1[1]+r1[2]+r1[3];
    float Q = r2[0]+r2[1]+r2[2]+r2[3];
    float m = S / (float)(MG*NNODE);
    float var = Q / (float)(MG*NNODE) - m*m;
    mu[s] = m;
    rs[s] = rsqrtf(var + EPSV);
  }
}

// ---------------- embed: T fp32 + split bf16 ----------------
__global__ __launch_bounds__(256) void embed_kernel(const float* __restrict__ x,
    const float* __restrict__ mu, const float* __restrict__ rs,
    const float* __restrict__ gg, const float* __restrict__ bb,
    const float* __restrict__ W, float* __restrict__ T,
    u16* __restrict__ Th, u16* __restrict__ Tl) {
  int tok = blockIdx.x;
  int s = tok >> 7, b = tok & 127;
  __shared__ float xb[NNODE];
  if (threadIdx.x < NNODE) {
    float v = x[(size_t)(b*NNODE + s)*NNODE + threadIdx.x];
    xb[threadIdx.x] = (v - mu[s]) * rs[s] * gg[s] + bb[s];
  }
  __syncthreads();
  int d = threadIdx.x;
  float a0 = 0.f, a1 = 0.f;
  for (int j = 0; j < NNODE; ++j) {
    float xv = xb[j];
    a0 += xv * W[(size_t)j*DD + d];
    a1 += xv * W[(size_t)j*DD + d + 256];
  }
  size_t o = (size_t)tok*DD + d;
  T[o] = a0; T[o+256] = a1;
  u16 h, l;
  f2bsplit(a0, h, l); Th[o] = h; Tl[o] = l;
  f2bsplit(a1, h, l); Th[o+256] = h; Tl[o+256] = l;
}

// ---------------- fp32 GEMM (only for Wcomb = W_emb1 @ conv1_W) ----------------
__global__ __launch_bounds__(256) void gemm_kernel(const float* __restrict__ A,
    const float* __restrict__ B, float* __restrict__ C, int M, int N, int K) {
  __shared__ float As[16][68];
  __shared__ float Bs[16][68];
  int bm = blockIdx.y * 64, bn = blockIdx.x * 64;
  int tid = threadIdx.x;
  int tx = tid & 15, ty = tid >> 4;
  float acc[4][4] = {};
  for (int k0 = 0; k0 < K; k0 += 16) {
    {
      int row = tid >> 2; int kk = (tid & 3) * 4;
      int gm = bm + row;
      #pragma unroll
      for (int i = 0; i < 4; ++i) {
        int gk = k0 + kk + i;
        As[kk+i][row] = (gm < M && gk < K) ? A[(size_t)gm*K + gk] : 0.f;
      }
    }
    {
      int krow = tid >> 4; int nn = (tid & 15) * 4;
      int gk = k0 + krow;
      #pragma unroll
      for (int i = 0; i < 4; ++i) {
        int gn = bn + nn + i;
        Bs[krow][nn+i] = (gk < K && gn < N) ? B[(size_t)gk*N + gn] : 0.f;
      }
    }
    __syncthreads();
    #pragma unroll
    for (int k = 0; k < 16; ++k) {
      float a[4], bb2[4];
      #pragma unroll
      for (int i = 0; i < 4; ++i) a[i] = As[k][ty*4+i];
      #pragma unroll
      for (int j = 0; j < 4; ++j) bb2[j] = Bs[k][tx*4+j];
      #pragma unroll
      for (int i = 0; i < 4; ++i)
        #pragma unroll
        for (int j = 0; j < 4; ++j) acc[i][j] += a[i]*bb2[j];
    }
    __syncthreads();
  }
  #pragma unroll
  for (int i = 0; i < 4; ++i) {
    int gm = bm + ty*4 + i;
    if (gm >= M) continue;
    #pragma unroll
    for (int j = 0; j < 4; ++j) {
      int gn = bn + tx*4 + j;
      if (gn >= N) continue;
      C[(size_t)gm*N + gn] = acc[i][j];
    }
  }
}

// ---------------- transpose+split tile helper ----------------
__device__ __forceinline__ void transpose_split_tile(const float* __restrict__ W,
    u16* __restrict__ th, u16* __restrict__ tl,
    int K, int N, int Kp, int bx, int by, float (*t)[65]) {
  int k0 = by*64, n0 = bx*64;
  for (int i = threadIdx.x; i < 64*64; i += 256) {
    int r = i >> 6, c = i & 63;
    int gk = k0 + r, gn = n0 + c;
    t[r][c] = (gk < K && gn < N) ? W[(size_t)gk*N + gn] : 0.f;
  }
  __syncthreads();
  for (int i = threadIdx.x; i < 64*64; i += 256) {
    int r = i >> 6, c = i & 63;
    int gn = n0 + r, gk = k0 + c;
    u16 h, l; f2bsplit(t[c][r], h, l);
    th[(size_t)gn*Kp + gk] = h;
    tl[(size_t)gn*Kp + gk] = l;
  }
}

// ---------------- per-layer batched weight transpose ----------------
__global__ __launch_bounds__(256) void layerT_kernel(
    const float* __restrict__ Wqkv, const float* __restrict__ Wo,
    const float* __restrict__ W1, const float* __restrict__ W2,
    u16* WQh, u16* WQl, u16* WOh, u16* WOl,
    u16* W1h, u16* W1l, u16* W2h, u16* W2l) {
  __shared__ float t[64][65];
  int b = blockIdx.x;
  if (b < 192)      transpose_split_tile(Wqkv, WQh, WQl, 512, 1536, 512, b % 24, b / 24, t);
  else if (b < 256) { int q = b - 192; transpose_split_tile(Wo, WOh, WOl, 512, 512, 512, q % 8, q / 8, t); }
  else if (b < 512) { int q = b - 256; transpose_split_tile(W1, W1h, W1l, 512, 2048, 512, q % 32, q / 32, t); }
  else              { int q = b - 512; transpose_split_tile(W2, W2h, W2l, 2048, 512, 2048, q % 8, q / 8, t); }
}

// ---------------- GCN weights transpose (Wcomb, convs_W[0..2]) ----------------
__global__ __launch_bounds__(256) void gcnT_kernel(
    const float* __restrict__ WC, const float* __restrict__ convs_W,
    u16* CTh, u16* CTl, u16* CVh, u16* CVl) {
  __shared__ float t[64][65];
  int job = blockIdx.x >> 6, q = blockIdx.x & 63;
  int bx = q % 8, by = q / 8;
  if (job == 0) transpose_split_tile(WC, CTh, CTl, 512, 512, 512, bx, by, t);
  else {
    int l = job - 1;
    transpose_split_tile(convs_W + (size_t)l*DD*DD,
        CVh + (size_t)l*DD*DD, CVl + (size_t)l*DD*DD, 512, 512, 512, bx, by, t);
  }
}

// ---------------- split-bf16 MFMA GEMM, 2-phase double-buffered global_load_lds ----------------
// prologue-stage buf0; per iter: issue next-tile loads into buf^1, compute buf,
// one __syncthreads (implicit vmcnt(0) drains AFTER compute -> latency hidden).
template<bool RELU, int OUTMODE>
__global__ __launch_bounds__(256) void gemm3_kernel(
    const u16* __restrict__ Ah, const u16* __restrict__ Al,
    const u16* __restrict__ Bh, const u16* __restrict__ Bl,
    const float* __restrict__ bias,
    float* __restrict__ Cf, u16* __restrict__ Ch, u16* __restrict__ Cl,
    int Nreal, int Nstride, int Kp, int KC) {
  __shared__ alignas(16) u16 sA[2][2][4096];   // [buf][hi/lo][128*32]
  __shared__ alignas(16) u16 sB[2][2][4096];
  int bm = blockIdx.y * 128, bn = blockIdx.x * 128;
  int z = blockIdx.z;
  int tid = threadIdx.x;
  int wv = tid >> 6, lane = tid & 63;
  int wr = (wv >> 1) * 64, wc = (wv & 1) * 64;
  f32x4 acc[4][4];
  #pragma unroll
  for (int i = 0; i < 4; ++i)
    #pragma unroll
    for (int j = 0; j < 4; ++j) acc[i][j] = (f32x4){0.f,0.f,0.f,0.f};

  int r0 = tid >> 2;
  int lin = (tid & 3) * 8;
  int c0 = lin ^ (((r0 >> 1) & 3) << 3);
  int r1 = r0 + 64;
  int c1 = lin ^ (((r1 >> 1) & 3) << 3);
  int fr = lane & 15, fo = (lane >> 4) * 8;

  auto stage = [&](int k0, int bi) {
    size_t a0 = (size_t)(bm + r0)*Kp + k0 + c0;
    size_t a1 = (size_t)(bm + r1)*Kp + k0 + c1;
    size_t b0 = (size_t)(bn + r0)*Kp + k0 + c0;
    size_t b1 = (size_t)(bn + r1)*Kp + k0 + c1;
    load_lds16(Ah + a0, &sA[bi][0][tid*8]);
    load_lds16(Ah + a1, &sA[bi][0][2048 + tid*8]);
    load_lds16(Al + a0, &sA[bi][1][tid*8]);
    load_lds16(Al + a1, &sA[bi][1][2048 + tid*8]);
    load_lds16(Bh + b0, &sB[bi][0][tid*8]);
    load_lds16(Bh + b1, &sB[bi][0][2048 + tid*8]);
    load_lds16(Bl + b0, &sB[bi][1][tid*8]);
    load_lds16(Bl + b1, &sB[bi][1][2048 + tid*8]);
  };

  int kbeg = z * KC;
  int nk = KC >> 5;
  stage(kbeg, 0);
  __syncthreads();
  int cur = 0;
  for (int t = 0; t < nk; ++t) {
    if (t + 1 < nk) stage(kbeg + (t+1)*32, cur ^ 1);   // prefetch next tile
    bf16x8 ah[4], al[4], bh[4], bl[4];
    #pragma unroll
    for (int i = 0; i < 4; ++i) {
      int ra = wr + i*16 + fr;
      int ea = ra*32 + (fo ^ (((ra >> 1) & 3) << 3));
      ah[i] = *(const bf16x8*)&sA[cur][0][ea];
      al[i] = *(const bf16x8*)&sA[cur][1][ea];
      int rb = wc + i*16 + fr;
      int eb = rb*32 + (fo ^ (((rb >> 1) & 3) << 3));
      bh[i] = *(const bf16x8*)&sB[cur][0][eb];
      bl[i] = *(const bf16x8*)&sB[cur][1][eb];
    }
    #pragma unroll
    for (int i = 0; i < 4; ++i)
      #pragma unroll
      for (int j = 0; j < 4; ++j) {
        acc[i][j] = __builtin_amdgcn_mfma_f32_16x16x32_bf16(ah[i], bh[j], acc[i][j], 0, 0, 0);
        acc[i][j] = __builtin_amdgcn_mfma_f32_16x16x32_bf16(ah[i], bl[j], acc[i][j], 0, 0, 0);
        acc[i][j] = __builtin_amdgcn_mfma_f32_16x16x32_bf16(al[i], bh[j], acc[i][j], 0, 0, 0);
      }
    __syncthreads();   // drains prefetch vmcnt AFTER compute; also guards buf reuse
    cur ^= 1;
  }
  size_t pstride = (size_t)gridDim.y * 128 * Nstride;
  int cr = (lane >> 4) * 4, cc = lane & 15;
  #pragma unroll
  for (int i = 0; i < 4; ++i) {
    #pragma unroll
    for (int j = 0; j < 4; ++j) {
      int gn = bn + wc + j*16 + cc;
      if (gn >= Nstride) continue;
      #pragma unroll
      for (int q = 0; q < 4; ++q) {
        int gm = bm + wr + i*16 + cr + q;
        float v = acc[i][j][q];
        if (gn < Nreal) { if (bias && z == 0) v += bias[gn]; } else v = 0.f;
        if (RELU) v = fmaxf(v, 0.f);
        size_t o = (size_t)z*pstride + (size_t)gm*Nstride + gn;
        if (OUTMODE == 0) {
          Cf[o] = v;
        } else {
          u16 h, l; f2bsplit(v, h, l);
          Ch[o] = h; Cl[o] = l;
        }
      }
    }
  }
}

// ---------------- fused attention per (b,h) ----------------
__global__ __launch_bounds__(256) void attn_kernel(const float* __restrict__ QKV,
    u16* __restrict__ Oh, u16* __restrict__ Ol) {
  int b = blockIdx.x >> 3, h = blockIdx.x & 7;
  __shared__ float qs[NNODE][DH+1];
  __shared__ float ks[NNODE][DH+1];
  __shared__ float ps[NNODE][DH+1];
  for (int i = threadIdx.x; i < NNODE*DH; i += 256) {
    int s = i >> 6, d = i & 63;
    size_t base = ((size_t)(s*MG + b))*(3*DD) + h*DH + d;
    qs[s][d] = QKV[base];
    ks[s][d] = QKV[base + DD];
  }
  __syncthreads();
  int lane = threadIdx.x & 63, wv = threadIdx.x >> 6;
  for (int s = wv; s < NNODE; s += 4) {
    float acc = -FLT_MAX;
    if (lane < NNODE) {
      float a = 0.f;
      #pragma unroll
      for (int d = 0; d < DH; ++d) a += qs[s][d]*ks[lane][d];
      acc = a * 0.125f;
    }
    float mx = wave_max(acc);
    float e = (lane < NNODE) ? expf(acc - mx) : 0.f;
    float sm = wave_sum(e);
    ps[s][lane] = e / sm;
  }
  __syncthreads();
  for (int i = threadIdx.x; i < NNODE*DH; i += 256) {
    int s = i >> 6, d = i & 63;
    qs[s][d] = QKV[((size_t)(s*MG + b))*(3*DD) + 2*DD + h*DH + d];
  }
  __syncthreads();
  for (int s = wv; s < NNODE; s += 4) {
    float acc = 0.f;
    for (int t = 0; t < NNODE; ++t) acc += ps[s][t]*qs[t][lane];
    size_t o = ((size_t)(s*MG + b))*DD + h*DH + lane;
    u16 hh, ll; f2bsplit(acc, hh, ll);
    Oh[o] = hh; Ol[o] = ll;
  }
}

// ---------------- X = LayerNorm(X + sum_z PART[z]) ----------------
__global__ __launch_bounds__(256) void add_ln_kernel(float* __restrict__ X,
    const float* __restrict__ P, int nchunk,
    const float* __restrict__ gg, const float* __restrict__ bb,
    u16* __restrict__ Xh, u16* __restrict__ Xl) {
  size_t row = blockIdx.x;
  int t = threadIdx.x;
  const size_t MN = (size_t)NTOK*DD;
  float r0 = 0.f, r1 = 0.f;
  for (int z = 0; z < nchunk; ++z) {
    r0 += P[z*MN + row*DD + t];
    r1 += P[z*MN + row*DD + t + 256];
  }
  float v0 = X[row*DD + t] + r0;
  float v1 = X[row*DD + t + 256] + r1;
  __shared__ float red[4];
  float s = wave_sum(v0 + v1);
  int wv = t >> 6, lane = t & 63;
  if (lane == 0) red[wv] = s;
  __syncthreads();
  float mu = (red[0]+red[1]+red[2]+red[3]) * (1.f/DD);
  float d0 = v0 - mu, d1 = v1 - mu;
  float q = wave_sum(d0*d0 + d1*d1);
  __syncthreads();
  if (lane == 0) red[wv] = q;
  __syncthreads();
  float var = (red[0]+red[1]+red[2]+red[3]) * (1.f/DD);
  float rs = rsqrtf(var + EPSV);
  float o0 = d0*rs*gg[t] + bb[t];
  float o1 = d1*rs*gg[t+256] + bb[t+256];
  X[row*DD + t] = o0;
  X[row*DD + t+256] = o1;
  u16 h, l;
  f2bsplit(o0, h, l); Xh[row*DD + t] = h; Xl[row*DD + t] = l;
  f2bsplit(o1, h, l); Xh[row*DD + t+256] = h; Xl[row*DD + t+256] = l;
}

// ---------------- graph-structure helpers ----------------
__global__ void fill_int_kernel(int* p, int v, int n) {
  int i = blockIdx.x*256 + threadIdx.x;
  if (i < n) p[i] = v;
}
__global__ void zero_f_kernel(float* p, int n) {
  int i = blockIdx.x*256 + threadIdx.x;
  if (i < n) p[i] = 0.f;
}
__global__ void count_deg_kernel(const int* __restrict__ dst, int* deg, int n) {
  int e = blockIdx.x*256 + threadIdx.x;
  if (e < n) atomicAdd(&deg[dst[e]], 1);
}
__global__ void dis_kernel(const int* __restrict__ deg, float* dis, int n) {
  int i = blockIdx.x*256+threadIdx.x;
  if (i < n) dis[i] = rsqrtf((float)deg[i]);
}
__global__ void coef0_kernel(const int* __restrict__ src, const int* __restrict__ dst,
                             const float* __restrict__ dis, float* coef) {
  int e = blockIdx.x*256+threadIdx.x;
  if (e < NEDGE) coef[e] = dis[src[e]]*dis[dst[e]];
}
__global__ void coef1_kernel(const int* __restrict__ src, const int* __restrict__ dst,
                             const int* __restrict__ keep,
                             const float* __restrict__ dis, float* coef) {
  int e = blockIdx.x*256+threadIdx.x;
  if (e < NEDGE) coef[e] = keep[e] ? dis[src[e]]*dis[dst[e]] : 0.f;
}

// ---------------- dense per-graph normalized adjacency build ----------------
__global__ __launch_bounds__(64) void diagA_kernel(const float* __restrict__ dis,
    float* __restrict__ AG, int NP) {
  int g = blockIdx.x, lane = threadIdx.x;
  if (lane < NP) {
    float d = dis[g*NP + lane];
    AG[(size_t)g*4096 + lane*64 + lane] = d*d;
  }
}
__global__ __launch_bounds__(256) void edgeA_kernel(const int* __restrict__ src,
    const int* __restrict__ dst, const float* __restrict__ coef,
    float* __restrict__ AG, int NP) {
  int e = blockIdx.x*256 + threadIdx.x;
  if (e >= NEDGE) return;
  float c = coef[e];
  if (c == 0.f) return;
  int g = e / EPG;
  int ls = src[e] - g*NP, ld = dst[e] - g*NP;
  atomicAdd(&AG[(size_t)g*4096 + ld*64 + ls], c);
}

// ---------------- dense GCN aggregation: out = A~ @ (sum_z P[z]) + bias (relu) ----------------
__global__ __launch_bounds__(256) void dense_agg_kernel(
    const float* __restrict__ AG,
    const float* __restrict__ P, int nchunk, size_t mn,
    const float* __restrict__ bias,
    float* __restrict__ Hout, int NP, int relu,
    u16* __restrict__ outh, u16* __restrict__ outl) {
  int g = blockIdx.x >> 3;
  int ct = (blockIdx.x & 7) * 64;
  __shared__ float hls[64*64];
  __shared__ float At[64*68];
  int base = g * NP;
  for (int idx = threadIdx.x; idx < 64*64; idx += 256) {
    int r = idx >> 6, c = idx & 63;
    float v = 0.f;
    if (r < NP) {
      for (int z = 0; z < nchunk; ++z)
        v += P[z*mn + (size_t)(base+r)*DD + ct + c];
    }
    hls[idx] = v;
    At[c*68 + r] = AG[(size_t)g*4096 + idx];
  }
  __syncthreads();
  int wv = threadIdx.x >> 6, lane = threadIdx.x & 63;
  int i0 = wv * 16;
  f32x4 acc[4];
  #pragma unroll
  for (int q = 0; q < 4; ++q) acc[q] = (f32x4){0.f,0.f,0.f,0.f};
  for (int j = 0; j < NP; ++j) {
    float hv = hls[j*64 + lane];
    const f32x4* ap = (const f32x4*)&At[j*68 + i0];
    f32x4 a0 = ap[0], a1 = ap[1], a2 = ap[2], a3 = ap[3];
    #pragma unroll
    for (int t = 0; t < 4; ++t) {
      acc[0][t] += a0[t] * hv;
      acc[1][t] += a1[t] * hv;
      acc[2][t] += a2[t] * hv;
      acc[3][t] += a3[t] * hv;
    }
  }
  float bv = bias[ct + lane];
  #pragma unroll
  for (int q = 0; q < 4; ++q) {
    #pragma unroll
    for (int t = 0; t < 4; ++t) {
      int i = i0 + q*4 + t;
      if (i < NP) {
        float v = acc[q][t] + bv;
        if (relu) v = fmaxf(v, 0.f);
        size_t o = (size_t)(base+i)*DD + ct + lane;
        Hout[o] = v;
        if (outh) { u16 h, l; f2bsplit(v, h, l); outh[o] = h; outl[o] = l; }
      }
    }
  }
}

// ---------------- dense SAGPool score: sc = A~ @ hs + b ----------------
__global__ __launch_bounds__(64) void dense_score_kernel(
    const float* __restrict__ AG, const float* __restrict__ hsv,
    const float* __restrict__ pb, float* __restrict__ sc, int NP) {
  int g = blockIdx.x, lane = threadIdx.x;
  __shared__ float hls[64];
  __shared__ float At[64*65];
  hls[lane] = (lane < NP) ? hsv[g*NP + lane] : 0.f;
  for (int idx = lane; idx < 64*64; idx += 64) {
    int i = idx >> 6, j = idx & 63;
    At[j*65 + i] = AG[(size_t)g*4096 + idx];
  }
  __syncthreads();
  if (lane < NP) {
    float acc = 0.f;
    for (int j = 0; j < NP; ++j) acc += At[j*65 + lane] * hls[j];
    sc[g*NP + lane] = acc + pb[0];
  }
}

// ---------------- gemv: hs[i] = h[i,:] . w ----------------
__global__ __launch_bounds__(256) void gemv_kernel(const float* __restrict__ h,
    const float* __restrict__ wv, float* __restrict__ out, int n) {
  int node = blockIdx.x*4 + (threadIdx.x >> 6);
  int lane = threadIdx.x & 63;
  if (node >= n) return;
  const float* row = h + (size_t)node*DD;
  float acc = 0.f;
  for (int d = lane; d < DD; d += 64) acc += row[d]*wv[d];
  acc = wave_sum(acc);
  if (lane == 0) out[node] = acc;
}

// ---------------- per-graph top-k ----------------
__global__ __launch_bounds__(64) void topk_kernel(const float* __restrict__ sc,
    int* __restrict__ perm, int NP, int KK) {
  int g = blockIdx.x, lane = threadIdx.x;
  float v = (lane < NP) ? sc[g*NP+lane] : -FLT_MAX;
  for (int r = 0; r < KK; ++r) {
    float bv = v; int bi = lane;
    for (int off = 32; off; off >>= 1) {
      float ov = __shfl_xor(bv, off);
      int oi = __shfl_xor(bi, off);
      if (ov > bv || (ov == bv && oi < bi)) { bv = ov; bi = oi; }
    }
    if (lane == 0) perm[g*KK + r] = bi;
    if (lane == bi) v = -FLT_MAX;
  }
}

// ---------------- gather pooled ----------------
__global__ __launch_bounds__(256) void gather_kernel(const float* __restrict__ h,
    const float* __restrict__ sc, const int* __restrict__ perm,
    float* __restrict__ xn, u16* __restrict__ outh, u16* __restrict__ outl,
    int NP, int KK) {
  int j = blockIdx.x;
  int g = j / KK;
  int pi = perm[j];
  float t = tanhf(sc[g*NP + pi]);
  const float* srow = h + (size_t)(g*NP + pi)*DD;
  size_t o = (size_t)j*DD + threadIdx.x;
  float v0 = srow[threadIdx.x]*t;
  float v1 = srow[threadIdx.x+256]*t;
  xn[o] = v0; xn[o+256] = v1;
  if (outh) {
    u16 hh, ll;
    f2bsplit(v0, hh, ll); outh[o] = hh; outl[o] = ll;
    f2bsplit(v1, hh, ll); outh[o+256] = hh; outl[o+256] = ll;
  }
}

__global__ void nmap_scatter_kernel(const int* __restrict__ perm, int* __restrict__ nmap) {
  int j = blockIdx.x*256 + threadIdx.x;
  if (j < MG*KP1) nmap[(j/KP1)*NNODE + perm[j]] = j;
}

__global__ void filter_kernel(const int* __restrict__ src0, const int* __restrict__ dst0,
    const int* __restrict__ nmap, int* __restrict__ es, int* __restrict__ ed,
    int* __restrict__ keep, int* __restrict__ deg1) {
  int e = blockIdx.x*256+threadIdx.x;
  if (e >= NEDGE) return;
  int ns = nmap[src0[e]], nd = nmap[dst0[e]];
  int k = (ns >= 0) && (nd >= 0);
  es[e] = k ? ns : 0;
  ed[e] = k ? nd : 0;
  keep[e] = k;
  if (k) atomicAdd(&deg1[nd], 1);
}

// ---------------- readout: gmp || gap ----------------
__global__ __launch_bounds__(256) void readout_kernel(const float* __restrict__ h,
    float* __restrict__ z, int KK, int acc) {
  int g = blockIdx.x;
  for (int c = threadIdx.x; c < DD; c += 256) {
    float mx = -FLT_MAX, sm = 0.f;
    for (int r = 0; r < KK; ++r) {
      float v = h[(size_t)(g*KK+r)*DD + c];
      mx = fmaxf(mx, v); sm += v;
    }
    float mean = sm / (float)KK;
    if (acc) { z[(size_t)g*1024 + c] += mx; z[(size_t)g*1024 + 512 + c] += mean; }
    else     { z[(size_t)g*1024 + c]  = mx; z[(size_t)g*1024 + 512 + c]  = mean; }
  }
}

// ---------------- MLP head stage 1: fc1 split-K partials ----------------
// block = (g, zc): Pm[zc][g][n] = Z[g, zc*256 : zc*256+256] @ W1[zc*256 : ...,n]
__global__ __launch_bounds__(256) void mlp1_kernel(const float* __restrict__ Z,
    const float* __restrict__ W1, float* __restrict__ Pm) {
  int b = blockIdx.x;
  int g = b >> 2, zc = b & 3;
  __shared__ float z[256];
  int t = threadIdx.x;
  z[t] = Z[(size_t)g*1024 + zc*256 + t];
  __syncthreads();
  const float* Wb = W1 + (size_t)zc*256*512;
  float a0 = 0.f, a1 = 0.f;
  for (int k = 0; k < 256; ++k) {
    float zv = z[k];
    a0 += zv * Wb[(size_t)k*512 + t];
    a1 += zv * Wb[(size_t)k*512 + t + 256];
  }
  size_t o = ((size_t)zc*MG + g)*512;
  Pm[o + t] = a0;
  Pm[o + t + 256] = a1;
}

// ---------------- MLP head stage 2: reduce + relu, fc2 (wave-K-split), fc3 ----------------
__global__ __launch_bounds__(256) void mlp2_kernel(const float* __restrict__ Pm,
    const float* __restrict__ b1,
    const float* __restrict__ W2, const float* __restrict__ b2,
    const float* __restrict__ W3, const float* __restrict__ b3,
    float* __restrict__ out) {
  int g = blockIdx.x;
  int t = threadIdx.x;
  int wv = t >> 6, lane = t & 63;
  __shared__ float h1[512];
  __shared__ float p2[4][256];
  __shared__ float h2[256];
  #pragma unroll
  for (int half = 0; half < 2; ++half) {
    int n = t + half*256;
    float a = b1[n];
    #pragma unroll
    for (int zc = 0; zc < 4; ++zc) a += Pm[((size_t)zc*MG + g)*512 + n];
    h1[n] = fmaxf(a, 0.f);
  }
  __syncthreads();
  {
    float a[4] = {0.f, 0.f, 0.f, 0.f};
    for (int k = wv*128; k < wv*128 + 128; ++k) {
      float hv = h1[k];
      #pragma unroll
      for (int q = 0; q < 4; ++q)
        a[q] += hv * W2[(size_t)k*256 + lane + q*64];
    }
    #pragma unroll
    for (int q = 0; q < 4; ++q) p2[wv][lane + q*64] = a[q];
  }
  __syncthreads();
  h2[t] = fmaxf(p2[0][t] + p2[1][t] + p2[2][t] + p2[3][t] + b2[t], 0.f);
  __syncthreads();
  if (wv < 2) {
    float acc = 0.f;
    for (int k = lane; k < 256; k += 64) acc += h2[k]*W3[(size_t)k*2 + wv];
    acc = wave_sum(acc);
    if (lane == 0) out[(size_t)g*2 + wv] = acc + b3[wv];
  }
}

extern "C" void kernel_launch(void* const* d_in, const int* in_sizes, int n_in,
                              void* d_out, int out_size, void* d_ws, size_t ws_size,
                              hipStream_t stream) {
  const float* x       = (const float*)d_in[0];
  const int*   edge    = (const int*)d_in[1];
  const float* bn_g    = (const float*)d_in[2];
  const float* bn_b    = (const float*)d_in[3];
  const float* W_emb   = (const float*)d_in[4];
  const float* Wqkv    = (const float*)d_in[5];
  const float* bqkv    = (const float*)d_in[6];
  const float* Wo      = (const float*)d_in[7];
  const float* bo      = (const float*)d_in[8];
  const float* W1      = (const float*)d_in[9];
  const float* b1      = (const float*)d_in[10];
  const float* W2      = (const float*)d_in[11];
  const float* b2      = (const float*)d_in[12];
  const float* g1      = (const float*)d_in[13];
  const float* be1     = (const float*)d_in[14];
  const float* g2      = (const float*)d_in[15];
  const float* be2     = (const float*)d_in[16];
  const float* W_emb1  = (const float*)d_in[17];
  const float* conv1_W = (const float*)d_in[18];
  const float* conv1_b = (const float*)d_in[19];
  const float* convs_W = (const float*)d_in[20];
  const float* convs_b = (const float*)d_in[21];
  const float* pool1_W = (const float*)d_in[22];
  const float* pool1_b = (const float*)d_in[23];
  const float* pool2_W = (const float*)d_in[24];
  const float* pool2_b = (const float*)d_in[25];
  const float* fc1_W   = (const float*)d_in[26];
  const float* fc1_b   = (const float*)d_in[27];
  const float* fc2_W   = (const float*)d_in[28];
  const float* fc2_b   = (const float*)d_in[29];
  const float* fc3_W   = (const float*)d_in[30];
  const float* fc3_b   = (const float*)d_in[31];
  (void)in_sizes; (void)n_in; (void)out_size; (void)ws_size;

  const int* srcp = edge;
  const int* dstp = edge + NEDGE;

  char* wsb = (char*)d_ws;
  size_t off = 0;
  auto alloc = [&](size_t bytes)->void* {
    void* p = wsb + off;
    off += (bytes + 255) & ~(size_t)255;
    return p;
  };
  const size_t MN = (size_t)NTOK*DD;
  float* T    = (float*)alloc(MN*4);
  size_t qkvB = (size_t)NTOK*3*DD*4, ffnB = (size_t)NTOK*DFF*2*2;
  char* BIGU  = (char*)alloc(qkvB > ffnB ? qkvB : ffnB);
  float* QKVf = (float*)BIGU;
  u16* BIGh   = (u16*)BIGU;
  u16* BIGl   = BIGh + (size_t)NTOK*DFF;
  float* PART = (float*)alloc(4*MN*4);
  u16* Th   = (u16*)alloc(MN*2);
  u16* Tl   = (u16*)alloc(MN*2);
  u16* ATh  = (u16*)alloc(MN*2);
  u16* ATl  = (u16*)alloc(MN*2);
  u16* Hh   = (u16*)alloc((size_t)MG*KP1*DD*2);
  u16* Hl   = (u16*)alloc((size_t)MG*KP1*DD*2);
  u16* WQh  = (u16*)alloc((size_t)1536*512*2);
  u16* WQl  = (u16*)alloc((size_t)1536*512*2);
  u16* WOh  = (u16*)alloc((size_t)512*512*2);
  u16* WOl  = (u16*)alloc((size_t)512*512*2);
  u16* W1h  = (u16*)alloc((size_t)2048*512*2);
  u16* W1l  = (u16*)alloc((size_t)2048*512*2);
  u16* W2h  = (u16*)alloc((size_t)512*2048*2);
  u16* W2l  = (u16*)alloc((size_t)512*2048*2);
  float* WCf = (float*)alloc((size_t)512*512*4);
  u16* CTh  = (u16*)alloc((size_t)512*512*2);
  u16* CTl  = (u16*)alloc((size_t)512*512*2);
  u16* CVh  = (u16*)alloc((size_t)3*512*512*2);
  u16* CVl  = (u16*)alloc((size_t)3*512*512*2);
  float* AG0 = (float*)alloc((size_t)MG*4096*4);
  float* AG1 = (float*)alloc((size_t)MG*4096*4);
  float* MU   = (float*)alloc(NNODE*4);
  float* RS   = (float*)alloc(NNODE*4);
  int*   DEG0 = (int*)alloc(NTOK*4);
  float* DIS0 = (float*)alloc(NTOK*4);
  float* COEF0= (float*)alloc(NEDGE*4);
  float* HS   = (float*)alloc(NTOK*4);
  float* SC   = (float*)alloc(NTOK*4);
  int*   PERM1= (int*)alloc(MG*KP1*4);
  int*   NMAP = (int*)alloc(NTOK*4);
  int*   ES1  = (int*)alloc(NEDGE*4);
  int*   ED1  = (int*)alloc(NEDGE*4);
  int*   KEEP1= (int*)alloc(NEDGE*4);
  int*   DEG1 = (int*)alloc(MG*KP1*4);
  float* DIS1 = (float*)alloc(MG*KP1*4);
  float* COEF1= (float*)alloc(NEDGE*4);
  int*   PERM2= (int*)alloc(MG*KP2*4);
  float* Z    = (float*)alloc(MG*1024*4);
  float* Pm   = (float*)alloc((size_t)4*MG*512*4);

  float* PA = PART;
  float* PB = PART + 2*MN;

  // ---- BN + embed + graph structure + GCN weight prep ----
  bn_stats_kernel<<<NNODE, 256, 0, stream>>>(x, MU, RS);
  embed_kernel<<<NTOK, 256, 0, stream>>>(x, MU, RS, bn_g, bn_b, W_emb, T, Th, Tl);
  fill_int_kernel<<<(NTOK+255)/256, 256, 0, stream>>>(DEG0, 1, NTOK);
  count_deg_kernel<<<(NEDGE+255)/256, 256, 0, stream>>>(dstp, DEG0, NEDGE);
  dis_kernel<<<(NTOK+255)/256, 256, 0, stream>>>(DEG0, DIS0, NTOK);
  coef0_kernel<<<(NEDGE+255)/256, 256, 0, stream>>>(srcp, dstp, DIS0, COEF0);
  zero_f_kernel<<<(MG*4096+255)/256, 256, 0, stream>>>(AG0, MG*4096);
  diagA_kernel<<<MG, 64, 0, stream>>>(DIS0, AG0, NNODE);
  edgeA_kernel<<<(NEDGE+255)/256, 256, 0, stream>>>(srcp, dstp, COEF0, AG0, NNODE);
  gemm_kernel<<<dim3(8,8), 256, 0, stream>>>(W_emb1, conv1_W, WCf, 512, 512, NNODE);
  gcnT_kernel<<<256, 256, 0, stream>>>(WCf, convs_W, CTh, CTl, CVh, CVl);

  // ---- transformer encoder ----
  for (int l = 0; l < NLAYER; ++l) {
    layerT_kernel<<<768, 256, 0, stream>>>(
        Wqkv + (size_t)l*DD*3*DD, Wo + (size_t)l*DD*DD,
        W1 + (size_t)l*DD*DFF, W2 + (size_t)l*DFF*DD,
        WQh, WQl, WOh, WOl, W1h, W1l, W2h, W2l);
    gemm3_kernel<false,0><<<dim3(12,62,1), 256, 0, stream>>>(Th, Tl, WQh, WQl,
        bqkv + (size_t)l*3*DD, QKVf, nullptr, nullptr, 3*DD, 3*DD, DD, DD);
    attn_kernel<<<MG*NH, 256, 0, stream>>>(QKVf, ATh, ATl);
    gemm3_kernel<false,0><<<dim3(4,62,2), 256, 0, stream>>>(ATh, ATl, WOh, WOl,
        bo + (size_t)l*DD, PART, nullptr, nullptr, DD, DD, DD, 256);
    add_ln_kernel<<<NTOK, 256, 0, stream>>>(T, PART, 2,
        g1 + (size_t)l*DD, be1 + (size_t)l*DD, Th, Tl);
    gemm3_kernel<true,1><<<dim3(16,62,1), 256, 0, stream>>>(Th, Tl, W1h, W1l,
        b1 + (size_t)l*DFF, nullptr, BIGh, BIGl, DFF, DFF, DD, DD);
    gemm3_kernel<false,0><<<dim3(4,62,4), 256, 0, stream>>>(BIGh, BIGl, W2h, W2l,
        b2 + (size_t)l*DD, PART, nullptr, nullptr, DD, DD, DFF, 512);
    add_ln_kernel<<<NTOK, 256, 0, stream>>>(T, PART, 4,
        g2 + (size_t)l*DD, be2 + (size_t)l*DD, Th, Tl);
  }

  // ---- conv1 = relu(A~0 @ (t @ Wcomb) + b) ----
  gemm3_kernel<false,0><<<dim3(4,62,2), 256, 0, stream>>>(Th, Tl, CTh, CTl,
      nullptr, PA, nullptr, nullptr, DD, DD, DD, 256);
  dense_agg_kernel<<<MG*8, 256, 0, stream>>>(AG0, PA, 2, MN, conv1_b,
      PA, NNODE, 1, nullptr, nullptr);

  // ---- SAGPool 1 ----
  gemv_kernel<<<(NTOK+3)/4, 256, 0, stream>>>(PA, pool1_W, HS, NTOK);
  dense_score_kernel<<<MG, 64, 0, stream>>>(AG0, HS, pool1_b, SC, NNODE);
  topk_kernel<<<MG, 64, 0, stream>>>(SC, PERM1, NNODE, KP1);
  gather_kernel<<<MG*KP1, 256, 0, stream>>>(PA, SC, PERM1, PA + MN, Hh, Hl, NNODE, KP1);
  readout_kernel<<<MG, 256, 0, stream>>>(PA + MN, Z, KP1, 0);

  // ---- filter_adj + dense adjacency level 1 ----
  fill_int_kernel<<<(NTOK+255)/256, 256, 0, stream>>>(NMAP, -1, NTOK);
  nmap_scatter_kernel<<<(MG*KP1+255)/256, 256, 0, stream>>>(PERM1, NMAP);
  fill_int_kernel<<<(MG*KP1+255)/256, 256, 0, stream>>>(DEG1, 1, MG*KP1);
  filter_kernel<<<(NEDGE+255)/256, 256, 0, stream>>>(srcp, dstp, NMAP, ES1, ED1, KEEP1, DEG1);
  dis_kernel<<<(MG*KP1+255)/256, 256, 0, stream>>>(DEG1, DIS1, MG*KP1);
  coef1_kernel<<<(NEDGE+255)/256, 256, 0, stream>>>(ES1, ED1, KEEP1, DIS1, COEF1);
  zero_f_kernel<<<(MG*4096+255)/256, 256, 0, stream>>>(AG1, MG*4096);
  diagA_kernel<<<MG, 64, 0, stream>>>(DIS1, AG1, KP1);
  edgeA_kernel<<<(NEDGE+255)/256, 256, 0, stream>>>(ES1, ED1, COEF1, AG1, KP1);

  // ---- 3 GCN layers on pooled graph ----
  const size_t MNP = (size_t)MG*KP1*DD;
  float* bases[3] = { PB, PA, PB };
  float* hfin = nullptr;
  for (int l = 0; l < NLAYER-1; ++l) {
    float* Pb = bases[l];
    gemm3_kernel<false,0><<<dim3(4,50,2), 256, 0, stream>>>(Hh, Hl, CVh + (size_t)l*DD*DD,
        CVl + (size_t)l*DD*DD, nullptr, Pb, nullptr, nullptr, DD, DD, DD, 256);
    dense_agg_kernel<<<MG*8, 256, 0, stream>>>(AG1, Pb, 2, MNP, convs_b + (size_t)l*DD,
        Pb, KP1, 1, (l < NLAYER-2) ? Hh : nullptr, (l < NLAYER-2) ? Hl : nullptr);
    hfin = Pb;
  }

  // ---- SAGPool 2 ----
  gemv_kernel<<<(MG*KP1+3)/4, 256, 0, stream>>>(hfin, pool2_W, HS, MG*KP1);
  dense_score_kernel<<<MG, 64, 0, stream>>>(AG1, HS, pool2_b, SC, KP1);
  topk_kernel<<<MG, 64, 0, stream>>>(SC, PERM2, KP1, KP2);
  gather_kernel<<<MG*KP2, 256, 0, stream>>>(hfin, SC, PERM2, PA, nullptr, nullptr, KP1, KP2);
  readout_kernel<<<MG, 256, 0, stream>>>(PA, Z, KP2, 1);

  // ---- MLP head (split-K fc1 + fused fc2/fc3) ----
  mlp1_kernel<<<MG*4, 256, 0, stream>>>(Z, fc1_W, Pm);
  mlp2_kernel<<<MG, 256, 0, stream>>>(Pm, fc1_b, fc2_W, fc2_b, fc3_W, fc3_b, (float*)d_out);
}

// Round 7
// 1808.124 us; speedup vs baseline: 3.6473x; 1.0549x over previous
//
#include <hip/hip_runtime.h>
#include <float.h>
#include <math.h>

#define MG 128
#define NNODE 62
#define DD 512
#define NH 8
#define DH 64
#define DFF 2048
#define NLAYER 4
#define EPG 600
#define KP1 50
#define KP2 40
#define NTOK (MG*NNODE)      // 7936
#define NEDGE (MG*EPG)       // 76800
#define EPSV 1e-5f

typedef unsigned short u16;
using bf16x8 = __attribute__((ext_vector_type(8))) short;
using f32x4  = __attribute__((ext_vector_type(4))) float;

__device__ __forceinline__ float wave_sum(float v) {
  for (int off = 32; off; off >>= 1) v += __shfl_xor(v, off);
  return v;
}
__device__ __forceinline__ float wave_max(float v) {
  for (int off = 32; off; off >>= 1) v = fmaxf(v, __shfl_xor(v, off));
  return v;
}
__device__ __forceinline__ u16 f2b(float x) {
  union { float f; unsigned u; } v; v.f = x;
  unsigned r = v.u + 0x7fffu + ((v.u >> 16) & 1u);
  return (u16)(r >> 16);
}
__device__ __forceinline__ float b2f(u16 h) {
  union { float f; unsigned u; } v; v.u = ((unsigned)h) << 16;
  return v.f;
}
__device__ __forceinline__ void f2bsplit(float x, u16& h, u16& l) {
  h = f2b(x);
  l = f2b(x - b2f(h));
}
__device__ __forceinline__ void load_lds16(const u16* g, u16* l) {
  __builtin_amdgcn_global_load_lds(
      (const __attribute__((address_space(1))) unsigned int*)(const void*)g,
      (__attribute__((address_space(3))) unsigned int*)(void*)l, 16, 0, 0);
}

// ---------------- BatchNorm stats ----------------
__global__ __launch_bounds__(256) void bn_stats_kernel(const float* __restrict__ x,
    float* __restrict__ mu, float* __restrict__ rs) {
  int s = blockIdx.x;
  float sum = 0.f, sq = 0.f;
  for (int i = threadIdx.x; i < MG*NNODE; i += 256) {
    int b = i / NNODE, j = i - b*NNODE;
    float v = x[(size_t)(b*NNODE + s)*NNODE + j];
    sum += v; sq += v*v;
  }
  __shared__ float r1[4], r2[4];
  sum = wave_sum(sum); sq = wave_sum(sq);
  int wv = threadIdx.x >> 6, lane = threadIdx.x & 63;
  if (lane == 0) { r1[wv] = sum; r2[wv] = sq; }
  __syncthreads();
  if (threadIdx.x == 0) {
    float S = r1[0]+r1[1]+r1[2]+r1[3];
    float Q = r2[0]+r2[1]+r2[2]+r2[3];
    float m = S / (float)(MG*NNODE);
    float var = Q / (float)(MG*NNODE) - m*m;
    mu[s] = m;
    rs[s] = rsqrtf(var + EPSV);
  }
}

// ---------------- embed: T fp32 + split bf16 ----------------
__global__ __launch_bounds__(256) void embed_kernel(const float* __restrict__ x,
    const float* __restrict__ mu, const float* __restrict__ rs,
    const float* __restrict__ gg, const float* __restrict__ bb,
    const float* __restrict__ W, float* __restrict__ T,
    u16* __restrict__ Th, u16* __restrict__ Tl) {
  int tok = blockIdx.x;
  int s = tok >> 7, b = tok & 127;
  __shared__ float xb[NNODE];
  if (threadIdx.x < NNODE) {
    float v = x[(size_t)(b*NNODE + s)*NNODE + threadIdx.x];
    xb[threadIdx.x] = (v - mu[s]) * rs[s] * gg[s] + bb[s];
  }
  __syncthreads();
  int d = threadIdx.x;
  float a0 = 0.f, a1 = 0.f;
  for (int j = 0; j < NNODE; ++j) {
    float xv = xb[j];
    a0 += xv * W[(size_t)j*DD + d];
    a1 += xv * W[(size_t)j*DD + d + 256];
  }
  size_t o = (size_t)tok*DD + d;
  T[o] = a0; T[o+256] = a1;
  u16 h, l;
  f2bsplit(a0, h, l); Th[o] = h; Tl[o] = l;
  f2bsplit(a1, h, l); Th[o+256] = h; Tl[o+256] = l;
}

// ---------------- fp32 GEMM (only for Wcomb = W_emb1 @ conv1_W) ----------------
__global__ __launch_bounds__(256) void gemm_kernel(const float* __restrict__ A,
    const float* __restrict__ B, float* __restrict__ C, int M, int N, int K) {
  __shared__ float As[16][68];
  __shared__ float Bs[16][68];
  int bm = blockIdx.y * 64, bn = blockIdx.x * 64;
  int tid = threadIdx.x;
  int tx = tid & 15, ty = tid >> 4;
  float acc[4][4] = {};
  for (int k0 = 0; k0 < K; k0 += 16) {
    {
      int row = tid >> 2; int kk = (tid & 3) * 4;
      int gm = bm + row;
      #pragma unroll
      for (int i = 0; i < 4; ++i) {
        int gk = k0 + kk + i;
        As[kk+i][row] = (gm < M && gk < K) ? A[(size_t)gm*K + gk] : 0.f;
      }
    }
    {
      int krow = tid >> 4; int nn = (tid & 15) * 4;
      int gk = k0 + krow;
      #pragma unroll
      for (int i = 0; i < 4; ++i) {
        int gn = bn + nn + i;
        Bs[krow][nn+i] = (gk < K && gn < N) ? B[(size_t)gk*N + gn] : 0.f;
      }
    }
    __syncthreads();
    #pragma unroll
    for (int k = 0; k < 16; ++k) {
      float a[4], bb2[4];
      #pragma unroll
      for (int i = 0; i < 4; ++i) a[i] = As[k][ty*4+i];
      #pragma unroll
      for (int j = 0; j < 4; ++j) bb2[j] = Bs[k][tx*4+j];
      #pragma unroll
      for (int i = 0; i < 4; ++i)
        #pragma unroll
        for (int j = 0; j < 4; ++j) acc[i][j] += a[i]*bb2[j];
    }
    __syncthreads();
  }
  #pragma unroll
  for (int i = 0; i < 4; ++i) {
    int gm = bm + ty*4 + i;
    if (gm >= M) continue;
    #pragma unroll
    for (int j = 0; j < 4; ++j) {
      int gn = bn + tx*4 + j;
      if (gn >= N) continue;
      C[(size_t)gm*N + gn] = acc[i][j];
    }
  }
}

// ---------------- transpose+split tile helper ----------------
__device__ __forceinline__ void transpose_split_tile(const float* __restrict__ W,
    u16* __restrict__ th, u16* __restrict__ tl,
    int K, int N, int Kp, int bx, int by, float (*t)[65]) {
  int k0 = by*64, n0 = bx*64;
  for (int i = threadIdx.x; i < 64*64; i += 256) {
    int r = i >> 6, c = i & 63;
    int gk = k0 + r, gn = n0 + c;
    t[r][c] = (gk < K && gn < N) ? W[(size_t)gk*N + gn] : 0.f;
  }
  __syncthreads();
  for (int i = threadIdx.x; i < 64*64; i += 256) {
    int r = i >> 6, c = i & 63;
    int gn = n0 + r, gk = k0 + c;
    u16 h, l; f2bsplit(t[c][r], h, l);
    th[(size_t)gn*Kp + gk] = h;
    tl[(size_t)gn*Kp + gk] = l;
  }
}

// ---------------- per-layer batched weight transpose ----------------
__global__ __launch_bounds__(256) void layerT_kernel(
    const float* __restrict__ Wqkv, const float* __restrict__ Wo,
    const float* __restrict__ W1, const float* __restrict__ W2,
    u16* WQh, u16* WQl, u16* WOh, u16* WOl,
    u16* W1h, u16* W1l, u16* W2h, u16* W2l) {
  __shared__ float t[64][65];
  int b = blockIdx.x;
  if (b < 192)      transpose_split_tile(Wqkv, WQh, WQl, 512, 1536, 512, b % 24, b / 24, t);
  else if (b < 256) { int q = b - 192; transpose_split_tile(Wo, WOh, WOl, 512, 512, 512, q % 8, q / 8, t); }
  else if (b < 512) { int q = b - 256; transpose_split_tile(W1, W1h, W1l, 512, 2048, 512, q % 32, q / 32, t); }
  else              { int q = b - 512; transpose_split_tile(W2, W2h, W2l, 2048, 512, 2048, q % 8, q / 8, t); }
}

// ---------------- GCN weights transpose (Wcomb, convs_W[0..2]) ----------------
__global__ __launch_bounds__(256) void gcnT_kernel(
    const float* __restrict__ WC, const float* __restrict__ convs_W,
    u16* CTh, u16* CTl, u16* CVh, u16* CVl) {
  __shared__ float t[64][65];
  int job = blockIdx.x >> 6, q = blockIdx.x & 63;
  int bx = q % 8, by = q / 8;
  if (job == 0) transpose_split_tile(WC, CTh, CTl, 512, 512, 512, bx, by, t);
  else {
    int l = job - 1;
    transpose_split_tile(convs_W + (size_t)l*DD*DD,
        CVh + (size_t)l*DD*DD, CVl + (size_t)l*DD*DD, 512, 512, 512, bx, by, t);
  }
}

// ---------------- split-bf16 MFMA GEMM, 2-phase dbuf + XCD-aware block swizzle ----------------
// XCD swizzle (T1): linear block id lb -> swz = (lb%8)*(nwg/8) + lb/8 so each XCD
// owns a contiguous x-fastest run (N-tiles of the same M-panels share A in its L2).
// Bijective because every launch's nwg is divisible by 8 (guarded otherwise).
template<bool RELU, int OUTMODE>
__global__ __launch_bounds__(256) void gemm3_kernel(
    const u16* __restrict__ Ah, const u16* __restrict__ Al,
    const u16* __restrict__ Bh, const u16* __restrict__ Bl,
    const float* __restrict__ bias,
    float* __restrict__ Cf, u16* __restrict__ Ch, u16* __restrict__ Cl,
    int Nreal, int Nstride, int Kp, int KC) {
  __shared__ alignas(16) u16 sA[2][2][4096];   // [buf][hi/lo][128*32]
  __shared__ alignas(16) u16 sB[2][2][4096];
  unsigned nx = gridDim.x, ny = gridDim.y;
  unsigned nwg = nx * ny * gridDim.z;
  unsigned lb = blockIdx.x + nx*(blockIdx.y + ny*blockIdx.z);
  unsigned swz = lb;
  if ((nwg & 7u) == 0u) {
    unsigned cpx = nwg >> 3;
    swz = (lb & 7u)*cpx + (lb >> 3);
  }
  unsigned bxi = swz % nx;
  unsigned rem = swz / nx;
  unsigned byi = rem % ny;
  unsigned bzi = rem / ny;
  int bm = byi * 128, bn = bxi * 128;
  int z = bzi;
  int tid = threadIdx.x;
  int wv = tid >> 6, lane = tid & 63;
  int wr = (wv >> 1) * 64, wc = (wv & 1) * 64;
  f32x4 acc[4][4];
  #pragma unroll
  for (int i = 0; i < 4; ++i)
    #pragma unroll
    for (int j = 0; j < 4; ++j) acc[i][j] = (f32x4){0.f,0.f,0.f,0.f};

  int r0 = tid >> 2;
  int lin = (tid & 3) * 8;
  int c0 = lin ^ (((r0 >> 1) & 3) << 3);
  int r1 = r0 + 64;
  int c1 = lin ^ (((r1 >> 1) & 3) << 3);
  int fr = lane & 15, fo = (lane >> 4) * 8;

  auto stage = [&](int k0, int bi) {
    size_t a0 = (size_t)(bm + r0)*Kp + k0 + c0;
    size_t a1 = (size_t)(bm + r1)*Kp + k0 + c1;
    size_t b0 = (size_t)(bn + r0)*Kp + k0 + c0;
    size_t b1 = (size_t)(bn + r1)*Kp + k0 + c1;
    load_lds16(Ah + a0, &sA[bi][0][tid*8]);
    load_lds16(Ah + a1, &sA[bi][0][2048 + tid*8]);
    load_lds16(Al + a0, &sA[bi][1][tid*8]);
    load_lds16(Al + a1, &sA[bi][1][2048 + tid*8]);
    load_lds16(Bh + b0, &sB[bi][0][tid*8]);
    load_lds16(Bh + b1, &sB[bi][0][2048 + tid*8]);
    load_lds16(Bl + b0, &sB[bi][1][tid*8]);
    load_lds16(Bl + b1, &sB[bi][1][2048 + tid*8]);
  };

  int kbeg = z * KC;
  int nk = KC >> 5;
  stage(kbeg, 0);
  __syncthreads();
  int cur = 0;
  for (int t = 0; t < nk; ++t) {
    if (t + 1 < nk) stage(kbeg + (t+1)*32, cur ^ 1);   // prefetch next tile
    bf16x8 ah[4], al[4], bh[4], bl[4];
    #pragma unroll
    for (int i = 0; i < 4; ++i) {
      int ra = wr + i*16 + fr;
      int ea = ra*32 + (fo ^ (((ra >> 1) & 3) << 3));
      ah[i] = *(const bf16x8*)&sA[cur][0][ea];
      al[i] = *(const bf16x8*)&sA[cur][1][ea];
      int rb = wc + i*16 + fr;
      int eb = rb*32 + (fo ^ (((rb >> 1) & 3) << 3));
      bh[i] = *(const bf16x8*)&sB[cur][0][eb];
      bl[i] = *(const bf16x8*)&sB[cur][1][eb];
    }
    #pragma unroll
    for (int i = 0; i < 4; ++i)
      #pragma unroll
      for (int j = 0; j < 4; ++j) {
        acc[i][j] = __builtin_amdgcn_mfma_f32_16x16x32_bf16(ah[i], bh[j], acc[i][j], 0, 0, 0);
        acc[i][j] = __builtin_amdgcn_mfma_f32_16x16x32_bf16(ah[i], bl[j], acc[i][j], 0, 0, 0);
        acc[i][j] = __builtin_amdgcn_mfma_f32_16x16x32_bf16(al[i], bh[j], acc[i][j], 0, 0, 0);
      }
    __syncthreads();   // drains prefetch vmcnt AFTER compute; also guards buf reuse
    cur ^= 1;
  }
  size_t pstride = (size_t)gridDim.y * 128 * Nstride;
  int cr = (lane >> 4) * 4, cc = lane & 15;
  #pragma unroll
  for (int i = 0; i < 4; ++i) {
    #pragma unroll
    for (int j = 0; j < 4; ++j) {
      int gn = bn + wc + j*16 + cc;
      if (gn >= Nstride) continue;
      #pragma unroll
      for (int q = 0; q < 4; ++q) {
        int gm = bm + wr + i*16 + cr + q;
        float v = acc[i][j][q];
        if (gn < Nreal) { if (bias && z == 0) v += bias[gn]; } else v = 0.f;
        if (RELU) v = fmaxf(v, 0.f);
        size_t o = (size_t)z*pstride + (size_t)gm*Nstride + gn;
        if (OUTMODE == 0) {
          Cf[o] = v;
        } else {
          u16 h, l; f2bsplit(v, h, l);
          Ch[o] = h; Cl[o] = l;
        }
      }
    }
  }
}

// ---------------- fused attention per (b,h) ----------------
__global__ __launch_bounds__(256) void attn_kernel(const float* __restrict__ QKV,
    u16* __restrict__ Oh, u16* __restrict__ Ol) {
  int b = blockIdx.x >> 3, h = blockIdx.x & 7;
  __shared__ float qs[NNODE][DH+1];
  __shared__ float ks[NNODE][DH+1];
  __shared__ float ps[NNODE][DH+1];
  for (int i = threadIdx.x; i < NNODE*DH; i += 256) {
    int s = i >> 6, d = i & 63;
    size_t base = ((size_t)(s*MG + b))*(3*DD) + h*DH + d;
    qs[s][d] = QKV[base];
    ks[s][d] = QKV[base + DD];
  }
  __syncthreads();
  int lane = threadIdx.x & 63, wv = threadIdx.x >> 6;
  for (int s = wv; s < NNODE; s += 4) {
    float acc = -FLT_MAX;
    if (lane < NNODE) {
      float a = 0.f;
      #pragma unroll
      for (int d = 0; d < DH; ++d) a += qs[s][d]*ks[lane][d];
      acc = a * 0.125f;
    }
    float mx = wave_max(acc);
    float e = (lane < NNODE) ? expf(acc - mx) : 0.f;
    float sm = wave_sum(e);
    ps[s][lane] = e / sm;
  }
  __syncthreads();
  for (int i = threadIdx.x; i < NNODE*DH; i += 256) {
    int s = i >> 6, d = i & 63;
    qs[s][d] = QKV[((size_t)(s*MG + b))*(3*DD) + 2*DD + h*DH + d];
  }
  __syncthreads();
  for (int s = wv; s < NNODE; s += 4) {
    float acc = 0.f;
    for (int t = 0; t < NNODE; ++t) acc += ps[s][t]*qs[t][lane];
    size_t o = ((size_t)(s*MG + b))*DD + h*DH + lane;
    u16 hh, ll; f2bsplit(acc, hh, ll);
    Oh[o] = hh; Ol[o] = ll;
  }
}

// ---------------- X = LayerNorm(X + sum_z PART[z]) ----------------
__global__ __launch_bounds__(256) void add_ln_kernel(float* __restrict__ X,
    const float* __restrict__ P, int nchunk,
    const float* __restrict__ gg, const float* __restrict__ bb,
    u16* __restrict__ Xh, u16* __restrict__ Xl) {
  size_t row = blockIdx.x;
  int t = threadIdx.x;
  const size_t MN = (size_t)NTOK*DD;
  float r0 = 0.f, r1 = 0.f;
  for (int z = 0; z < nchunk; ++z) {
    r0 += P[z*MN + row*DD + t];
    r1 += P[z*MN + row*DD + t + 256];
  }
  float v0 = X[row*DD + t] + r0;
  float v1 = X[row*DD + t + 256] + r1;
  __shared__ float red[4];
  float s = wave_sum(v0 + v1);
  int wv = t >> 6, lane = t & 63;
  if (lane == 0) red[wv] = s;
  __syncthreads();
  float mu = (red[0]+red[1]+red[2]+red[3]) * (1.f/DD);
  float d0 = v0 - mu, d1 = v1 - mu;
  float q = wave_sum(d0*d0 + d1*d1);
  __syncthreads();
  if (lane == 0) red[wv] = q;
  __syncthreads();
  float var = (red[0]+red[1]+red[2]+red[3]) * (1.f/DD);
  float rs = rsqrtf(var + EPSV);
  float o0 = d0*rs*gg[t] + bb[t];
  float o1 = d1*rs*gg[t+256] + bb[t+256];
  X[row*DD + t] = o0;
  X[row*DD + t+256] = o1;
  u16 h, l;
  f2bsplit(o0, h, l); Xh[row*DD + t] = h; Xl[row*DD + t] = l;
  f2bsplit(o1, h, l); Xh[row*DD + t+256] = h; Xl[row*DD + t+256] = l;
}

// ---------------- graph-structure helpers ----------------
__global__ void fill_int_kernel(int* p, int v, int n) {
  int i = blockIdx.x*256 + threadIdx.x;
  if (i < n) p[i] = v;
}
__global__ void zero_f_kernel(float* p, int n) {
  int i = blockIdx.x*256 + threadIdx.x;
  if (i < n) p[i] = 0.f;
}
__global__ void count_deg_kernel(const int* __restrict__ dst, int* deg, int n) {
  int e = blockIdx.x*256 + threadIdx.x;
  if (e < n) atomicAdd(&deg[dst[e]], 1);
}
__global__ void dis_kernel(const int* __restrict__ deg, float* dis, int n) {
  int i = blockIdx.x*256+threadIdx.x;
  if (i < n) dis[i] = rsqrtf((float)deg[i]);
}
__global__ void coef0_kernel(const int* __restrict__ src, const int* __restrict__ dst,
                             const float* __restrict__ dis, float* coef) {
  int e = blockIdx.x*256+threadIdx.x;
  if (e < NEDGE) coef[e] = dis[src[e]]*dis[dst[e]];
}
__global__ void coef1_kernel(const int* __restrict__ src, const int* __restrict__ dst,
                             const int* __restrict__ keep,
                             const float* __restrict__ dis, float* coef) {
  int e = blockIdx.x*256+threadIdx.x;
  if (e < NEDGE) coef[e] = keep[e] ? dis[src[e]]*dis[dst[e]] : 0.f;
}

// ---------------- dense per-graph normalized adjacency build ----------------
__global__ __launch_bounds__(64) void diagA_kernel(const float* __restrict__ dis,
    float* __restrict__ AG, int NP) {
  int g = blockIdx.x, lane = threadIdx.x;
  if (lane < NP) {
    float d = dis[g*NP + lane];
    AG[(size_t)g*4096 + lane*64 + lane] = d*d;
  }
}
__global__ __launch_bounds__(256) void edgeA_kernel(const int* __restrict__ src,
    const int* __restrict__ dst, const float* __restrict__ coef,
    float* __restrict__ AG, int NP) {
  int e = blockIdx.x*256 + threadIdx.x;
  if (e >= NEDGE) return;
  float c = coef[e];
  if (c == 0.f) return;
  int g = e / EPG;
  int ls = src[e] - g*NP, ld = dst[e] - g*NP;
  atomicAdd(&AG[(size_t)g*4096 + ld*64 + ls], c);
}

// ---------------- dense GCN aggregation: out = A~ @ (sum_z P[z]) + bias (relu) ----------------
__global__ __launch_bounds__(256) void dense_agg_kernel(
    const float* __restrict__ AG,
    const float* __restrict__ P, int nchunk, size_t mn,
    const float* __restrict__ bias,
    float* __restrict__ Hout, int NP, int relu,
    u16* __restrict__ outh, u16* __restrict__ outl) {
  int g = blockIdx.x >> 3;
  int ct = (blockIdx.x & 7) * 64;
  __shared__ float hls[64*64];
  __shared__ float At[64*68];
  int base = g * NP;
  for (int idx = threadIdx.x; idx < 64*64; idx += 256) {
    int r = idx >> 6, c = idx & 63;
    float v = 0.f;
    if (r < NP) {
      for (int z = 0; z < nchunk; ++z)
        v += P[z*mn + (size_t)(base+r)*DD + ct + c];
    }
    hls[idx] = v;
    At[c*68 + r] = AG[(size_t)g*4096 + idx];
  }
  __syncthreads();
  int wv = threadIdx.x >> 6, lane = threadIdx.x & 63;
  int i0 = wv * 16;
  f32x4 acc[4];
  #pragma unroll
  for (int q = 0; q < 4; ++q) acc[q] = (f32x4){0.f,0.f,0.f,0.f};
  for (int j = 0; j < NP; ++j) {
    float hv = hls[j*64 + lane];
    const f32x4* ap = (const f32x4*)&At[j*68 + i0];
    f32x4 a0 = ap[0], a1 = ap[1], a2 = ap[2], a3 = ap[3];
    #pragma unroll
    for (int t = 0; t < 4; ++t) {
      acc[0][t] += a0[t] * hv;
      acc[1][t] += a1[t] * hv;
      acc[2][t] += a2[t] * hv;
      acc[3][t] += a3[t] * hv;
    }
  }
  float bv = bias[ct + lane];
  #pragma unroll
  for (int q = 0; q < 4; ++q) {
    #pragma unroll
    for (int t = 0; t < 4; ++t) {
      int i = i0 + q*4 + t;
      if (i < NP) {
        float v = acc[q][t] + bv;
        if (relu) v = fmaxf(v, 0.f);
        size_t o = (size_t)(base+i)*DD + ct + lane;
        Hout[o] = v;
        if (outh) { u16 h, l; f2bsplit(v, h, l); outh[o] = h; outl[o] = l; }
      }
    }
  }
}

// ---------------- dense SAGPool score: sc = A~ @ hs + b ----------------
__global__ __launch_bounds__(64) void dense_score_kernel(
    const float* __restrict__ AG, const float* __restrict__ hsv,
    const float* __restrict__ pb, float* __restrict__ sc, int NP) {
  int g = blockIdx.x, lane = threadIdx.x;
  __shared__ float hls[64];
  __shared__ float At[64*65];
  hls[lane] = (lane < NP) ? hsv[g*NP + lane] : 0.f;
  for (int idx = lane; idx < 64*64; idx += 64) {
    int i = idx >> 6, j = idx & 63;
    At[j*65 + i] = AG[(size_t)g*4096 + idx];
  }
  __syncthreads();
  if (lane < NP) {
    float acc = 0.f;
    for (int j = 0; j < NP; ++j) acc += At[j*65 + lane] * hls[j];
    sc[g*NP + lane] = acc + pb[0];
  }
}

// ---------------- gemv: hs[i] = h[i,:] . w ----------------
__global__ __launch_bounds__(256) void gemv_kernel(const float* __restrict__ h,
    const float* __restrict__ wv, float* __restrict__ out, int n) {
  int node = blockIdx.x*4 + (threadIdx.x >> 6);
  int lane = threadIdx.x & 63;
  if (node >= n) return;
  const float* row = h + (size_t)node*DD;
  float acc = 0.f;
  for (int d = lane; d < DD; d += 64) acc += row[d]*wv[d];
  acc = wave_sum(acc);
  if (lane == 0) out[node] = acc;
}

// ---------------- per-graph top-k ----------------
__global__ __launch_bounds__(64) void topk_kernel(const float* __restrict__ sc,
    int* __restrict__ perm, int NP, int KK) {
  int g = blockIdx.x, lane = threadIdx.x;
  float v = (lane < NP) ? sc[g*NP+lane] : -FLT_MAX;
  for (int r = 0; r < KK; ++r) {
    float bv = v; int bi = lane;
    for (int off = 32; off; off >>= 1) {
      float ov = __shfl_xor(bv, off);
      int oi = __shfl_xor(bi, off);
      if (ov > bv || (ov == bv && oi < bi)) { bv = ov; bi = oi; }
    }
    if (lane == 0) perm[g*KK + r] = bi;
    if (lane == bi) v = -FLT_MAX;
  }
}

// ---------------- gather pooled ----------------
__global__ __launch_bounds__(256) void gather_kernel(const float* __restrict__ h,
    const float* __restrict__ sc, const int* __restrict__ perm,
    float* __restrict__ xn, u16* __restrict__ outh, u16* __restrict__ outl,
    int NP, int KK) {
  int j = blockIdx.x;
  int g = j / KK;
  int pi = perm[j];
  float t = tanhf(sc[g*NP + pi]);
  const float* srow = h + (size_t)(g*NP + pi)*DD;
  size_t o = (size_t)j*DD + threadIdx.x;
  float v0 = srow[threadIdx.x]*t;
  float v1 = srow[threadIdx.x+256]*t;
  xn[o] = v0; xn[o+256] = v1;
  if (outh) {
    u16 hh, ll;
    f2bsplit(v0, hh, ll); outh[o] = hh; outl[o] = ll;
    f2bsplit(v1, hh, ll); outh[o+256] = hh; outl[o+256] = ll;
  }
}

__global__ void nmap_scatter_kernel(const int* __restrict__ perm, int* __restrict__ nmap) {
  int j = blockIdx.x*256 + threadIdx.x;
  if (j < MG*KP1) nmap[(j/KP1)*NNODE + perm[j]] = j;
}

__global__ void filter_kernel(const int* __restrict__ src0, const int* __restrict__ dst0,
    const int* __restrict__ nmap, int* __restrict__ es, int* __restrict__ ed,
    int* __restrict__ keep, int* __restrict__ deg1) {
  int e = blockIdx.x*256+threadIdx.x;
  if (e >= NEDGE) return;
  int ns = nmap[src0[e]], nd = nmap[dst0[e]];
  int k = (ns >= 0) && (nd >= 0);
  es[e] = k ? ns : 0;
  ed[e] = k ? nd : 0;
  keep[e] = k;
  if (k) atomicAdd(&deg1[nd], 1);
}

// ---------------- readout: gmp || gap ----------------
__global__ __launch_bounds__(256) void readout_kernel(const float* __restrict__ h,
    float* __restrict__ z, int KK, int acc) {
  int g = blockIdx.x;
  for (int c = threadIdx.x; c < DD; c += 256) {
    float mx = -FLT_MAX, sm = 0.f;
    for (int r = 0; r < KK; ++r) {
      float v = h[(size_t)(g*KK+r)*DD + c];
      mx = fmaxf(mx, v); sm += v;
    }
    float mean = sm / (float)KK;
    if (acc) { z[(size_t)g*1024 + c] += mx; z[(size_t)g*1024 + 512 + c] += mean; }
    else     { z[(size_t)g*1024 + c]  = mx; z[(size_t)g*1024 + 512 + c]  = mean; }
  }
}

// ---------------- MLP head stage 1: fc1 split-K partials ----------------
__global__ __launch_bounds__(256) void mlp1_kernel(const float* __restrict__ Z,
    const float* __restrict__ W1, float* __restrict__ Pm) {
  int b = blockIdx.x;
  int g = b >> 2, zc = b & 3;
  __shared__ float z[256];
  int t = threadIdx.x;
  z[t] = Z[(size_t)g*1024 + zc*256 + t];
  __syncthreads();
  const float* Wb = W1 + (size_t)zc*256*512;
  float a0 = 0.f, a1 = 0.f;
  for (int k = 0; k < 256; ++k) {
    float zv = z[k];
    a0 += zv * Wb[(size_t)k*512 + t];
    a1 += zv * Wb[(size_t)k*512 + t + 256];
  }
  size_t o = ((size_t)zc*MG + g)*512;
  Pm[o + t] = a0;
  Pm[o + t + 256] = a1;
}

// ---------------- MLP head stage 2: reduce + relu, fc2 (wave-K-split), fc3 ----------------
__global__ __launch_bounds__(256) void mlp2_kernel(const float* __restrict__ Pm,
    const float* __restrict__ b1,
    const float* __restrict__ W2, const float* __restrict__ b2,
    const float* __restrict__ W3, const float* __restrict__ b3,
    float* __restrict__ out) {
  int g = blockIdx.x;
  int t = threadIdx.x;
  int wv = t >> 6, lane = t & 63;
  __shared__ float h1[512];
  __shared__ float p2[4][256];
  __shared__ float h2[256];
  #pragma unroll
  for (int half = 0; half < 2; ++half) {
    int n = t + half*256;
    float a = b1[n];
    #pragma unroll
    for (int zc = 0; zc < 4; ++zc) a += Pm[((size_t)zc*MG + g)*512 + n];
    h1[n] = fmaxf(a, 0.f);
  }
  __syncthreads();
  {
    float a[4] = {0.f, 0.f, 0.f, 0.f};
    for (int k = wv*128; k < wv*128 + 128; ++k) {
      float hv = h1[k];
      #pragma unroll
      for (int q = 0; q < 4; ++q)
        a[q] += hv * W2[(size_t)k*256 + lane + q*64];
    }
    #pragma unroll
    for (int q = 0; q < 4; ++q) p2[wv][lane + q*64] = a[q];
  }
  __syncthreads();
  h2[t] = fmaxf(p2[0][t] + p2[1][t] + p2[2][t] + p2[3][t] + b2[t], 0.f);
  __syncthreads();
  if (wv < 2) {
    float acc = 0.f;
    for (int k = lane; k < 256; k += 64) acc += h2[k]*W3[(size_t)k*2 + wv];
    acc = wave_sum(acc);
    if (lane == 0) out[(size_t)g*2 + wv] = acc + b3[wv];
  }
}

extern "C" void kernel_launch(void* const* d_in, const int* in_sizes, int n_in,
                              void* d_out, int out_size, void* d_ws, size_t ws_size,
                              hipStream_t stream) {
  const float* x       = (const float*)d_in[0];
  const int*   edge    = (const int*)d_in[1];
  const float* bn_g    = (const float*)d_in[2];
  const float* bn_b    = (const float*)d_in[3];
  const float* W_emb   = (const float*)d_in[4];
  const float* Wqkv    = (const float*)d_in[5];
  const float* bqkv    = (const float*)d_in[6];
  const float* Wo      = (const float*)d_in[7];
  const float* bo      = (const float*)d_in[8];
  const float* W1      = (const float*)d_in[9];
  const float* b1      = (const float*)d_in[10];
  const float* W2      = (const float*)d_in[11];
  const float* b2      = (const float*)d_in[12];
  const float* g1      = (const float*)d_in[13];
  const float* be1     = (const float*)d_in[14];
  const float* g2      = (const float*)d_in[15];
  const float* be2     = (const float*)d_in[16];
  const float* W_emb1  = (const float*)d_in[17];
  const float* conv1_W = (const float*)d_in[18];
  const float* conv1_b = (const float*)d_in[19];
  const float* convs_W = (const float*)d_in[20];
  const float* convs_b = (const float*)d_in[21];
  const float* pool1_W = (const float*)d_in[22];
  const float* pool1_b = (const float*)d_in[23];
  const float* pool2_W = (const float*)d_in[24];
  const float* pool2_b = (const float*)d_in[25];
  const float* fc1_W   = (const float*)d_in[26];
  const float* fc1_b   = (const float*)d_in[27];
  const float* fc2_W   = (const float*)d_in[28];
  const float* fc2_b   = (const float*)d_in[29];
  const float* fc3_W   = (const float*)d_in[30];
  const float* fc3_b   = (const float*)d_in[31];
  (void)in_sizes; (void)n_in; (void)out_size; (void)ws_size;

  const int* srcp = edge;
  const int* dstp = edge + NEDGE;

  char* wsb = (char*)d_ws;
  size_t off = 0;
  auto alloc = [&](size_t bytes)->void* {
    void* p = wsb + off;
    off += (bytes + 255) & ~(size_t)255;
    return p;
  };
  const size_t MN = (size_t)NTOK*DD;
  float* T    = (float*)alloc(MN*4);
  size_t qkvB = (size_t)NTOK*3*DD*4, ffnB = (size_t)NTOK*DFF*2*2;
  char* BIGU  = (char*)alloc(qkvB > ffnB ? qkvB : ffnB);
  float* QKVf = (float*)BIGU;
  u16* BIGh   = (u16*)BIGU;
  u16* BIGl   = BIGh + (size_t)NTOK*DFF;
  float* PART = (float*)alloc(4*MN*4);
  u16* Th   = (u16*)alloc(MN*2);
  u16* Tl   = (u16*)alloc(MN*2);
  u16* ATh  = (u16*)alloc(MN*2);
  u16* ATl  = (u16*)alloc(MN*2);
  u16* Hh   = (u16*)alloc((size_t)MG*KP1*DD*2);
  u16* Hl   = (u16*)alloc((size_t)MG*KP1*DD*2);
  u16* WQh  = (u16*)alloc((size_t)1536*512*2);
  u16* WQl  = (u16*)alloc((size_t)1536*512*2);
  u16* WOh  = (u16*)alloc((size_t)512*512*2);
  u16* WOl  = (u16*)alloc((size_t)512*512*2);
  u16* W1h  = (u16*)alloc((size_t)2048*512*2);
  u16* W1l  = (u16*)alloc((size_t)2048*512*2);
  u16* W2h  = (u16*)alloc((size_t)512*2048*2);
  u16* W2l  = (u16*)alloc((size_t)512*2048*2);
  float* WCf = (float*)alloc((size_t)512*512*4);
  u16* CTh  = (u16*)alloc((size_t)512*512*2);
  u16* CTl  = (u16*)alloc((size_t)512*512*2);
  u16* CVh  = (u16*)alloc((size_t)3*512*512*2);
  u16* CVl  = (u16*)alloc((size_t)3*512*512*2);
  float* AG0 = (float*)alloc((size_t)MG*4096*4);
  float* AG1 = (float*)alloc((size_t)MG*4096*4);
  float* MU   = (float*)alloc(NNODE*4);
  float* RS   = (float*)alloc(NNODE*4);
  int*   DEG0 = (int*)alloc(NTOK*4);
  float* DIS0 = (float*)alloc(NTOK*4);
  float* COEF0= (float*)alloc(NEDGE*4);
  float* HS   = (float*)alloc(NTOK*4);
  float* SC   = (float*)alloc(NTOK*4);
  int*   PERM1= (int*)alloc(MG*KP1*4);
  int*   NMAP = (int*)alloc(NTOK*4);
  int*   ES1  = (int*)alloc(NEDGE*4);
  int*   ED1  = (int*)alloc(NEDGE*4);
  int*   KEEP1= (int*)alloc(NEDGE*4);
  int*   DEG1 = (int*)alloc(MG*KP1*4);
  float* DIS1 = (float*)alloc(MG*KP1*4);
  float* COEF1= (float*)alloc(NEDGE*4);
  int*   PERM2= (int*)alloc(MG*KP2*4);
  float* Z    = (float*)alloc(MG*1024*4);
  float* Pm   = (float*)alloc((size_t)4*MG*512*4);

  float* PA = PART;
  float* PB = PART + 2*MN;

  // ---- BN + embed + graph structure + GCN weight prep ----
  bn_stats_kernel<<<NNODE, 256, 0, stream>>>(x, MU, RS);
  embed_kernel<<<NTOK, 256, 0, stream>>>(x, MU, RS, bn_g, bn_b, W_emb, T, Th, Tl);
  fill_int_kernel<<<(NTOK+255)/256, 256, 0, stream>>>(DEG0, 1, NTOK);
  count_deg_kernel<<<(NEDGE+255)/256, 256, 0, stream>>>(dstp, DEG0, NEDGE);
  dis_kernel<<<(NTOK+255)/256, 256, 0, stream>>>(DEG0, DIS0, NTOK);
  coef0_kernel<<<(NEDGE+255)/256, 256, 0, stream>>>(srcp, dstp, DIS0, COEF0);
  zero_f_kernel<<<(MG*4096+255)/256, 256, 0, stream>>>(AG0, MG*4096);
  diagA_kernel<<<MG, 64, 0, stream>>>(DIS0, AG0, NNODE);
  edgeA_kernel<<<(NEDGE+255)/256, 256, 0, stream>>>(srcp, dstp, COEF0, AG0, NNODE);
  gemm_kernel<<<dim3(8,8), 256, 0, stream>>>(W_emb1, conv1_W, WCf, 512, 512, NNODE);
  gcnT_kernel<<<256, 256, 0, stream>>>(WCf, convs_W, CTh, CTl, CVh, CVl);

  // ---- transformer encoder ----
  for (int l = 0; l < NLAYER; ++l) {
    layerT_kernel<<<768, 256, 0, stream>>>(
        Wqkv + (size_t)l*DD*3*DD, Wo + (size_t)l*DD*DD,
        W1 + (size_t)l*DD*DFF, W2 + (size_t)l*DFF*DD,
        WQh, WQl, WOh, WOl, W1h, W1l, W2h, W2l);
    gemm3_kernel<false,0><<<dim3(12,62,1), 256, 0, stream>>>(Th, Tl, WQh, WQl,
        bqkv + (size_t)l*3*DD, QKVf, nullptr, nullptr, 3*DD, 3*DD, DD, DD);
    attn_kernel<<<MG*NH, 256, 0, stream>>>(QKVf, ATh, ATl);
    gemm3_kernel<false,0><<<dim3(4,62,2), 256, 0, stream>>>(ATh, ATl, WOh, WOl,
        bo + (size_t)l*DD, PART, nullptr, nullptr, DD, DD, DD, 256);
    add_ln_kernel<<<NTOK, 256, 0, stream>>>(T, PART, 2,
        g1 + (size_t)l*DD, be1 + (size_t)l*DD, Th, Tl);
    gemm3_kernel<true,1><<<dim3(16,62,1), 256, 0, stream>>>(Th, Tl, W1h, W1l,
        b1 + (size_t)l*DFF, nullptr, BIGh, BIGl, DFF, DFF, DD, DD);
    gemm3_kernel<false,0><<<dim3(4,62,2), 256, 0, stream>>>(BIGh, BIGl, W2h, W2l,
        b2 + (size_t)l*DD, PART, nullptr, nullptr, DD, DD, DFF, 1024);
    add_ln_kernel<<<NTOK, 256, 0, stream>>>(T, PART, 2,
        g2 + (size_t)l*DD, be2 + (size_t)l*DD, Th, Tl);
  }

  // ---- conv1 = relu(A~0 @ (t @ Wcomb) + b) ----
  gemm3_kernel<false,0><<<dim3(4,62,2), 256, 0, stream>>>(Th, Tl, CTh, CTl,
      nullptr, PA, nullptr, nullptr, DD, DD, DD, 256);
  dense_agg_kernel<<<MG*8, 256, 0, stream>>>(AG0, PA, 2, MN, conv1_b,
      PA, NNODE, 1, nullptr, nullptr);

  // ---- SAGPool 1 ----
  gemv_kernel<<<(NTOK+3)/4, 256, 0, stream>>>(PA, pool1_W, HS, NTOK);
  dense_score_kernel<<<MG, 64, 0, stream>>>(AG0, HS, pool1_b, SC, NNODE);
  topk_kernel<<<MG, 64, 0, stream>>>(SC, PERM1, NNODE, KP1);
  gather_kernel<<<MG*KP1, 256, 0, stream>>>(PA, SC, PERM1, PA + MN, Hh, Hl, NNODE, KP1);
  readout_kernel<<<MG, 256, 0, stream>>>(PA + MN, Z, KP1, 0);

  // ---- filter_adj + dense adjacency level 1 ----
  fill_int_kernel<<<(NTOK+255)/256, 256, 0, stream>>>(NMAP, -1, NTOK);
  nmap_scatter_kernel<<<(MG*KP1+255)/256, 256, 0, stream>>>(PERM1, NMAP);
  fill_int_kernel<<<(MG*KP1+255)/256, 256, 0, stream>>>(DEG1, 1, MG*KP1);
  filter_kernel<<<(NEDGE+255)/256, 256, 0, stream>>>(srcp, dstp, NMAP, ES1, ED1, KEEP1, DEG1);
  dis_kernel<<<(MG*KP1+255)/256, 256, 0, stream>>>(DEG1, DIS1, MG*KP1);
  coef1_kernel<<<(NEDGE+255)/256, 256, 0, stream>>>(ES1, ED1, KEEP1, DIS1, COEF1);
  zero_f_kernel<<<(MG*4096+255)/256, 256, 0, stream>>>(AG1, MG*4096);
  diagA_kernel<<<MG, 64, 0, stream>>>(DIS1, AG1, KP1);
  edgeA_kernel<<<(NEDGE+255)/256, 256, 0, stream>>>(ES1, ED1, COEF1, AG1, KP1);

  // ---- 3 GCN layers on pooled graph ----
  const size_t MNP = (size_t)MG*KP1*DD;
  float* bases[3] = { PB, PA, PB };
  float* hfin = nullptr;
  for (int l = 0; l < NLAYER-1; ++l) {
    float* Pb = bases[l];
    gemm3_kernel<false,0><<<dim3(4,50,2), 256, 0, stream>>>(Hh, Hl, CVh + (size_t)l*DD*DD,
        CVl + (size_t)l*DD*DD, nullptr, Pb, nullptr, nullptr, DD, DD, DD, 256);
    dense_agg_kernel<<<MG*8, 256, 0, stream>>>(AG1, Pb, 2, MNP, convs_b + (size_t)l*DD,
        Pb, KP1, 1, (l < NLAYER-2) ? Hh : nullptr, (l < NLAYER-2) ? Hl : nullptr);
    hfin = Pb;
  }

  // ---- SAGPool 2 ----
  gemv_kernel<<<(MG*KP1+3)/4, 256, 0, stream>>>(hfin, pool2_W, HS, MG*KP1);
  dense_score_kernel<<<MG, 64, 0, stream>>>(AG1, HS, pool2_b, SC, KP1);
  topk_kernel<<<MG, 64, 0, stream>>>(SC, PERM2, KP1, KP2);
  gather_kernel<<<MG*KP2, 256, 0, stream>>>(hfin, SC, PERM2, PA, nullptr, nullptr, KP1, KP2);
  readout_kernel<<<MG, 256, 0, stream>>>(PA, Z, KP2, 1);

  // ---- MLP head (split-K fc1 + fused fc2/fc3) ----
  mlp1_kernel<<<MG*4, 256, 0, stream>>>(Z, fc1_W, Pm);
  mlp2_kernel<<<MG, 256, 0, stream>>>(Pm, fc1_b, fc2_W, fc2_b, fc3_W, fc3_b, (float*)d_out);
}

// Round 8
// 1800.824 us; speedup vs baseline: 3.6621x; 1.0041x over previous
//
#include <hip/hip_runtime.h>
#include <float.h>
#include <math.h>

#define MG 128
#define NNODE 62
#define DD 512
#define NH 8
#define DH 64
#define DFF 2048
#define NLAYER 4
#define EPG 600
#define KP1 50
#define KP2 40
#define NTOK (MG*NNODE)      // 7936
#define NEDGE (MG*EPG)       // 76800
#define EPSV 1e-5f

typedef unsigned short u16;
using bf16x8 = __attribute__((ext_vector_type(8))) short;
using f32x4  = __attribute__((ext_vector_type(4))) float;

__device__ __forceinline__ float wave_sum(float v) {
  for (int off = 32; off; off >>= 1) v += __shfl_xor(v, off);
  return v;
}
__device__ __forceinline__ float wave_max(float v) {
  for (int off = 32; off; off >>= 1) v = fmaxf(v, __shfl_xor(v, off));
  return v;
}
__device__ __forceinline__ u16 f2b(float x) {
  union { float f; unsigned u; } v; v.f = x;
  unsigned r = v.u + 0x7fffu + ((v.u >> 16) & 1u);
  return (u16)(r >> 16);
}
__device__ __forceinline__ float b2f(u16 h) {
  union { float f; unsigned u; } v; v.u = ((unsigned)h) << 16;
  return v.f;
}
__device__ __forceinline__ void f2bsplit(float x, u16& h, u16& l) {
  h = f2b(x);
  l = f2b(x - b2f(h));
}
__device__ __forceinline__ void load_lds16(const u16* g, u16* l) {
  __builtin_amdgcn_global_load_lds(
      (const __attribute__((address_space(1))) unsigned int*)(const void*)g,
      (__attribute__((address_space(3))) unsigned int*)(void*)l, 16, 0, 0);
}

// ---------------- BatchNorm stats ----------------
__global__ __launch_bounds__(256) void bn_stats_kernel(const float* __restrict__ x,
    float* __restrict__ mu, float* __restrict__ rs) {
  int s = blockIdx.x;
  float sum = 0.f, sq = 0.f;
  for (int i = threadIdx.x; i < MG*NNODE; i += 256) {
    int b = i / NNODE, j = i - b*NNODE;
    float v = x[(size_t)(b*NNODE + s)*NNODE + j];
    sum += v; sq += v*v;
  }
  __shared__ float r1[4], r2[4];
  sum = wave_sum(sum); sq = wave_sum(sq);
  int wv = threadIdx.x >> 6, lane = threadIdx.x & 63;
  if (lane == 0) { r1[wv] = sum; r2[wv] = sq; }
  __syncthreads();
  if (threadIdx.x == 0) {
    float S = r1[0]+r1[1]+r1[2]+r1[3];
    float Q = r2[0]+r2[1]+r2[2]+r2[3];
    float m = S / (float)(MG*NNODE);
    float var = Q / (float)(MG*NNODE) - m*m;
    mu[s] = m;
    rs[s] = rsqrtf(var + EPSV);
  }
}

// ---------------- embed: T fp32 + split bf16 ----------------
__global__ __launch_bounds__(256) void embed_kernel(const float* __restrict__ x,
    const float* __restrict__ mu, const float* __restrict__ rs,
    const float* __restrict__ gg, const float* __restrict__ bb,
    const float* __restrict__ W, float* __restrict__ T,
    u16* __restrict__ Th, u16* __restrict__ Tl) {
  int tok = blockIdx.x;
  int s = tok >> 7, b = tok & 127;
  __shared__ float xb[NNODE];
  if (threadIdx.x < NNODE) {
    float v = x[(size_t)(b*NNODE + s)*NNODE + threadIdx.x];
    xb[threadIdx.x] = (v - mu[s]) * rs[s] * gg[s] + bb[s];
  }
  __syncthreads();
  int d = threadIdx.x;
  float a0 = 0.f, a1 = 0.f;
  for (int j = 0; j < NNODE; ++j) {
    float xv = xb[j];
    a0 += xv * W[(size_t)j*DD + d];
    a1 += xv * W[(size_t)j*DD + d + 256];
  }
  size_t o = (size_t)tok*DD + d;
  T[o] = a0; T[o+256] = a1;
  u16 h, l;
  f2bsplit(a0, h, l); Th[o] = h; Tl[o] = l;
  f2bsplit(a1, h, l); Th[o+256] = h; Tl[o+256] = l;
}

// ---------------- fp32 GEMM (only for Wcomb = W_emb1 @ conv1_W) ----------------
__global__ __launch_bounds__(256) void gemm_kernel(const float* __restrict__ A,
    const float* __restrict__ B, float* __restrict__ C, int M, int N, int K) {
  __shared__ float As[16][68];
  __shared__ float Bs[16][68];
  int bm = blockIdx.y * 64, bn = blockIdx.x * 64;
  int tid = threadIdx.x;
  int tx = tid & 15, ty = tid >> 4;
  float acc[4][4] = {};
  for (int k0 = 0; k0 < K; k0 += 16) {
    {
      int row = tid >> 2; int kk = (tid & 3) * 4;
      int gm = bm + row;
      #pragma unroll
      for (int i = 0; i < 4; ++i) {
        int gk = k0 + kk + i;
        As[kk+i][row] = (gm < M && gk < K) ? A[(size_t)gm*K + gk] : 0.f;
      }
    }
    {
      int krow = tid >> 4; int nn = (tid & 15) * 4;
      int gk = k0 + krow;
      #pragma unroll
      for (int i = 0; i < 4; ++i) {
        int gn = bn + nn + i;
        Bs[krow][nn+i] = (gk < K && gn < N) ? B[(size_t)gk*N + gn] : 0.f;
      }
    }
    __syncthreads();
    #pragma unroll
    for (int k = 0; k < 16; ++k) {
      float a[4], bb2[4];
      #pragma unroll
      for (int i = 0; i < 4; ++i) a[i] = As[k][ty*4+i];
      #pragma unroll
      for (int j = 0; j < 4; ++j) bb2[j] = Bs[k][tx*4+j];
      #pragma unroll
      for (int i = 0; i < 4; ++i)
        #pragma unroll
        for (int j = 0; j < 4; ++j) acc[i][j] += a[i]*bb2[j];
    }
    __syncthreads();
  }
  #pragma unroll
  for (int i = 0; i < 4; ++i) {
    int gm = bm + ty*4 + i;
    if (gm >= M) continue;
    #pragma unroll
    for (int j = 0; j < 4; ++j) {
      int gn = bn + tx*4 + j;
      if (gn >= N) continue;
      C[(size_t)gm*N + gn] = acc[i][j];
    }
  }
}

// ---------------- transpose+split tile helper ----------------
__device__ __forceinline__ void transpose_split_tile(const float* __restrict__ W,
    u16* __restrict__ th, u16* __restrict__ tl,
    int K, int N, int Kp, int bx, int by, float (*t)[65]) {
  int k0 = by*64, n0 = bx*64;
  for (int i = threadIdx.x; i < 64*64; i += 256) {
    int r = i >> 6, c = i & 63;
    int gk = k0 + r, gn = n0 + c;
    t[r][c] = (gk < K && gn < N) ? W[(size_t)gk*N + gn] : 0.f;
  }
  __syncthreads();
  for (int i = threadIdx.x; i < 64*64; i += 256) {
    int r = i >> 6, c = i & 63;
    int gn = n0 + r, gk = k0 + c;
    u16 h, l; f2bsplit(t[c][r], h, l);
    th[(size_t)gn*Kp + gk] = h;
    tl[(size_t)gn*Kp + gk] = l;
  }
}

// ---------------- per-layer batched weight transpose ----------------
__global__ __launch_bounds__(256) void layerT_kernel(
    const float* __restrict__ Wqkv, const float* __restrict__ Wo,
    const float* __restrict__ W1, const float* __restrict__ W2,
    u16* WQh, u16* WQl, u16* WOh, u16* WOl,
    u16* W1h, u16* W1l, u16* W2h, u16* W2l) {
  __shared__ float t[64][65];
  int b = blockIdx.x;
  if (b < 192)      transpose_split_tile(Wqkv, WQh, WQl, 512, 1536, 512, b % 24, b / 24, t);
  else if (b < 256) { int q = b - 192; transpose_split_tile(Wo, WOh, WOl, 512, 512, 512, q % 8, q / 8, t); }
  else if (b < 512) { int q = b - 256; transpose_split_tile(W1, W1h, W1l, 512, 2048, 512, q % 32, q / 32, t); }
  else              { int q = b - 512; transpose_split_tile(W2, W2h, W2l, 2048, 512, 2048, q % 8, q / 8, t); }
}

// ---------------- GCN weights transpose (Wcomb, convs_W[0..2]) ----------------
__global__ __launch_bounds__(256) void gcnT_kernel(
    const float* __restrict__ WC, const float* __restrict__ convs_W,
    u16* CTh, u16* CTl, u16* CVh, u16* CVl) {
  __shared__ float t[64][65];
  int job = blockIdx.x >> 6, q = blockIdx.x & 63;
  int bx = q % 8, by = q / 8;
  if (job == 0) transpose_split_tile(WC, CTh, CTl, 512, 512, 512, bx, by, t);
  else {
    int l = job - 1;
    transpose_split_tile(convs_W + (size_t)l*DD*DD,
        CVh + (size_t)l*DD*DD, CVl + (size_t)l*DD*DD, 512, 512, 512, bx, by, t);
  }
}

// ---------------- split-bf16 MFMA GEMM: counted-vmcnt 2-phase pipeline (T3+T4) ----------------
// Per iter: issue next-tile stage (8 loads/wave) -> s_waitcnt vmcnt(8) (current tile
// landed, next stays IN FLIGHT across barrier) -> s_barrier -> MFMA -> s_barrier.
// Never drains vmcnt to 0 in the main loop (only last iter).
// OUTMODE: 0 fp32 [M][Nstride]; 1 split-bf16; 2 fp32 attn layout [q/k/v][h][b][s][d].
template<bool RELU, int OUTMODE>
__global__ __launch_bounds__(256) void gemm3_kernel(
    const u16* __restrict__ Ah, const u16* __restrict__ Al,
    const u16* __restrict__ Bh, const u16* __restrict__ Bl,
    const float* __restrict__ bias,
    float* __restrict__ Cf, u16* __restrict__ Ch, u16* __restrict__ Cl,
    int Nreal, int Nstride, int Kp, int KC) {
  __shared__ alignas(16) u16 sA[2][2][4096];   // [buf][hi/lo][128*32]
  __shared__ alignas(16) u16 sB[2][2][4096];
  unsigned nx = gridDim.x, ny = gridDim.y;
  unsigned nwg = nx * ny * gridDim.z;
  unsigned lb = blockIdx.x + nx*(blockIdx.y + ny*blockIdx.z);
  unsigned swz = lb;
  if ((nwg & 7u) == 0u) {
    unsigned cpx = nwg >> 3;
    swz = (lb & 7u)*cpx + (lb >> 3);
  }
  unsigned bxi = swz % nx;
  unsigned rem = swz / nx;
  unsigned byi = rem % ny;
  unsigned bzi = rem / ny;
  int bm = byi * 128, bn = bxi * 128;
  int z = bzi;
  int tid = threadIdx.x;
  int wv = tid >> 6, lane = tid & 63;
  int wr = (wv >> 1) * 64, wc = (wv & 1) * 64;
  f32x4 acc[4][4];
  #pragma unroll
  for (int i = 0; i < 4; ++i)
    #pragma unroll
    for (int j = 0; j < 4; ++j) acc[i][j] = (f32x4){0.f,0.f,0.f,0.f};

  int r0 = tid >> 2;
  int lin = (tid & 3) * 8;
  int c0 = lin ^ (((r0 >> 1) & 3) << 3);
  int r1 = r0 + 64;
  int c1 = lin ^ (((r1 >> 1) & 3) << 3);
  int fr = lane & 15, fo = (lane >> 4) * 8;

  auto stage = [&](int k0, int bi) {
    size_t a0 = (size_t)(bm + r0)*Kp + k0 + c0;
    size_t a1 = (size_t)(bm + r1)*Kp + k0 + c1;
    size_t b0 = (size_t)(bn + r0)*Kp + k0 + c0;
    size_t b1 = (size_t)(bn + r1)*Kp + k0 + c1;
    load_lds16(Ah + a0, &sA[bi][0][tid*8]);
    load_lds16(Ah + a1, &sA[bi][0][2048 + tid*8]);
    load_lds16(Al + a0, &sA[bi][1][tid*8]);
    load_lds16(Al + a1, &sA[bi][1][2048 + tid*8]);
    load_lds16(Bh + b0, &sB[bi][0][tid*8]);
    load_lds16(Bh + b1, &sB[bi][0][2048 + tid*8]);
    load_lds16(Bl + b0, &sB[bi][1][tid*8]);
    load_lds16(Bl + b1, &sB[bi][1][2048 + tid*8]);
  };

  int kbeg = z * KC;
  int nk = KC >> 5;
  stage(kbeg, 0);
  int cur = 0;
  for (int t = 0; t < nk; ++t) {
    if (t + 1 < nk) {
      stage(kbeg + (t+1)*32, cur ^ 1);   // prefetch next tile (8 loads/wave)
      asm volatile("s_waitcnt vmcnt(8)" ::: "memory");  // cur landed; next in flight
    } else {
      asm volatile("s_waitcnt vmcnt(0)" ::: "memory");  // tail drain
    }
    __builtin_amdgcn_s_barrier();        // B1: all waves' cur-tile staged
    __builtin_amdgcn_sched_barrier(0);   // keep ds_reads below the barrier
    bf16x8 ah[4], al[4], bh[4], bl[4];
    #pragma unroll
    for (int i = 0; i < 4; ++i) {
      int ra = wr + i*16 + fr;
      int ea = ra*32 + (fo ^ (((ra >> 1) & 3) << 3));
      ah[i] = *(const bf16x8*)&sA[cur][0][ea];
      al[i] = *(const bf16x8*)&sA[cur][1][ea];
      int rb = wc + i*16 + fr;
      int eb = rb*32 + (fo ^ (((rb >> 1) & 3) << 3));
      bh[i] = *(const bf16x8*)&sB[cur][0][eb];
      bl[i] = *(const bf16x8*)&sB[cur][1][eb];
    }
    #pragma unroll
    for (int i = 0; i < 4; ++i)
      #pragma unroll
      for (int j = 0; j < 4; ++j) {
        acc[i][j] = __builtin_amdgcn_mfma_f32_16x16x32_bf16(ah[i], bh[j], acc[i][j], 0, 0, 0);
        acc[i][j] = __builtin_amdgcn_mfma_f32_16x16x32_bf16(ah[i], bl[j], acc[i][j], 0, 0, 0);
        acc[i][j] = __builtin_amdgcn_mfma_f32_16x16x32_bf16(al[i], bh[j], acc[i][j], 0, 0, 0);
      }
    __builtin_amdgcn_s_barrier();        // B2: all reads of buf retired -> safe to overwrite
    cur ^= 1;
  }
  size_t pstride = (size_t)gridDim.y * 128 * Nstride;
  int cr = (lane >> 4) * 4, cc = lane & 15;
  #pragma unroll
  for (int i = 0; i < 4; ++i) {
    #pragma unroll
    for (int j = 0; j < 4; ++j) {
      int gn = bn + wc + j*16 + cc;
      if (gn >= Nstride) continue;
      #pragma unroll
      for (int q = 0; q < 4; ++q) {
        int gm = bm + wr + i*16 + cr + q;
        float v = acc[i][j][q];
        if (gn < Nreal) { if (bias && z == 0) v += bias[gn]; } else v = 0.f;
        if (RELU) v = fmaxf(v, 0.f);
        if (OUTMODE == 0) {
          Cf[(size_t)z*pstride + (size_t)gm*Nstride + gn] = v;
        } else if (OUTMODE == 1) {
          size_t o = (size_t)z*pstride + (size_t)gm*Nstride + gn;
          u16 h, l; f2bsplit(v, h, l);
          Ch[o] = h; Cl[o] = l;
        } else {
          // attn layout: which = gn>>9, head = (gn>>6)&7, d = gn&63; b = gm&127, s = gm>>7
          int which = gn >> 9, hh2 = (gn >> 6) & 7, d = gn & 63;
          int b2 = gm & 127, s2 = gm >> 7;
          Cf[(size_t)((which*NH + hh2)*MG + b2)*(NNODE*DH) + s2*DH + d] = v;
        }
      }
    }
  }
}

// ---------------- fused attention per (b,h): contiguous head-blocked QKV ----------------
__global__ __launch_bounds__(256) void attn_kernel(const float* __restrict__ QKV,
    u16* __restrict__ Oh, u16* __restrict__ Ol) {
  int b = blockIdx.x >> 3, h = blockIdx.x & 7;
  __shared__ float qs[NNODE][DH+1];
  __shared__ float ks[NNODE][DH+1];
  __shared__ float ps[NNODE][DH+1];
  size_t qb = (size_t)((0*NH + h)*MG + b)*(NNODE*DH);
  size_t kb = (size_t)((1*NH + h)*MG + b)*(NNODE*DH);
  size_t vb = (size_t)((2*NH + h)*MG + b)*(NNODE*DH);
  for (int i = threadIdx.x; i < NNODE*DH; i += 256) {
    qs[i >> 6][i & 63] = QKV[qb + i];
    ks[i >> 6][i & 63] = QKV[kb + i];
  }
  __syncthreads();
  int lane = threadIdx.x & 63, wv = threadIdx.x >> 6;
  for (int s = wv; s < NNODE; s += 4) {
    float acc = -FLT_MAX;
    if (lane < NNODE) {
      float a = 0.f;
      #pragma unroll
      for (int d = 0; d < DH; ++d) a += qs[s][d]*ks[lane][d];
      acc = a * 0.125f;
    }
    float mx = wave_max(acc);
    float e = (lane < NNODE) ? expf(acc - mx) : 0.f;
    float sm = wave_sum(e);
    ps[s][lane] = e / sm;
  }
  __syncthreads();
  for (int i = threadIdx.x; i < NNODE*DH; i += 256) {
    qs[i >> 6][i & 63] = QKV[vb + i];
  }
  __syncthreads();
  for (int s = wv; s < NNODE; s += 4) {
    float acc = 0.f;
    for (int t = 0; t < NNODE; ++t) acc += ps[s][t]*qs[t][lane];
    size_t o = ((size_t)(s*MG + b))*DD + h*DH + lane;
    u16 hh, ll; f2bsplit(acc, hh, ll);
    Oh[o] = hh; Ol[o] = ll;
  }
}

// ---------------- X = LayerNorm(X + sum_z PART[z]) ----------------
__global__ __launch_bounds__(256) void add_ln_kernel(float* __restrict__ X,
    const float* __restrict__ P, int nchunk,
    const float* __restrict__ gg, const float* __restrict__ bb,
    u16* __restrict__ Xh, u16* __restrict__ Xl) {
  size_t row = blockIdx.x;
  int t = threadIdx.x;
  const size_t MN = (size_t)NTOK*DD;
  float r0 = 0.f, r1 = 0.f;
  for (int z = 0; z < nchunk; ++z) {
    r0 += P[z*MN + row*DD + t];
    r1 += P[z*MN + row*DD + t + 256];
  }
  float v0 = X[row*DD + t] + r0;
  float v1 = X[row*DD + t + 256] + r1;
  __shared__ float red[4];
  float s = wave_sum(v0 + v1);
  int wv = t >> 6, lane = t & 63;
  if (lane == 0) red[wv] = s;
  __syncthreads();
  float mu = (red[0]+red[1]+red[2]+red[3]) * (1.f/DD);
  float d0 = v0 - mu, d1 = v1 - mu;
  float q = wave_sum(d0*d0 + d1*d1);
  __syncthreads();
  if (lane == 0) red[wv] = q;
  __syncthreads();
  float var = (red[0]+red[1]+red[2]+red[3]) * (1.f/DD);
  float rs = rsqrtf(var + EPSV);
  float o0 = d0*rs*gg[t] + bb[t];
  float o1 = d1*rs*gg[t+256] + bb[t+256];
  X[row*DD + t] = o0;
  X[row*DD + t+256] = o1;
  u16 h, l;
  f2bsplit(o0, h, l); Xh[row*DD + t] = h; Xl[row*DD + t] = l;
  f2bsplit(o1, h, l); Xh[row*DD + t+256] = h; Xl[row*DD + t+256] = l;
}

// ---------------- graph-structure helpers ----------------
__global__ void fill_int_kernel(int* p, int v, int n) {
  int i = blockIdx.x*256 + threadIdx.x;
  if (i < n) p[i] = v;
}
__global__ void zero_f_kernel(float* p, int n) {
  int i = blockIdx.x*256 + threadIdx.x;
  if (i < n) p[i] = 0.f;
}
__global__ void count_deg_kernel(const int* __restrict__ dst, int* deg, int n) {
  int e = blockIdx.x*256 + threadIdx.x;
  if (e < n) atomicAdd(&deg[dst[e]], 1);
}
__global__ void dis_kernel(const int* __restrict__ deg, float* dis, int n) {
  int i = blockIdx.x*256+threadIdx.x;
  if (i < n) dis[i] = rsqrtf((float)deg[i]);
}
__global__ void coef0_kernel(const int* __restrict__ src, const int* __restrict__ dst,
                             const float* __restrict__ dis, float* coef) {
  int e = blockIdx.x*256+threadIdx.x;
  if (e < NEDGE) coef[e] = dis[src[e]]*dis[dst[e]];
}
__global__ void coef1_kernel(const int* __restrict__ src, const int* __restrict__ dst,
                             const int* __restrict__ keep,
                             const float* __restrict__ dis, float* coef) {
  int e = blockIdx.x*256+threadIdx.x;
  if (e < NEDGE) coef[e] = keep[e] ? dis[src[e]]*dis[dst[e]] : 0.f;
}

// ---------------- dense per-graph normalized adjacency build ----------------
__global__ __launch_bounds__(64) void diagA_kernel(const float* __restrict__ dis,
    float* __restrict__ AG, int NP) {
  int g = blockIdx.x, lane = threadIdx.x;
  if (lane < NP) {
    float d = dis[g*NP + lane];
    AG[(size_t)g*4096 + lane*64 + lane] = d*d;
  }
}
__global__ __launch_bounds__(256) void edgeA_kernel(const int* __restrict__ src,
    const int* __restrict__ dst, const float* __restrict__ coef,
    float* __restrict__ AG, int NP) {
  int e = blockIdx.x*256 + threadIdx.x;
  if (e >= NEDGE) return;
  float c = coef[e];
  if (c == 0.f) return;
  int g = e / EPG;
  int ls = src[e] - g*NP, ld = dst[e] - g*NP;
  atomicAdd(&AG[(size_t)g*4096 + ld*64 + ls], c);
}

// ---------------- dense GCN aggregation ----------------
__global__ __launch_bounds__(256) void dense_agg_kernel(
    const float* __restrict__ AG,
    const float* __restrict__ P, int nchunk, size_t mn,
    const float* __restrict__ bias,
    float* __restrict__ Hout, int NP, int relu,
    u16* __restrict__ outh, u16* __restrict__ outl) {
  int g = blockIdx.x >> 3;
  int ct = (blockIdx.x & 7) * 64;
  __shared__ float hls[64*64];
  __shared__ float At[64*68];
  int base = g * NP;
  for (int idx = threadIdx.x; idx < 64*64; idx += 256) {
    int r = idx >> 6, c = idx & 63;
    float v = 0.f;
    if (r < NP) {
      for (int z = 0; z < nchunk; ++z)
        v += P[z*mn + (size_t)(base+r)*DD + ct + c];
    }
    hls[idx] = v;
    At[c*68 + r] = AG[(size_t)g*4096 + idx];
  }
  __syncthreads();
  int wv = threadIdx.x >> 6, lane = threadIdx.x & 63;
  int i0 = wv * 16;
  f32x4 acc[4];
  #pragma unroll
  for (int q = 0; q < 4; ++q) acc[q] = (f32x4){0.f,0.f,0.f,0.f};
  for (int j = 0; j < NP; ++j) {
    float hv = hls[j*64 + lane];
    const f32x4* ap = (const f32x4*)&At[j*68 + i0];
    f32x4 a0 = ap[0], a1 = ap[1], a2 = ap[2], a3 = ap[3];
    #pragma unroll
    for (int t = 0; t < 4; ++t) {
      acc[0][t] += a0[t] * hv;
      acc[1][t] += a1[t] * hv;
      acc[2][t] += a2[t] * hv;
      acc[3][t] += a3[t] * hv;
    }
  }
  float bv = bias[ct + lane];
  #pragma unroll
  for (int q = 0; q < 4; ++q) {
    #pragma unroll
    for (int t = 0; t < 4; ++t) {
      int i = i0 + q*4 + t;
      if (i < NP) {
        float v = acc[q][t] + bv;
        if (relu) v = fmaxf(v, 0.f);
        size_t o = (size_t)(base+i)*DD + ct + lane;
        Hout[o] = v;
        if (outh) { u16 h, l; f2bsplit(v, h, l); outh[o] = h; outl[o] = l; }
      }
    }
  }
}

// ---------------- dense SAGPool score ----------------
__global__ __launch_bounds__(64) void dense_score_kernel(
    const float* __restrict__ AG, const float* __restrict__ hsv,
    const float* __restrict__ pb, float* __restrict__ sc, int NP) {
  int g = blockIdx.x, lane = threadIdx.x;
  __shared__ float hls[64];
  __shared__ float At[64*65];
  hls[lane] = (lane < NP) ? hsv[g*NP + lane] : 0.f;
  for (int idx = lane; idx < 64*64; idx += 64) {
    int i = idx >> 6, j = idx & 63;
    At[j*65 + i] = AG[(size_t)g*4096 + idx];
  }
  __syncthreads();
  if (lane < NP) {
    float acc = 0.f;
    for (int j = 0; j < NP; ++j) acc += At[j*65 + lane] * hls[j];
    sc[g*NP + lane] = acc + pb[0];
  }
}

// ---------------- gemv ----------------
__global__ __launch_bounds__(256) void gemv_kernel(const float* __restrict__ h,
    const float* __restrict__ wv, float* __restrict__ out, int n) {
  int node = blockIdx.x*4 + (threadIdx.x >> 6);
  int lane = threadIdx.x & 63;
  if (node >= n) return;
  const float* row = h + (size_t)node*DD;
  float acc = 0.f;
  for (int d = lane; d < DD; d += 64) acc += row[d]*wv[d];
  acc = wave_sum(acc);
  if (lane == 0) out[node] = acc;
}

// ---------------- per-graph top-k ----------------
__global__ __launch_bounds__(64) void topk_kernel(const float* __restrict__ sc,
    int* __restrict__ perm, int NP, int KK) {
  int g = blockIdx.x, lane = threadIdx.x;
  float v = (lane < NP) ? sc[g*NP+lane] : -FLT_MAX;
  for (int r = 0; r < KK; ++r) {
    float bv = v; int bi = lane;
    for (int off = 32; off; off >>= 1) {
      float ov = __shfl_xor(bv, off);
      int oi = __shfl_xor(bi, off);
      if (ov > bv || (ov == bv && oi < bi)) { bv = ov; bi = oi; }
    }
    if (lane == 0) perm[g*KK + r] = bi;
    if (lane == bi) v = -FLT_MAX;
  }
}

// ---------------- gather pooled ----------------
__global__ __launch_bounds__(256) void gather_kernel(const float* __restrict__ h,
    const float* __restrict__ sc, const int* __restrict__ perm,
    float* __restrict__ xn, u16* __restrict__ outh, u16* __restrict__ outl,
    int NP, int KK) {
  int j = blockIdx.x;
  int g = j / KK;
  int pi = perm[j];
  float t = tanhf(sc[g*NP + pi]);
  const float* srow = h + (size_t)(g*NP + pi)*DD;
  size_t o = (size_t)j*DD + threadIdx.x;
  float v0 = srow[threadIdx.x]*t;
  float v1 = srow[threadIdx.x+256]*t;
  xn[o] = v0; xn[o+256] = v1;
  if (outh) {
    u16 hh, ll;
    f2bsplit(v0, hh, ll); outh[o] = hh; outl[o] = ll;
    f2bsplit(v1, hh, ll); outh[o+256] = hh; outl[o+256] = ll;
  }
}

__global__ void nmap_scatter_kernel(const int* __restrict__ perm, int* __restrict__ nmap) {
  int j = blockIdx.x*256 + threadIdx.x;
  if (j < MG*KP1) nmap[(j/KP1)*NNODE + perm[j]] = j;
}

__global__ void filter_kernel(const int* __restrict__ src0, const int* __restrict__ dst0,
    const int* __restrict__ nmap, int* __restrict__ es, int* __restrict__ ed,
    int* __restrict__ keep, int* __restrict__ deg1) {
  int e = blockIdx.x*256+threadIdx.x;
  if (e >= NEDGE) return;
  int ns = nmap[src0[e]], nd = nmap[dst0[e]];
  int k = (ns >= 0) && (nd >= 0);
  es[e] = k ? ns : 0;
  ed[e] = k ? nd : 0;
  keep[e] = k;
  if (k) atomicAdd(&deg1[nd], 1);
}

// ---------------- readout: gmp || gap ----------------
__global__ __launch_bounds__(256) void readout_kernel(const float* __restrict__ h,
    float* __restrict__ z, int KK, int acc) {
  int g = blockIdx.x;
  for (int c = threadIdx.x; c < DD; c += 256) {
    float mx = -FLT_MAX, sm = 0.f;
    for (int r = 0; r < KK; ++r) {
      float v = h[(size_t)(g*KK+r)*DD + c];
      mx = fmaxf(mx, v); sm += v;
    }
    float mean = sm / (float)KK;
    if (acc) { z[(size_t)g*1024 + c] += mx; z[(size_t)g*1024 + 512 + c] += mean; }
    else     { z[(size_t)g*1024 + c]  = mx; z[(size_t)g*1024 + 512 + c]  = mean; }
  }
}

// ---------------- MLP head stage 1: fc1 split-K partials ----------------
__global__ __launch_bounds__(256) void mlp1_kernel(const float* __restrict__ Z,
    const float* __restrict__ W1, float* __restrict__ Pm) {
  int b = blockIdx.x;
  int g = b >> 2, zc = b & 3;
  __shared__ float z[256];
  int t = threadIdx.x;
  z[t] = Z[(size_t)g*1024 + zc*256 + t];
  __syncthreads();
  const float* Wb = W1 + (size_t)zc*256*512;
  float a0 = 0.f, a1 = 0.f;
  for (int k = 0; k < 256; ++k) {
    float zv = z[k];
    a0 += zv * Wb[(size_t)k*512 + t];
    a1 += zv * Wb[(size_t)k*512 + t + 256];
  }
  size_t o = ((size_t)zc*MG + g)*512;
  Pm[o + t] = a0;
  Pm[o + t + 256] = a1;
}

// ---------------- MLP head stage 2 ----------------
__global__ __launch_bounds__(256) void mlp2_kernel(const float* __restrict__ Pm,
    const float* __restrict__ b1,
    const float* __restrict__ W2, const float* __restrict__ b2,
    const float* __restrict__ W3, const float* __restrict__ b3,
    float* __restrict__ out) {
  int g = blockIdx.x;
  int t = threadIdx.x;
  int wv = t >> 6, lane = t & 63;
  __shared__ float h1[512];
  __shared__ float p2[4][256];
  __shared__ float h2[256];
  #pragma unroll
  for (int half = 0; half < 2; ++half) {
    int n = t + half*256;
    float a = b1[n];
    #pragma unroll
    for (int zc = 0; zc < 4; ++zc) a += Pm[((size_t)zc*MG + g)*512 + n];
    h1[n] = fmaxf(a, 0.f);
  }
  __syncthreads();
  {
    float a[4] = {0.f, 0.f, 0.f, 0.f};
    for (int k = wv*128; k < wv*128 + 128; ++k) {
      float hv = h1[k];
      #pragma unroll
      for (int q = 0; q < 4; ++q)
        a[q] += hv * W2[(size_t)k*256 + lane + q*64];
    }
    #pragma unroll
    for (int q = 0; q < 4; ++q) p2[wv][lane + q*64] = a[q];
  }
  __syncthreads();
  h2[t] = fmaxf(p2[0][t] + p2[1][t] + p2[2][t] + p2[3][t] + b2[t], 0.f);
  __syncthreads();
  if (wv < 2) {
    float acc = 0.f;
    for (int k = lane; k < 256; k += 64) acc += h2[k]*W3[(size_t)k*2 + wv];
    acc = wave_sum(acc);
    if (lane == 0) out[(size_t)g*2 + wv] = acc + b3[wv];
  }
}

extern "C" void kernel_launch(void* const* d_in, const int* in_sizes, int n_in,
                              void* d_out, int out_size, void* d_ws, size_t ws_size,
                              hipStream_t stream) {
  const float* x       = (const float*)d_in[0];
  const int*   edge    = (const int*)d_in[1];
  const float* bn_g    = (const float*)d_in[2];
  const float* bn_b    = (const float*)d_in[3];
  const float* W_emb   = (const float*)d_in[4];
  const float* Wqkv    = (const float*)d_in[5];
  const float* bqkv    = (const float*)d_in[6];
  const float* Wo      = (const float*)d_in[7];
  const float* bo      = (const float*)d_in[8];
  const float* W1      = (const float*)d_in[9];
  const float* b1      = (const float*)d_in[10];
  const float* W2      = (const float*)d_in[11];
  const float* b2      = (const float*)d_in[12];
  const float* g1      = (const float*)d_in[13];
  const float* be1     = (const float*)d_in[14];
  const float* g2      = (const float*)d_in[15];
  const float* be2     = (const float*)d_in[16];
  const float* W_emb1  = (const float*)d_in[17];
  const float* conv1_W = (const float*)d_in[18];
  const float* conv1_b = (const float*)d_in[19];
  const float* convs_W = (const float*)d_in[20];
  const float* convs_b = (const float*)d_in[21];
  const float* pool1_W = (const float*)d_in[22];
  const float* pool1_b = (const float*)d_in[23];
  const float* pool2_W = (const float*)d_in[24];
  const float* pool2_b = (const float*)d_in[25];
  const float* fc1_W   = (const float*)d_in[26];
  const float* fc1_b   = (const float*)d_in[27];
  const float* fc2_W   = (const float*)d_in[28];
  const float* fc2_b   = (const float*)d_in[29];
  const float* fc3_W   = (const float*)d_in[30];
  const float* fc3_b   = (const float*)d_in[31];
  (void)in_sizes; (void)n_in; (void)out_size; (void)ws_size;

  const int* srcp = edge;
  const int* dstp = edge + NEDGE;

  char* wsb = (char*)d_ws;
  size_t off = 0;
  auto alloc = [&](size_t bytes)->void* {
    void* p = wsb + off;
    off += (bytes + 255) & ~(size_t)255;
    return p;
  };
  const size_t MN = (size_t)NTOK*DD;
  float* T    = (float*)alloc(MN*4);
  size_t qkvB = (size_t)NTOK*3*DD*4, ffnB = (size_t)NTOK*DFF*2*2;
  char* BIGU  = (char*)alloc(qkvB > ffnB ? qkvB : ffnB);
  float* QKVf = (float*)BIGU;
  u16* BIGh   = (u16*)BIGU;
  u16* BIGl   = BIGh + (size_t)NTOK*DFF;
  float* PART = (float*)alloc(4*MN*4);
  u16* Th   = (u16*)alloc(MN*2);
  u16* Tl   = (u16*)alloc(MN*2);
  u16* ATh  = (u16*)alloc(MN*2);
  u16* ATl  = (u16*)alloc(MN*2);
  u16* Hh   = (u16*)alloc((size_t)MG*KP1*DD*2);
  u16* Hl   = (u16*)alloc((size_t)MG*KP1*DD*2);
  u16* WQh  = (u16*)alloc((size_t)1536*512*2);
  u16* WQl  = (u16*)alloc((size_t)1536*512*2);
  u16* WOh  = (u16*)alloc((size_t)512*512*2);
  u16* WOl  = (u16*)alloc((size_t)512*512*2);
  u16* W1h  = (u16*)alloc((size_t)2048*512*2);
  u16* W1l  = (u16*)alloc((size_t)2048*512*2);
  u16* W2h  = (u16*)alloc((size_t)512*2048*2);
  u16* W2l  = (u16*)alloc((size_t)512*2048*2);
  float* WCf = (float*)alloc((size_t)512*512*4);
  u16* CTh  = (u16*)alloc((size_t)512*512*2);
  u16* CTl  = (u16*)alloc((size_t)512*512*2);
  u16* CVh  = (u16*)alloc((size_t)3*512*512*2);
  u16* CVl  = (u16*)alloc((size_t)3*512*512*2);
  float* AG0 = (float*)alloc((size_t)MG*4096*4);
  float* AG1 = (float*)alloc((size_t)MG*4096*4);
  float* MU   = (float*)alloc(NNODE*4);
  float* RS   = (float*)alloc(NNODE*4);
  int*   DEG0 = (int*)alloc(NTOK*4);
  float* DIS0 = (float*)alloc(NTOK*4);
  float* COEF0= (float*)alloc(NEDGE*4);
  float* HS   = (float*)alloc(NTOK*4);
  float* SC   = (float*)alloc(NTOK*4);
  int*   PERM1= (int*)alloc(MG*KP1*4);
  int*   NMAP = (int*)alloc(NTOK*4);
  int*   ES1  = (int*)alloc(NEDGE*4);
  int*   ED1  = (int*)alloc(NEDGE*4);
  int*   KEEP1= (int*)alloc(NEDGE*4);
  int*   DEG1 = (int*)alloc(MG*KP1*4);
  float* DIS1 = (float*)alloc(MG*KP1*4);
  float* COEF1= (float*)alloc(NEDGE*4);
  int*   PERM2= (int*)alloc(MG*KP2*4);
  float* Z    = (float*)alloc(MG*1024*4);
  float* Pm   = (float*)alloc((size_t)4*MG*512*4);

  float* PA = PART;
  float* PB = PART + 2*MN;

  // ---- BN + embed + graph structure + GCN weight prep ----
  bn_stats_kernel<<<NNODE, 256, 0, stream>>>(x, MU, RS);
  embed_kernel<<<NTOK, 256, 0, stream>>>(x, MU, RS, bn_g, bn_b, W_emb, T, Th, Tl);
  fill_int_kernel<<<(NTOK+255)/256, 256, 0, stream>>>(DEG0, 1, NTOK);
  count_deg_kernel<<<(NEDGE+255)/256, 256, 0, stream>>>(dstp, DEG0, NEDGE);
  dis_kernel<<<(NTOK+255)/256, 256, 0, stream>>>(DEG0, DIS0, NTOK);
  coef0_kernel<<<(NEDGE+255)/256, 256, 0, stream>>>(srcp, dstp, DIS0, COEF0);
  zero_f_kernel<<<(MG*4096+255)/256, 256, 0, stream>>>(AG0, MG*4096);
  diagA_kernel<<<MG, 64, 0, stream>>>(DIS0, AG0, NNODE);
  edgeA_kernel<<<(NEDGE+255)/256, 256, 0, stream>>>(srcp, dstp, COEF0, AG0, NNODE);
  gemm_kernel<<<dim3(8,8), 256, 0, stream>>>(W_emb1, conv1_W, WCf, 512, 512, NNODE);
  gcnT_kernel<<<256, 256, 0, stream>>>(WCf, convs_W, CTh, CTl, CVh, CVl);

  // ---- transformer encoder ----
  for (int l = 0; l < NLAYER; ++l) {
    layerT_kernel<<<768, 256, 0, stream>>>(
        Wqkv + (size_t)l*DD*3*DD, Wo + (size_t)l*DD*DD,
        W1 + (size_t)l*DD*DFF, W2 + (size_t)l*DFF*DD,
        WQh, WQl, WOh, WOl, W1h, W1l, W2h, W2l);
    gemm3_kernel<false,2><<<dim3(12,62,1), 256, 0, stream>>>(Th, Tl, WQh, WQl,
        bqkv + (size_t)l*3*DD, QKVf, nullptr, nullptr, 3*DD, 3*DD, DD, DD);
    attn_kernel<<<MG*NH, 256, 0, stream>>>(QKVf, ATh, ATl);
    gemm3_kernel<false,0><<<dim3(4,62,2), 256, 0, stream>>>(ATh, ATl, WOh, WOl,
        bo + (size_t)l*DD, PART, nullptr, nullptr, DD, DD, DD, 256);
    add_ln_kernel<<<NTOK, 256, 0, stream>>>(T, PART, 2,
        g1 + (size_t)l*DD, be1 + (size_t)l*DD, Th, Tl);
    gemm3_kernel<true,1><<<dim3(16,62,1), 256, 0, stream>>>(Th, Tl, W1h, W1l,
        b1 + (size_t)l*DFF, nullptr, BIGh, BIGl, DFF, DFF, DD, DD);
    gemm3_kernel<false,0><<<dim3(4,62,2), 256, 0, stream>>>(BIGh, BIGl, W2h, W2l,
        b2 + (size_t)l*DD, PART, nullptr, nullptr, DD, DD, DFF, 1024);
    add_ln_kernel<<<NTOK, 256, 0, stream>>>(T, PART, 2,
        g2 + (size_t)l*DD, be2 + (size_t)l*DD, Th, Tl);
  }

  // ---- conv1 = relu(A~0 @ (t @ Wcomb) + b) ----
  gemm3_kernel<false,0><<<dim3(4,62,2), 256, 0, stream>>>(Th, Tl, CTh, CTl,
      nullptr, PA, nullptr, nullptr, DD, DD, DD, 256);
  dense_agg_kernel<<<MG*8, 256, 0, stream>>>(AG0, PA, 2, MN, conv1_b,
      PA, NNODE, 1, nullptr, nullptr);

  // ---- SAGPool 1 ----
  gemv_kernel<<<(NTOK+3)/4, 256, 0, stream>>>(PA, pool1_W, HS, NTOK);
  dense_score_kernel<<<MG, 64, 0, stream>>>(AG0, HS, pool1_b, SC, NNODE);
  topk_kernel<<<MG, 64, 0, stream>>>(SC, PERM1, NNODE, KP1);
  gather_kernel<<<MG*KP1, 256, 0, stream>>>(PA, SC, PERM1, PA + MN, Hh, Hl, NNODE, KP1);
  readout_kernel<<<MG, 256, 0, stream>>>(PA + MN, Z, KP1, 0);

  // ---- filter_adj + dense adjacency level 1 ----
  fill_int_kernel<<<(NTOK+255)/256, 256, 0, stream>>>(NMAP, -1, NTOK);
  nmap_scatter_kernel<<<(MG*KP1+255)/256, 256, 0, stream>>>(PERM1, NMAP);
  fill_int_kernel<<<(MG*KP1+255)/256, 256, 0, stream>>>(DEG1, 1, MG*KP1);
  filter_kernel<<<(NEDGE+255)/256, 256, 0, stream>>>(srcp, dstp, NMAP, ES1, ED1, KEEP1, DEG1);
  dis_kernel<<<(MG*KP1+255)/256, 256, 0, stream>>>(DEG1, DIS1, MG*KP1);
  coef1_kernel<<<(NEDGE+255)/256, 256, 0, stream>>>(ES1, ED1, KEEP1, DIS1, COEF1);
  zero_f_kernel<<<(MG*4096+255)/256, 256, 0, stream>>>(AG1, MG*4096);
  diagA_kernel<<<MG, 64, 0, stream>>>(DIS1, AG1, KP1);
  edgeA_kernel<<<(NEDGE+255)/256, 256, 0, stream>>>(ES1, ED1, COEF1, AG1, KP1);

  // ---- 3 GCN layers on pooled graph ----
  const size_t MNP = (size_t)MG*KP1*DD;
  float* bases[3] = { PB, PA, PB };
  float* hfin = nullptr;
  for (int l = 0; l < NLAYER-1; ++l) {
    float* Pb = bases[l];
    gemm3_kernel<false,0><<<dim3(4,50,2), 256, 0, stream>>>(Hh, Hl, CVh + (size_t)l*DD*DD,
        CVl + (size_t)l*DD*DD, nullptr, Pb, nullptr, nullptr, DD, DD, DD, 256);
    dense_agg_kernel<<<MG*8, 256, 0, stream>>>(AG1, Pb, 2, MNP, convs_b + (size_t)l*DD,
        Pb, KP1, 1, (l < NLAYER-2) ? Hh : nullptr, (l < NLAYER-2) ? Hl : nullptr);
    hfin = Pb;
  }

  // ---- SAGPool 2 ----
  gemv_kernel<<<(MG*KP1+3)/4, 256, 0, stream>>>(hfin, pool2_W, HS, MG*KP1);
  dense_score_kernel<<<MG, 64, 0, stream>>>(AG1, HS, pool2_b, SC, KP1);
  topk_kernel<<<MG, 64, 0, stream>>>(SC, PERM2, KP1, KP2);
  gather_kernel<<<MG*KP2, 256, 0, stream>>>(hfin, SC, PERM2, PA, nullptr, nullptr, KP1, KP2);
  readout_kernel<<<MG, 256, 0, stream>>>(PA, Z, KP2, 1);

  // ---- MLP head ----
  mlp1_kernel<<<MG*4, 256, 0, stream>>>(Z, fc1_W, Pm);
  mlp2_kernel<<<MG, 256, 0, stream>>>(Pm, fc1_b, fc2_W, fc2_b, fc3_W, fc3_b, (float*)d_out);
}